// Round 1
// 3570.735 us; speedup vs baseline: 1.1184x; 1.1184x over previous
//
#include <hip/hip_runtime.h>
#include <math.h>

// MPNN on MI355X. R20 = R19 + MFMA-ized GRU/node_pre path.
// gru_fused (fp32 GEMV, ~33% VALUBusy, MfmaUtil 0) is replaced by
// gru_mfma_kernel: bf16 hi/lo 3-term split (hi*hi+hi*lo+lo*hi, fp32 acc,
// ~17 mantissa bits => added err ~1e-5 << 6.35e-4 budget) on
// v_mfma_f32_16x16x32_bf16. A and B fragments are packed with the SAME
// (lane>>4,elem)->k map, so correctness is invariant to the HW's internal
// k-ordering; C/D layout col=lane&15,row=(lane>>4)*4+reg (HW-verified).
// Gate GEMM: [64 nodes x K=256(concat m*ci,h)] @ [256 x 512(z|r|xh|hh)],
// epilogue is lane-local, then h' is re-split into LDS frags feeding the
// fused node_pre GEMM [64x128]@[128x128]. Weights pre-packed once into
// global B-fragment buffers (pack_gateB/pack_preB).
// Edge MLP / CSR / straddle machinery unchanged from R19.

#define DDIM 128
#define NTOT 128000
#define HBYTES 65536000ULL   // 128000*128*4
#define EBLK 128

typedef unsigned short u16;
using f32x4 = __attribute__((ext_vector_type(4))) float;
using s16x8 = __attribute__((ext_vector_type(8))) short;

__device__ __forceinline__ float gelu_exact(float x) {
    return 0.5f * x * (1.0f + erff(x * 0.70710678118654752440f));
}
__device__ __forceinline__ float sigmoidf_(float x) {
    return 1.0f / (1.0f + expf(-x));
}
__device__ __forceinline__ u16 f2bf(float x) {            // RNE f32->bf16
    unsigned u = __float_as_uint(x);
    u += 0x7fffu + ((u >> 16) & 1u);
    return (u16)(u >> 16);
}
__device__ __forceinline__ float bf2f(u16 h) {
    return __uint_as_float(((unsigned)h) << 16);
}

__global__ __launch_bounds__(256) void embed_kernel(
    const int* __restrict__ inp, const float* __restrict__ table,
    float* __restrict__ h)
{
    int gid = blockIdx.x * 256 + threadIdx.x;
    if (gid >= NTOT * 32) return;
    int row = gid >> 5;
    int q   = gid & 31;
    int b   = row / 4000;
    int n   = (row % 4000) % 1000;
    int e   = inp[b * 1000 + n];
    ((float4*)h)[gid] = ((const float4*)table)[e * 32 + q];
}

__global__ __launch_bounds__(256) void hist_kernel(
    const int* __restrict__ ni, const int* __restrict__ bi, int E,
    int* __restrict__ deg)
{
    int g = blockIdx.x * 256 + threadIdx.x;
    if (g < E)          atomicAdd(&deg[bi[g]], 1);
    else if (g < 2 * E) atomicAdd(&deg[ni[g - E]], 1);
}

__global__ __launch_bounds__(256) void blockscan_kernel(
    const int* __restrict__ deg, int* __restrict__ offp, int* __restrict__ bsum)
{
    __shared__ int s[256];
    int tid = threadIdx.x;
    int i = blockIdx.x * 256 + tid;
    int v = deg[i];
    s[tid] = v;
    __syncthreads();
    for (int off = 1; off < 256; off <<= 1) {
        int t = (tid >= off) ? s[tid - off] : 0;
        __syncthreads();
        s[tid] += t;
        __syncthreads();
    }
    offp[i] = s[tid] - v;
    if (tid == 255) bsum[blockIdx.x] = s[255];
}

__global__ __launch_bounds__(512) void bscan_kernel(
    const int* __restrict__ bsum, int* __restrict__ bexc, int nb)
{
    __shared__ int s[512];
    int t = threadIdx.x;
    int v = (t < nb) ? bsum[t] : 0;
    s[t] = v;
    __syncthreads();
    for (int off = 1; off < 512; off <<= 1) {
        int u = (t >= off) ? s[t - off] : 0;
        __syncthreads();
        s[t] += u;
        __syncthreads();
    }
    if (t < nb) bexc[t] = s[t] - v;
}

__global__ __launch_bounds__(256) void fill_kernel(
    const int* __restrict__ ni, const int* __restrict__ bi, int E,
    const int* __restrict__ offp, const int* __restrict__ bexc,
    int* __restrict__ cursor, int* __restrict__ elist, int* __restrict__ slotseg)
{
    int g = blockIdx.x * 256 + threadIdx.x;
    if (g >= 2 * E) return;
    int seg = (g < E) ? bi[g] : ni[g - E];
    int pos = atomicAdd(&cursor[seg], 1);
    int slot = offp[seg] + bexc[seg >> 8] + pos;
    elist[slot] = g;
    slotseg[slot] = seg;
}

// Segments straddling an EBLK boundary (the only atomicAdd targets).
__global__ __launch_bounds__(256) void straddle_kernel(
    const int* __restrict__ slotseg, int nblocks,
    int* __restrict__ list, int* __restrict__ count)
{
    int b = blockIdx.x * 256 + threadIdx.x + 1;
    if (b >= nblocks) return;
    int s = slotseg[b * EBLK];
    if (s >= 0 && slotseg[b * EBLK - 1] == s) {
        int pos = atomicAdd(count, 1);
        list[pos] = s;
    }
}

__global__ __launch_bounds__(64) void zero_rows_kernel(
    const int* __restrict__ list, const int* __restrict__ count,
    float* __restrict__ sbuf)
{
    int i = blockIdx.x;
    if (i >= *count) return;
    int seg = list[i];
    float4* row = (float4*)(sbuf + (size_t)seg * DDIM);
    if (threadIdx.x < 32) row[threadIdx.x] = make_float4(0.f, 0.f, 0.f, 0.f);
}

// ---------------------------------------------------------------------------
// B-fragment packers (run once per launch).
// Gate B: [K=256][N=512] with N = z(128)|r(128)|xh(128)|hh(128);
//   K rows 0..127 multiply m*ci (Wx), rows 128..255 multiply h (Wh);
//   xh has zero h-rows, hh has zero x-rows (padding trades 25% MFMA for a
//   lane-local gate epilogue).
// Fragment map (shared with A packing): lane l, elem j -> k = kt*32+(l>>4)*8+j,
//   n = nt*16+(l&15). idx = ((kt*32+nt)*64+lane)*8+j.
// ---------------------------------------------------------------------------
__global__ __launch_bounds__(256) void pack_gateB_kernel(
    const float* __restrict__ Wx, const float* __restrict__ Wh,
    u16* __restrict__ BH, u16* __restrict__ BL)
{
    int idx = blockIdx.x * 256 + threadIdx.x;   // 131072 total
    if (idx >= 131072) return;
    int j    = idx & 7;
    int lane = (idx >> 3) & 63;
    int ntG  = (idx >> 9) & 31;
    int ktG  = idx >> 14;                        // 0..7
    int k = ktG * 32 + (lane >> 4) * 8 + j;      // 0..255
    int n = ntG * 16 + (lane & 15);              // 0..511
    int g = n >> 7, jj = n & 127;
    float v;
    if (g == 0)      v = (k < 128) ? Wx[k * 384 + jj]       : Wh[(k - 128) * 384 + jj];
    else if (g == 1) v = (k < 128) ? Wx[k * 384 + 128 + jj] : Wh[(k - 128) * 384 + 128 + jj];
    else if (g == 2) v = (k < 128) ? Wx[k * 384 + 256 + jj] : 0.0f;
    else             v = (k < 128) ? 0.0f                   : Wh[(k - 128) * 384 + 256 + jj];
    u16 hb = f2bf(v);
    BH[idx] = hb;
    BL[idx] = f2bf(v - bf2f(hb));
}

// node_pre B: [K=128][N=128], n<64 -> Win rows 0..127 (top, +bin),
//             n>=64 -> Win rows 128..255 (bottom).
__global__ __launch_bounds__(256) void pack_preB_kernel(
    const float* __restrict__ Win, u16* __restrict__ BH, u16* __restrict__ BL)
{
    int idx = blockIdx.x * 256 + threadIdx.x;   // 16384 total
    if (idx >= 16384) return;
    int j    = idx & 7;
    int lane = (idx >> 3) & 63;
    int nt2  = (idx >> 9) & 7;
    int kt2  = idx >> 12;                        // 0..3
    int k = kt2 * 32 + (lane >> 4) * 8 + j;      // 0..127
    int n = nt2 * 16 + (lane & 15);              // 0..127
    float v = (n < 64) ? Win[k * 64 + n] : Win[(128 + k) * 64 + (n - 64)];
    u16 hb = f2bf(v);
    BH[idx] = hb;
    BL[idx] = f2bf(v - bf2f(hb));
}

// Initial p only: p[v][0:64)=Wtop@h[v]+bin, p[v][64:128)=Wbot@h[v].
__global__ __launch_bounds__(256) void node_pre_kernel(
    const float* __restrict__ h, const float* __restrict__ Win,
    const float* __restrict__ bin, float* __restrict__ p)
{
    const int node = blockIdx.x * 256 + threadIdx.x;
    const float4* h4 = (const float4*)(h + (size_t)node * DDIM);
    float* prow = p + (size_t)node * DDIM;

    for (int c = 0; c < 4; ++c) {
        const int top   = (c < 2) ? 1 : 0;
        const int j0    = (c & 1) * 32;
        const int kbase = top ? 0 : 128;
        float acc[32];
        #pragma unroll
        for (int j = 0; j < 32; ++j) acc[j] = top ? bin[j0 + j] : 0.0f;
        for (int k4 = 0; k4 < 32; ++k4) {
            float4 hv = h4[k4];
            #pragma unroll
            for (int kk = 0; kk < 4; ++kk) {
                const float hk = (&hv.x)[kk];
                const float* wr = Win + (size_t)(kbase + k4 * 4 + kk) * 64 + j0;
                #pragma unroll
                for (int j = 0; j < 32; ++j) acc[j] = fmaf(hk, wr[j], acc[j]);
            }
        }
        float* dst = prow + (top ? 0 : 64) + j0;
        #pragma unroll
        for (int q = 0; q < 8; ++q)
            ((float4*)dst)[q] = make_float4(acc[q*4], acc[q*4+1],
                                            acc[q*4+2], acc[q*4+3]);
    }
}

// Edge MLP: per-thread LDS activation slices, scalar weights, fused
// segmented reduction. Straddle rows of sbuf must be pre-zeroed.
__global__ __launch_bounds__(EBLK) void edge_mlp_kernel3(
    const int* __restrict__ ni, const int* __restrict__ bi, int E,
    const int* __restrict__ elist, const int* __restrict__ slotseg,
    const float* __restrict__ p,
    const float* __restrict__ Whid, const float* __restrict__ bhid,
    const float* __restrict__ Wout, const float* __restrict__ bout,
    float* __restrict__ sbuf)
{
    __shared__ float xs[EBLK * 65];
    __shared__ float scat[16 * 68];
    __shared__ int   segLDS[EBLK];
    __shared__ int   segedge[2];
    const int tid  = threadIdx.x;
    const int lane = tid & 63;
    const int s0   = blockIdx.x * EBLK;
    const int slot = s0 + tid;

    const int seg = slotseg[slot];
    const int g   = (seg >= 0) ? elist[slot] : 0;
    int first = 0, second = 0;
    if (seg >= 0) {
        if (g < E) { first = ni[g];     second = bi[g];     }
        else       { first = bi[g - E]; second = ni[g - E]; }
    }
    segLDS[tid] = seg;
    if (tid == 0) segedge[0] = slotseg[s0 - 1];
    if (tid == 1) segedge[1] = slotseg[s0 + EBLK];

    {
        const float4* pa = (const float4*)(p + (size_t)first  * DDIM);
        const float4* pb = (const float4*)(p + (size_t)second * DDIM + 64);
        #pragma unroll 4
        for (int q = 0; q < 16; ++q) {
            float4 a = pa[q], b = pb[q];
            xs[tid * 65 + q * 4 + 0] = gelu_exact(a.x + b.x);
            xs[tid * 65 + q * 4 + 1] = gelu_exact(a.y + b.y);
            xs[tid * 65 + q * 4 + 2] = gelu_exact(a.z + b.z);
            xs[tid * 65 + q * 4 + 3] = gelu_exact(a.w + b.w);
        }
    }

    for (int L = 0; L < 3; ++L) {
        float acc[64];
        #pragma unroll
        for (int j = 0; j < 64; ++j) acc[j] = bhid[L * 64 + j];
        #pragma unroll 4
        for (int k = 0; k < 64; ++k) {
            const float xk = xs[tid * 65 + k];
            const float* wr = Whid + (size_t)L * 4096 + (size_t)k * 64;
            #pragma unroll
            for (int j = 0; j < 64; ++j) acc[j] = fmaf(xk, wr[j], acc[j]);
        }
        #pragma unroll
        for (int j = 0; j < 64; ++j) xs[tid * 65 + j] = gelu_exact(acc[j]);
    }

    for (int half = 0; half < 2; ++half) {
        float acc[64];
        #pragma unroll
        for (int j = 0; j < 64; ++j) acc[j] = bout[half * 64 + j];
        #pragma unroll 4
        for (int k = 0; k < 64; ++k) {
            const float xk = xs[tid * 65 + k];
            const float* wr = Wout + (size_t)k * 128 + half * 64;
            #pragma unroll
            for (int j = 0; j < 64; ++j) acc[j] = fmaf(xk, wr[j], acc[j]);
        }

        int   runSeg = -2;
        float runacc = 0.0f;
        bool  leftC  = true;
        for (int b = 0; b < 8; ++b) {
            __syncthreads();
            if ((tid >> 4) == b) {
                float4* dp = (float4*)&scat[(tid & 15) * 68];
                #pragma unroll
                for (int q = 0; q < 16; ++q)
                    dp[q] = make_float4(acc[q*4], acc[q*4+1], acc[q*4+2], acc[q*4+3]);
            }
            __syncthreads();
            if (tid < 64) {
                for (int r = 0; r < 16; ++r) {
                    const int rowi = b * 16 + r;
                    const int sg = segLDS[rowi];
                    const float v = scat[r * 68 + lane];
                    if (sg != runSeg) {
                        if (runSeg >= 0) {
                            float* pp = sbuf + (size_t)runSeg * DDIM + half * 64 + lane;
                            if (leftC) *pp = runacc;
                            else       atomicAdd(pp, runacc);
                        }
                        runSeg = sg;
                        runacc = v;
                        leftC  = (rowi == 0) ? (segedge[0] != sg) : true;
                    } else {
                        runacc += v;
                    }
                }
            }
        }
        if (tid < 64 && runSeg >= 0) {
            const bool rightC = (segedge[1] != runSeg);
            float* pp = sbuf + (size_t)runSeg * DDIM + half * 64 + lane;
            if (leftC && rightC) *pp = runacc;
            else                 atomicAdd(pp, runacc);
        }
        __syncthreads();
    }
}

// ---------------------------------------------------------------------------
// MFMA GRU + fused node_pre. 64 nodes/block, 512 threads (8 waves).
// wave w: mt = w>>1 (m-tile of 16 nodes), jg = w&1 (j-half of 64 cols).
// LDS: 64KB. Phase 1: stage A = [m*ci | h] as bf16 hi/lo frags (32KB hi +
// 32KB lo). Phase 2: gate GEMM K=256, N=512 -> acc[g 0..3][t 0..3] f32x4.
// Phase 3: lane-local gate epilogue -> h' (write hout) + scatter h' frags
// into reused LDS. Phase 4: node_pre GEMM K=128,N=128 -> p (write msum).
// ---------------------------------------------------------------------------
__global__ __launch_bounds__(512) void gru_mfma_kernel(
    const float* __restrict__ h, float* __restrict__ msum,
    const int* __restrict__ deg,
    const u16* __restrict__ BgH, const u16* __restrict__ BgL,
    const float* __restrict__ bi_, const float* __restrict__ br_,
    const u16* __restrict__ BpH, const u16* __restrict__ BpL,
    const float* __restrict__ binp,
    float* __restrict__ hout)
{
    __shared__ short sm[32768];   // 64 KB: [hi 16384][lo 16384] shorts
    const int tid  = threadIdx.x;
    const int lane = tid & 63;
    const int w    = tid >> 6;
    const int mt   = w >> 1;
    const int jg   = w & 1;
    const int nbase = blockIdx.x * 64;

    // ---- Phase 1: stage A fragments (all K=256 at once) ----
    {
        const int mS = tid >> 3, g8 = tid & 7;
        const int nodeS = nbase + mS;
        const int dg = deg[nodeS];
        const float ci = (dg > 0) ? (1.0f / (float)dg) : 0.0f;
        #pragma unroll
        for (int c = 0; c < 4; ++c) {
            const float* src = (c < 2)
                ? (msum + (size_t)nodeS * DDIM + c * 64 + g8 * 8)
                : (h    + (size_t)nodeS * DDIM + (c - 2) * 64 + g8 * 8);
            const float4 v0 = ((const float4*)src)[0];
            const float4 v1 = ((const float4*)src)[1];
            const float sc = (c < 2) ? ci : 1.0f;
            float xv[8] = { v0.x * sc, v0.y * sc, v0.z * sc, v0.w * sc,
                            v1.x * sc, v1.y * sc, v1.z * sc, v1.w * sc };
            s16x8 hi8, lo8;
            #pragma unroll
            for (int i = 0; i < 8; ++i) {
                u16 hb = f2bf(xv[i]);
                hi8[i] = (short)hb;
                lo8[i] = (short)f2bf(xv[i] - bf2f(hb));
            }
            const int ktG   = c * 2 + (g8 >> 2);
            const int laneS = (mS & 15) + 16 * (g8 & 3);
            const int off   = (ktG * 4 + (mS >> 4)) * 512 + laneS * 8;
            *(s16x8*)(sm + off)         = hi8;
            *(s16x8*)(sm + off + 16384) = lo8;
        }
    }
    __syncthreads();

    // ---- Phase 2: gate GEMM ----
    f32x4 acc[4][4];
    #pragma unroll
    for (int g = 0; g < 4; ++g)
        #pragma unroll
        for (int t4 = 0; t4 < 4; ++t4)
            acc[g][t4] = (f32x4){0.f, 0.f, 0.f, 0.f};

    const s16x8* Bh8 = (const s16x8*)BgH;
    const s16x8* Bl8 = (const s16x8*)BgL;
    #pragma unroll
    for (int ktG = 0; ktG < 8; ++ktG) {
        const s16x8 aH = *(const s16x8*)(sm + (ktG * 4 + mt) * 512 + lane * 8);
        const s16x8 aL = *(const s16x8*)(sm + 16384 + (ktG * 4 + mt) * 512 + lane * 8);
        #pragma unroll
        for (int g = 0; g < 4; ++g) {
            #pragma unroll
            for (int t4 = 0; t4 < 4; ++t4) {
                const int idx = (ktG * 32 + g * 8 + jg * 4 + t4) * 64 + lane;
                const s16x8 bH = Bh8[idx];
                const s16x8 bL = Bl8[idx];
                acc[g][t4] = __builtin_amdgcn_mfma_f32_16x16x32_bf16(aH, bH, acc[g][t4], 0, 0, 0);
                acc[g][t4] = __builtin_amdgcn_mfma_f32_16x16x32_bf16(aH, bL, acc[g][t4], 0, 0, 0);
                acc[g][t4] = __builtin_amdgcn_mfma_f32_16x16x32_bf16(aL, bH, acc[g][t4], 0, 0, 0);
            }
        }
    }

    // ---- Phase 3: gate epilogue (lane-local) -> h' ----
    float hn[4][4];
    #pragma unroll
    for (int t4 = 0; t4 < 4; ++t4) {
        const int j = jg * 64 + t4 * 16 + (lane & 15);
        const float b_az = bi_[j]       + br_[j];
        const float b_ar = bi_[128 + j] + br_[128 + j];
        const float b_xh = bi_[256 + j];
        const float b_hh = br_[256 + j];
        #pragma unroll
        for (int r = 0; r < 4; ++r) {
            const int m = mt * 16 + (lane >> 4) * 4 + r;
            const float az = acc[0][t4][r] + b_az;
            const float ar = acc[1][t4][r] + b_ar;
            const float xh = acc[2][t4][r] + b_xh;
            const float hh = acc[3][t4][r] + b_hh;
            const float z    = sigmoidf_(az);
            const float rr   = sigmoidf_(ar);
            const float cand = tanhf(xh + rr * hh);
            const float hv   = h[(size_t)(nbase + m) * DDIM + j];
            const float v    = z * hv + (1.0f - z) * cand;
            hout[(size_t)(nbase + m) * DDIM + j] = v;
            hn[t4][r] = v;
        }
    }

    __syncthreads();   // gate GEMM LDS reads done everywhere; reuse sm

    // scatter h' into node_pre A-frag layout (k = j, same frag map)
    #pragma unroll
    for (int t4 = 0; t4 < 4; ++t4) {
        #pragma unroll
        for (int r = 0; r < 4; ++r) {
            const int m  = mt * 16 + (lane >> 4) * 4 + r;
            const int j  = jg * 64 + t4 * 16 + (lane & 15);
            const int kt2 = j >> 5, gg = (j >> 3) & 3, jj = j & 7;
            const int lane2 = (m & 15) + 16 * gg;
            const int off = (kt2 * 4 + mt) * 512 + lane2 * 8 + jj;
            const float v = hn[t4][r];
            u16 hb = f2bf(v);
            sm[off]        = (short)hb;
            sm[off + 8192] = (short)f2bf(v - bf2f(hb));
        }
    }
    __syncthreads();

    // ---- Phase 4: node_pre GEMM -> p (into msum) ----
    f32x4 acc2[4];
    #pragma unroll
    for (int t4 = 0; t4 < 4; ++t4) acc2[t4] = (f32x4){0.f, 0.f, 0.f, 0.f};

    const s16x8* Ph8 = (const s16x8*)BpH;
    const s16x8* Pl8 = (const s16x8*)BpL;
    #pragma unroll
    for (int kt2 = 0; kt2 < 4; ++kt2) {
        const s16x8 aH = *(const s16x8*)(sm + (kt2 * 4 + mt) * 512 + lane * 8);
        const s16x8 aL = *(const s16x8*)(sm + 8192 + (kt2 * 4 + mt) * 512 + lane * 8);
        #pragma unroll
        for (int t4 = 0; t4 < 4; ++t4) {
            const int idx = (kt2 * 8 + jg * 4 + t4) * 64 + lane;
            const s16x8 bH = Ph8[idx];
            const s16x8 bL = Pl8[idx];
            acc2[t4] = __builtin_amdgcn_mfma_f32_16x16x32_bf16(aH, bH, acc2[t4], 0, 0, 0);
            acc2[t4] = __builtin_amdgcn_mfma_f32_16x16x32_bf16(aH, bL, acc2[t4], 0, 0, 0);
            acc2[t4] = __builtin_amdgcn_mfma_f32_16x16x32_bf16(aL, bH, acc2[t4], 0, 0, 0);
        }
    }
    #pragma unroll
    for (int t4 = 0; t4 < 4; ++t4) {
        const int n = jg * 64 + t4 * 16 + (lane & 15);
        const float badd = (n < 64) ? binp[n] : 0.0f;
        #pragma unroll
        for (int r = 0; r < 4; ++r) {
            const int m = mt * 16 + (lane >> 4) * 4 + r;
            msum[(size_t)(nbase + m) * DDIM + n] = acc2[t4][r] + badd;
        }
    }
}

// Readout: block=64, LDS activation slices, scalar weights.
__global__ __launch_bounds__(64) void readout_kernel(
    const float* __restrict__ h,
    const float* __restrict__ Win,  const float* __restrict__ bin,
    const float* __restrict__ Whid, const float* __restrict__ bhid,
    const float* __restrict__ Wout, const float* __restrict__ bout,
    float* __restrict__ out)
{
    __shared__ float xs[64 * 65];
    const int tid = threadIdx.x;
    const int row = blockIdx.x * 64 + tid;
    const int b = row / 1000, n = row % 1000;
    const float4* xrow = (const float4*)(h + ((size_t)b * 4000 + n) * DDIM);

    {
        float acc[64];
        #pragma unroll
        for (int j = 0; j < 64; ++j) acc[j] = bin[j];
        #pragma unroll 2
        for (int k4 = 0; k4 < 32; ++k4) {
            float4 xv = xrow[k4];
            #pragma unroll
            for (int kk = 0; kk < 4; ++kk) {
                const float xk = (&xv.x)[kk];
                const float* wr = Win + (size_t)(k4 * 4 + kk) * 64;
                #pragma unroll
                for (int j = 0; j < 64; ++j) acc[j] = fmaf(xk, wr[j], acc[j]);
            }
        }
        #pragma unroll
        for (int j = 0; j < 64; ++j) xs[tid * 65 + j] = gelu_exact(acc[j]);
    }

    for (int L = 0; L < 3; ++L) {
        float acc[64];
        #pragma unroll
        for (int j = 0; j < 64; ++j) acc[j] = bhid[L * 64 + j];
        #pragma unroll 4
        for (int k = 0; k < 64; ++k) {
            const float xk = xs[tid * 65 + k];
            const float* wr = Whid + (size_t)L * 4096 + (size_t)k * 64;
            #pragma unroll
            for (int j = 0; j < 64; ++j) acc[j] = fmaf(xk, wr[j], acc[j]);
        }
        #pragma unroll
        for (int j = 0; j < 64; ++j) xs[tid * 65 + j] = gelu_exact(acc[j]);
    }

    float acc[10];
    #pragma unroll
    for (int pj = 0; pj < 10; ++pj) acc[pj] = bout[pj];
    #pragma unroll 4
    for (int k = 0; k < 64; ++k) {
        const float xk = xs[tid * 65 + k];
        const float* wr = Wout + k * 10;
        #pragma unroll
        for (int pj = 0; pj < 10; ++pj) acc[pj] = fmaf(xk, wr[pj], acc[pj]);
    }
    #pragma unroll
    for (int pj = 0; pj < 10; ++pj) out[(size_t)row * 10 + pj] = acc[pj];
}

extern "C" void kernel_launch(void* const* d_in, const int* in_sizes, int n_in,
                              void* d_out, int out_size, void* d_ws, size_t ws_size,
                              hipStream_t stream) {
    const int*   node_inputs = (const int*)d_in[0];
    const int*   ni_int = (const int*)d_in[1];
    const int*   bi_int = (const int*)d_in[2];
    const int*   ni_tmp = (const int*)d_in[3];
    const int*   bi_tmp = (const int*)d_in[4];
    const float* embed  = (const float*)d_in[5];
    const float* mWin   = (const float*)d_in[6];
    const float* mbin   = (const float*)d_in[7];
    const float* mWhid  = (const float*)d_in[8];
    const float* mbhid  = (const float*)d_in[9];
    const float* mWout  = (const float*)d_in[10];
    const float* mbout  = (const float*)d_in[11];
    const float* roWin  = (const float*)d_in[12];
    const float* robin  = (const float*)d_in[13];
    const float* roWhid = (const float*)d_in[14];
    const float* robhid = (const float*)d_in[15];
    const float* roWout = (const float*)d_in[16];
    const float* robout = (const float*)d_in[17];
    const float* giWx = (const float*)d_in[18];
    const float* giWh = (const float*)d_in[19];
    const float* gibi = (const float*)d_in[20];
    const float* gibr = (const float*)d_in[21];
    const float* gtWx = (const float*)d_in[22];
    const float* gtWh = (const float*)d_in[23];
    const float* gtbi = (const float*)d_in[24];
    const float* gtbr = (const float*)d_in[25];
    float* out = (float*)d_out;

    const int E_INT = 200000, E_TMP = 96000;
    const int NSLOT_I = 400000;   // 3125*128 exact
    const int NSLOT_T = 192000;   // 1500*128 exact
    const int NBLK_I = NSLOT_I / EBLK;
    const int NBLK_T = NSLOT_T / EBLK;

    char* ws = (char*)d_ws;
    float* B0 = (float*)(ws);
    float* B1 = (float*)(ws + HBYTES);
    float* B2 = (float*)(ws + 2 * HBYTES);
    char*  ib = ws + 3 * HBYTES;

    int* deg_i   = (int*)(ib);
    int* deg_t   = (int*)(ib + 512000);
    int* offp_i  = (int*)(ib + 1024000);
    int* offp_t  = (int*)(ib + 1536000);
    int* bexc_i  = (int*)(ib + 2048000);
    int* bexc_t  = (int*)(ib + 2052096);
    int* bsum    = (int*)(ib + 2056192);
    int* cursor  = (int*)(ib + 2060288);
    int* el_i    = (int*)(ib + 2572288);
    int* el_t    = (int*)(ib + 4172288);
    int* ssi_raw = (int*)(ib + 4940288);
    int* sst_raw = (int*)(ib + 6540296);
    int* str_i   = (int*)(ib + 8094784);
    int* str_t   = (int*)(ib + 8107384);
    int* strc_i  = (int*)(ib + 8113484);
    int* strc_t  = (int*)(ib + 8113488);
    // bf16-split B-fragment buffers (new in R20)
    char* fb = ib + 8114176;
    u16* BgiH = (u16*)(fb);
    u16* BgiL = (u16*)(fb +  262144);
    u16* BgtH = (u16*)(fb +  524288);
    u16* BgtL = (u16*)(fb +  786432);
    u16* BpH  = (u16*)(fb + 1048576);
    u16* BpL  = (u16*)(fb + 1081344);
    int* ssi = ssi_raw + 1;
    int* sst = sst_raw + 1;

    embed_kernel<<<16000, 256, 0, stream>>>(node_inputs, embed, B0);

    hipMemsetAsync(deg_i, 0, NTOT * sizeof(int), stream);
    hipMemsetAsync(deg_t, 0, NTOT * sizeof(int), stream);
    hist_kernel<<<(2 * E_INT + 255) / 256, 256, 0, stream>>>(ni_int, bi_int, E_INT, deg_i);
    hist_kernel<<<(2 * E_TMP + 255) / 256, 256, 0, stream>>>(ni_tmp, bi_tmp, E_TMP, deg_t);

    hipMemsetAsync(ssi_raw, 0xFF, (size_t)(NSLOT_I + 2) * sizeof(int), stream);
    hipMemsetAsync(sst_raw, 0xFF, (size_t)(NSLOT_T + 2) * sizeof(int), stream);

    blockscan_kernel<<<500, 256, 0, stream>>>(deg_i, offp_i, bsum);
    bscan_kernel<<<1, 512, 0, stream>>>(bsum, bexc_i, 500);
    hipMemsetAsync(cursor, 0, NTOT * sizeof(int), stream);
    fill_kernel<<<(2 * E_INT + 255) / 256, 256, 0, stream>>>(
        ni_int, bi_int, E_INT, offp_i, bexc_i, cursor, el_i, ssi);

    blockscan_kernel<<<500, 256, 0, stream>>>(deg_t, offp_t, bsum);
    bscan_kernel<<<1, 512, 0, stream>>>(bsum, bexc_t, 500);
    hipMemsetAsync(cursor, 0, NTOT * sizeof(int), stream);
    fill_kernel<<<(2 * E_TMP + 255) / 256, 256, 0, stream>>>(
        ni_tmp, bi_tmp, E_TMP, offp_t, bexc_t, cursor, el_t, sst);

    hipMemsetAsync(strc_i, 0, sizeof(int), stream);
    hipMemsetAsync(strc_t, 0, sizeof(int), stream);
    straddle_kernel<<<(NBLK_I + 255) / 256, 256, 0, stream>>>(ssi, NBLK_I, str_i, strc_i);
    straddle_kernel<<<(NBLK_T + 255) / 256, 256, 0, stream>>>(sst, NBLK_T, str_t, strc_t);

    pack_gateB_kernel<<<512, 256, 0, stream>>>(giWx, giWh, BgiH, BgiL);
    pack_gateB_kernel<<<512, 256, 0, stream>>>(gtWx, gtWh, BgtH, BgtL);
    pack_preB_kernel<<<64, 256, 0, stream>>>(mWin, BpH, BpL);

    node_pre_kernel<<<NTOT / 256, 256, 0, stream>>>(B0, mWin, mbin, B1);

    // rotation: X=h, Y=p, Z=free
    float* X = B0; float* Y = B1; float* Z = B2;
    for (int ph = 0; ph < 4; ++ph) {
        const bool isInt = (ph % 2 == 0);
        if (isInt) {
            zero_rows_kernel<<<NBLK_I, 64, 0, stream>>>(str_i, strc_i, Z);
            edge_mlp_kernel3<<<NBLK_I, EBLK, 0, stream>>>(
                ni_int, bi_int, E_INT, el_i, ssi, Y,
                mWhid, mbhid, mWout, mbout, Z);
            gru_mfma_kernel<<<NTOT / 64, 512, 0, stream>>>(
                X, Z, deg_i, BgiH, BgiL, gibi, gibr, BpH, BpL, mbin, Y);
        } else {
            zero_rows_kernel<<<NBLK_T, 64, 0, stream>>>(str_t, strc_t, Z);
            edge_mlp_kernel3<<<NBLK_T, EBLK, 0, stream>>>(
                ni_tmp, bi_tmp, E_TMP, el_t, sst, Y,
                mWhid, mbhid, mWout, mbout, Z);
            gru_mfma_kernel<<<NTOT / 64, 512, 0, stream>>>(
                X, Z, deg_t, BgtH, BgtL, gtbi, gtbr, BpH, BpL, mbin, Y);
        }
        float* oldX = X;  X = Y;  Y = Z;  Z = oldX;
    }

    readout_kernel<<<500, 64, 0, stream>>>(
        X, roWin, robin, roWhid, robhid, roWout, robout, out);
}

// Round 2
// 2498.328 us; speedup vs baseline: 1.5985x; 1.4293x over previous
//
#include <hip/hip_runtime.h>
#include <math.h>

// MPNN on MI355X. R21 = R20 + MFMA-ized edge MLP.
// edge_mlp_kernel3 (fp32 GEMV, 33% VALUBusy, MfmaUtil 0, 4x ~560/275us)
// replaced by edge_mlp_mfma: same bf16 hi/lo 3-term split as the
// R20-validated GRU path, same fragment maps (A: lane=(m&15)+16*g,
// k=kt*32+(l>>4)*8+j; C/D: col=lane&15, row=(lane>>4)*4+reg).
// Key structure: 512 thr / 128 slots per block; wave w owns m-tile w and
// stages EXACTLY the LDS A-frag segments it later reads (lane2==lane,
// contiguous b128, conflict-free) -> no barriers from staging through all
// 4 layers; inter-layer activation transpose via wave-private LDS
// (RAW-in-order per wave). Segmented reduction = R19's validated
// runSeg/straddle logic widened to 128 cols, one scat round per wave.
// gelu in edge kernel only: A&S 7.1.26 rational erf (|err|<=1.5e-7,
// ~15 instrs vs ~65 for libm erff) -- 102M gelus/dispatch was the VALU
// floor. erff kept elsewhere (cold paths).
// GRU/node_pre MFMA path, CSR machinery, rotation: unchanged from R20.

#define DDIM 128
#define NTOT 128000
#define HBYTES 65536000ULL   // 128000*128*4
#define EBLK 128

typedef unsigned short u16;
using f32x4 = __attribute__((ext_vector_type(4))) float;
using s16x8 = __attribute__((ext_vector_type(8))) short;

__device__ __forceinline__ float gelu_exact(float x) {
    return 0.5f * x * (1.0f + erff(x * 0.70710678118654752440f));
}
// A&S 7.1.26 erf, |abs err| <= 1.5e-7; gelu err <= ~1e-6 (budget 6.35e-4).
__device__ __forceinline__ float gelu_fast(float x) {
    const float ax = fabsf(x) * 0.70710678118654752440f;
    const float t  = 1.0f / (1.0f + 0.3275911f * ax);
    const float poly = t * (0.254829592f + t * (-0.284496736f +
                       t * (1.421413741f + t * (-1.453152027f +
                       t * 1.061405429f))));
    const float e = __expf(-ax * ax);
    const float erfax = 1.0f - poly * e;
    const float erfv = copysignf(erfax, x);
    return 0.5f * x * (1.0f + erfv);
}
__device__ __forceinline__ float sigmoidf_(float x) {
    return 1.0f / (1.0f + expf(-x));
}
__device__ __forceinline__ u16 f2bf(float x) {            // RNE f32->bf16
    unsigned u = __float_as_uint(x);
    u += 0x7fffu + ((u >> 16) & 1u);
    return (u16)(u >> 16);
}
__device__ __forceinline__ float bf2f(u16 h) {
    return __uint_as_float(((unsigned)h) << 16);
}

__global__ __launch_bounds__(256) void embed_kernel(
    const int* __restrict__ inp, const float* __restrict__ table,
    float* __restrict__ h)
{
    int gid = blockIdx.x * 256 + threadIdx.x;
    if (gid >= NTOT * 32) return;
    int row = gid >> 5;
    int q   = gid & 31;
    int b   = row / 4000;
    int n   = (row % 4000) % 1000;
    int e   = inp[b * 1000 + n];
    ((float4*)h)[gid] = ((const float4*)table)[e * 32 + q];
}

__global__ __launch_bounds__(256) void hist_kernel(
    const int* __restrict__ ni, const int* __restrict__ bi, int E,
    int* __restrict__ deg)
{
    int g = blockIdx.x * 256 + threadIdx.x;
    if (g < E)          atomicAdd(&deg[bi[g]], 1);
    else if (g < 2 * E) atomicAdd(&deg[ni[g - E]], 1);
}

__global__ __launch_bounds__(256) void blockscan_kernel(
    const int* __restrict__ deg, int* __restrict__ offp, int* __restrict__ bsum)
{
    __shared__ int s[256];
    int tid = threadIdx.x;
    int i = blockIdx.x * 256 + tid;
    int v = deg[i];
    s[tid] = v;
    __syncthreads();
    for (int off = 1; off < 256; off <<= 1) {
        int t = (tid >= off) ? s[tid - off] : 0;
        __syncthreads();
        s[tid] += t;
        __syncthreads();
    }
    offp[i] = s[tid] - v;
    if (tid == 255) bsum[blockIdx.x] = s[255];
}

__global__ __launch_bounds__(512) void bscan_kernel(
    const int* __restrict__ bsum, int* __restrict__ bexc, int nb)
{
    __shared__ int s[512];
    int t = threadIdx.x;
    int v = (t < nb) ? bsum[t] : 0;
    s[t] = v;
    __syncthreads();
    for (int off = 1; off < 512; off <<= 1) {
        int u = (t >= off) ? s[t - off] : 0;
        __syncthreads();
        s[t] += u;
        __syncthreads();
    }
    if (t < nb) bexc[t] = s[t] - v;
}

__global__ __launch_bounds__(256) void fill_kernel(
    const int* __restrict__ ni, const int* __restrict__ bi, int E,
    const int* __restrict__ offp, const int* __restrict__ bexc,
    int* __restrict__ cursor, int* __restrict__ elist, int* __restrict__ slotseg)
{
    int g = blockIdx.x * 256 + threadIdx.x;
    if (g >= 2 * E) return;
    int seg = (g < E) ? bi[g] : ni[g - E];
    int pos = atomicAdd(&cursor[seg], 1);
    int slot = offp[seg] + bexc[seg >> 8] + pos;
    elist[slot] = g;
    slotseg[slot] = seg;
}

// Segments straddling an EBLK boundary (the only atomicAdd targets).
__global__ __launch_bounds__(256) void straddle_kernel(
    const int* __restrict__ slotseg, int nblocks,
    int* __restrict__ list, int* __restrict__ count)
{
    int b = blockIdx.x * 256 + threadIdx.x + 1;
    if (b >= nblocks) return;
    int s = slotseg[b * EBLK];
    if (s >= 0 && slotseg[b * EBLK - 1] == s) {
        int pos = atomicAdd(count, 1);
        list[pos] = s;
    }
}

__global__ __launch_bounds__(64) void zero_rows_kernel(
    const int* __restrict__ list, const int* __restrict__ count,
    float* __restrict__ sbuf)
{
    int i = blockIdx.x;
    if (i >= *count) return;
    int seg = list[i];
    float4* row = (float4*)(sbuf + (size_t)seg * DDIM);
    if (threadIdx.x < 32) row[threadIdx.x] = make_float4(0.f, 0.f, 0.f, 0.f);
}

// ---------------------------------------------------------------------------
// B-fragment packers (run once per launch). Shared frag map:
// lane l, elem j -> k = kt*32+(l>>4)*8+j, n = nt*16+(l&15).
// ---------------------------------------------------------------------------
__global__ __launch_bounds__(256) void pack_gateB_kernel(
    const float* __restrict__ Wx, const float* __restrict__ Wh,
    u16* __restrict__ BH, u16* __restrict__ BL)
{
    int idx = blockIdx.x * 256 + threadIdx.x;   // 131072 total
    if (idx >= 131072) return;
    int j    = idx & 7;
    int lane = (idx >> 3) & 63;
    int ntG  = (idx >> 9) & 31;
    int ktG  = idx >> 14;                        // 0..7
    int k = ktG * 32 + (lane >> 4) * 8 + j;      // 0..255
    int n = ntG * 16 + (lane & 15);              // 0..511
    int g = n >> 7, jj = n & 127;
    float v;
    if (g == 0)      v = (k < 128) ? Wx[k * 384 + jj]       : Wh[(k - 128) * 384 + jj];
    else if (g == 1) v = (k < 128) ? Wx[k * 384 + 128 + jj] : Wh[(k - 128) * 384 + 128 + jj];
    else if (g == 2) v = (k < 128) ? Wx[k * 384 + 256 + jj] : 0.0f;
    else             v = (k < 128) ? 0.0f                   : Wh[(k - 128) * 384 + 256 + jj];
    u16 hb = f2bf(v);
    BH[idx] = hb;
    BL[idx] = f2bf(v - bf2f(hb));
}

// node_pre B: [K=128][N=128], n<64 -> Win rows 0..127, n>=64 -> rows 128..255.
__global__ __launch_bounds__(256) void pack_preB_kernel(
    const float* __restrict__ Win, u16* __restrict__ BH, u16* __restrict__ BL)
{
    int idx = blockIdx.x * 256 + threadIdx.x;   // 16384 total
    if (idx >= 16384) return;
    int j    = idx & 7;
    int lane = (idx >> 3) & 63;
    int nt2  = (idx >> 9) & 7;
    int kt2  = idx >> 12;                        // 0..3
    int k = kt2 * 32 + (lane >> 4) * 8 + j;      // 0..127
    int n = nt2 * 16 + (lane & 15);              // 0..127
    float v = (n < 64) ? Win[k * 64 + n] : Win[(128 + k) * 64 + (n - 64)];
    u16 hb = f2bf(v);
    BH[idx] = hb;
    BL[idx] = f2bf(v - bf2f(hb));
}

// Edge-MLP hidden B: 3 layers x [K=64][N=64]. idx=(L*8+kt*4+nt)*512+lane*8+j.
__global__ __launch_bounds__(256) void pack_hidB_kernel(
    const float* __restrict__ Whid, u16* __restrict__ BH, u16* __restrict__ BL)
{
    int idx = blockIdx.x * 256 + threadIdx.x;   // 12288 total
    if (idx >= 12288) return;
    int j    = idx & 7;
    int lane = (idx >> 3) & 63;
    int nt   = (idx >> 9) & 3;
    int kt   = (idx >> 11) & 1;
    int L    = idx >> 12;
    int k = kt * 32 + (lane >> 4) * 8 + j;       // 0..63
    int n = nt * 16 + (lane & 15);               // 0..63
    float v = Whid[L * 4096 + k * 64 + n];
    u16 hb = f2bf(v);
    BH[idx] = hb;
    BL[idx] = f2bf(v - bf2f(hb));
}

// Edge-MLP out B: [K=64][N=128]. idx=(kt*8+nt)*512+lane*8+j.
__global__ __launch_bounds__(256) void pack_outB_kernel(
    const float* __restrict__ Wout, u16* __restrict__ BH, u16* __restrict__ BL)
{
    int idx = blockIdx.x * 256 + threadIdx.x;   // 8192 total
    if (idx >= 8192) return;
    int j    = idx & 7;
    int lane = (idx >> 3) & 63;
    int nt   = (idx >> 9) & 7;
    int kt   = idx >> 12;                        // 0..1
    int k = kt * 32 + (lane >> 4) * 8 + j;       // 0..63
    int n = nt * 16 + (lane & 15);               // 0..127
    float v = Wout[k * 128 + n];
    u16 hb = f2bf(v);
    BH[idx] = hb;
    BL[idx] = f2bf(v - bf2f(hb));
}

// Initial p only: p[v][0:64)=Wtop@h[v]+bin, p[v][64:128)=Wbot@h[v].
__global__ __launch_bounds__(256) void node_pre_kernel(
    const float* __restrict__ h, const float* __restrict__ Win,
    const float* __restrict__ bin, float* __restrict__ p)
{
    const int node = blockIdx.x * 256 + threadIdx.x;
    const float4* h4 = (const float4*)(h + (size_t)node * DDIM);
    float* prow = p + (size_t)node * DDIM;

    for (int c = 0; c < 4; ++c) {
        const int top   = (c < 2) ? 1 : 0;
        const int j0    = (c & 1) * 32;
        const int kbase = top ? 0 : 128;
        float acc[32];
        #pragma unroll
        for (int j = 0; j < 32; ++j) acc[j] = top ? bin[j0 + j] : 0.0f;
        for (int k4 = 0; k4 < 32; ++k4) {
            float4 hv = h4[k4];
            #pragma unroll
            for (int kk = 0; kk < 4; ++kk) {
                const float hk = (&hv.x)[kk];
                const float* wr = Win + (size_t)(kbase + k4 * 4 + kk) * 64 + j0;
                #pragma unroll
                for (int j = 0; j < 32; ++j) acc[j] = fmaf(hk, wr[j], acc[j]);
            }
        }
        float* dst = prow + (top ? 0 : 64) + j0;
        #pragma unroll
        for (int q = 0; q < 8; ++q)
            ((float4*)dst)[q] = make_float4(acc[q*4], acc[q*4+1],
                                            acc[q*4+2], acc[q*4+3]);
    }
}

// ---------------------------------------------------------------------------
// MFMA edge MLP. 512 threads / 128 slots per block. Wave w owns m-tile w
// (16 slots). Staging lane2==lane => wave-private A-frag segments, no
// barriers until the reduction. Layers: 3x [128x64]@[64x64] gelu, then
// [128x64]@[64x128]; all bf16 hi/lo 3-term MFMA, bias via C-init.
// Reduction: 8 rounds (wave b dumps its C tile to scat), threads 0..127
// run R19's runSeg walk over 16 rows each round; straddle rows atomicAdd.
// ---------------------------------------------------------------------------
__global__ __launch_bounds__(512) void edge_mlp_mfma(
    const int* __restrict__ ni, const int* __restrict__ bi, int E,
    const int* __restrict__ elist, const int* __restrict__ slotseg,
    const float* __restrict__ p,
    const u16* __restrict__ BhH, const u16* __restrict__ BhL,
    const float* __restrict__ bhid,
    const u16* __restrict__ BoH, const u16* __restrict__ BoL,
    const float* __restrict__ bout,
    float* __restrict__ sbuf)
{
    __shared__ short smA[16384];      // hi [0,8192), lo [8192,16384)
    __shared__ float scat[16 * 132];
    __shared__ int   segLDS[EBLK];
    __shared__ int   segedge[2];

    const int tid  = threadIdx.x;
    const int lane = tid & 63;
    const int w    = tid >> 6;        // wave = m-tile
    const int s0   = blockIdx.x * EBLK;

    if (tid < 128) segLDS[tid] = slotseg[s0 + tid];
    if (tid == 0) segedge[0] = slotseg[s0 - 1];
    if (tid == 1) segedge[1] = slotseg[s0 + EBLK];

    // ---- staging: thread covers slot m=(tid&15)+16*w, k-group gg=(tid>>4)&3
    {
        const int m  = (tid & 15) | (w << 4);
        const int gg = (tid >> 4) & 3;
        const int slot = s0 + m;
        const int g = elist[slot];
        int first, second;
        if (g < E) { first = ni[g];     second = bi[g];     }
        else       { first = bi[g - E]; second = ni[g - E]; }
        #pragma unroll
        for (int kt = 0; kt < 2; ++kt) {
            const int k0 = kt * 32 + gg * 8;
            const float4* pa = (const float4*)(p + (size_t)first  * DDIM + k0);
            const float4* pb = (const float4*)(p + (size_t)second * DDIM + 64 + k0);
            const float4 a0 = pa[0], a1 = pa[1], b0 = pb[0], b1 = pb[1];
            float x[8] = { a0.x + b0.x, a0.y + b0.y, a0.z + b0.z, a0.w + b0.w,
                           a1.x + b1.x, a1.y + b1.y, a1.z + b1.z, a1.w + b1.w };
            s16x8 hi8, lo8;
            #pragma unroll
            for (int j = 0; j < 8; ++j) {
                const float v = gelu_fast(x[j]);
                u16 hb = f2bf(v);
                hi8[j] = (short)hb;
                lo8[j] = (short)f2bf(v - bf2f(hb));
            }
            const int off = (kt * 8 + w) * 512 + lane * 8;
            *(s16x8*)(smA + off)        = hi8;
            *(s16x8*)(smA + 8192 + off) = lo8;
        }
    }
    // no barrier: wave w staged exactly the segments (kt*8+w) it reads.

    // ---- 3 hidden layers ----
    const int mt = w;
    for (int L = 0; L < 3; ++L) {
        f32x4 acc[4];
        #pragma unroll
        for (int nt = 0; nt < 4; ++nt) {
            const float bv = bhid[L * 64 + nt * 16 + (lane & 15)];
            acc[nt] = (f32x4){bv, bv, bv, bv};
        }
        #pragma unroll
        for (int kt = 0; kt < 2; ++kt) {
            const s16x8 aH = *(const s16x8*)(smA + (kt * 8 + mt) * 512 + lane * 8);
            const s16x8 aL = *(const s16x8*)(smA + 8192 + (kt * 8 + mt) * 512 + lane * 8);
            #pragma unroll
            for (int nt = 0; nt < 4; ++nt) {
                const int bidx = (L * 8 + kt * 4 + nt) * 64 + lane;
                const s16x8 bH = ((const s16x8*)BhH)[bidx];
                const s16x8 bL = ((const s16x8*)BhL)[bidx];
                acc[nt] = __builtin_amdgcn_mfma_f32_16x16x32_bf16(aH, bH, acc[nt], 0, 0, 0);
                acc[nt] = __builtin_amdgcn_mfma_f32_16x16x32_bf16(aH, bL, acc[nt], 0, 0, 0);
                acc[nt] = __builtin_amdgcn_mfma_f32_16x16x32_bf16(aL, bH, acc[nt], 0, 0, 0);
            }
        }
        // epilogue: gelu + scatter back into own A-frag segments (k = col).
        #pragma unroll
        for (int nt = 0; nt < 4; ++nt) {
            #pragma unroll
            for (int r = 0; r < 4; ++r) {
                const float v = gelu_fast(acc[nt][r]);
                const int ml  = (lane >> 4) * 4 + r;        // row within tile
                const int k   = nt * 16 + (lane & 15);      // col -> next k
                const int kt2 = k >> 5, gg = (k >> 3) & 3, j = k & 7;
                const int off = (kt2 * 8 + mt) * 512 + (ml + 16 * gg) * 8 + j;
                u16 hb = f2bf(v);
                smA[off]        = (short)hb;
                smA[8192 + off] = (short)f2bf(v - bf2f(hb));
            }
        }
    }

    // ---- out layer: N=128 ----
    f32x4 acc2[8];
    #pragma unroll
    for (int nt = 0; nt < 8; ++nt) {
        const float bv = bout[nt * 16 + (lane & 15)];
        acc2[nt] = (f32x4){bv, bv, bv, bv};
    }
    #pragma unroll
    for (int kt = 0; kt < 2; ++kt) {
        const s16x8 aH = *(const s16x8*)(smA + (kt * 8 + mt) * 512 + lane * 8);
        const s16x8 aL = *(const s16x8*)(smA + 8192 + (kt * 8 + mt) * 512 + lane * 8);
        #pragma unroll
        for (int nt = 0; nt < 8; ++nt) {
            const int bidx = (kt * 8 + nt) * 64 + lane;
            const s16x8 bH = ((const s16x8*)BoH)[bidx];
            const s16x8 bL = ((const s16x8*)BoL)[bidx];
            acc2[nt] = __builtin_amdgcn_mfma_f32_16x16x32_bf16(aH, bH, acc2[nt], 0, 0, 0);
            acc2[nt] = __builtin_amdgcn_mfma_f32_16x16x32_bf16(aH, bL, acc2[nt], 0, 0, 0);
            acc2[nt] = __builtin_amdgcn_mfma_f32_16x16x32_bf16(aL, bH, acc2[nt], 0, 0, 0);
        }
    }

    // ---- fused segmented reduction (R19 semantics, 128 cols) ----
    int   runSeg = -2;
    float runacc = 0.0f;
    bool  leftC  = true;
    for (int b = 0; b < 8; ++b) {
        __syncthreads();
        if (w == b) {
            #pragma unroll
            for (int nt = 0; nt < 8; ++nt)
                #pragma unroll
                for (int r = 0; r < 4; ++r)
                    scat[((lane >> 4) * 4 + r) * 132 + nt * 16 + (lane & 15)] = acc2[nt][r];
        }
        __syncthreads();
        if (tid < 128) {
            for (int r = 0; r < 16; ++r) {
                const int rowi = b * 16 + r;
                const int sg = segLDS[rowi];
                const float v = scat[r * 132 + tid];
                if (sg != runSeg) {
                    if (runSeg >= 0) {
                        float* pp = sbuf + (size_t)runSeg * DDIM + tid;
                        if (leftC) *pp = runacc;
                        else       atomicAdd(pp, runacc);
                    }
                    runSeg = sg;
                    runacc = v;
                    leftC  = (rowi == 0) ? (segedge[0] != sg) : true;
                } else {
                    runacc += v;
                }
            }
        }
    }
    if (tid < 128 && runSeg >= 0) {
        const bool rightC = (segedge[1] != runSeg);
        float* pp = sbuf + (size_t)runSeg * DDIM + tid;
        if (leftC && rightC) *pp = runacc;
        else                 atomicAdd(pp, runacc);
    }
}

// ---------------------------------------------------------------------------
// MFMA GRU + fused node_pre (R20, validated).
// ---------------------------------------------------------------------------
__global__ __launch_bounds__(512) void gru_mfma_kernel(
    const float* __restrict__ h, float* __restrict__ msum,
    const int* __restrict__ deg,
    const u16* __restrict__ BgH, const u16* __restrict__ BgL,
    const float* __restrict__ bi_, const float* __restrict__ br_,
    const u16* __restrict__ BpH, const u16* __restrict__ BpL,
    const float* __restrict__ binp,
    float* __restrict__ hout)
{
    __shared__ short sm[32768];   // 64 KB: [hi 16384][lo 16384] shorts
    const int tid  = threadIdx.x;
    const int lane = tid & 63;
    const int w    = tid >> 6;
    const int mt   = w >> 1;
    const int jg   = w & 1;
    const int nbase = blockIdx.x * 64;

    // ---- Phase 1: stage A fragments (all K=256 at once) ----
    {
        const int mS = tid >> 3, g8 = tid & 7;
        const int nodeS = nbase + mS;
        const int dg = deg[nodeS];
        const float ci = (dg > 0) ? (1.0f / (float)dg) : 0.0f;
        #pragma unroll
        for (int c = 0; c < 4; ++c) {
            const float* src = (c < 2)
                ? (msum + (size_t)nodeS * DDIM + c * 64 + g8 * 8)
                : (h    + (size_t)nodeS * DDIM + (c - 2) * 64 + g8 * 8);
            const float4 v0 = ((const float4*)src)[0];
            const float4 v1 = ((const float4*)src)[1];
            const float sc = (c < 2) ? ci : 1.0f;
            float xv[8] = { v0.x * sc, v0.y * sc, v0.z * sc, v0.w * sc,
                            v1.x * sc, v1.y * sc, v1.z * sc, v1.w * sc };
            s16x8 hi8, lo8;
            #pragma unroll
            for (int i = 0; i < 8; ++i) {
                u16 hb = f2bf(xv[i]);
                hi8[i] = (short)hb;
                lo8[i] = (short)f2bf(xv[i] - bf2f(hb));
            }
            const int ktG   = c * 2 + (g8 >> 2);
            const int laneS = (mS & 15) + 16 * (g8 & 3);
            const int off   = (ktG * 4 + (mS >> 4)) * 512 + laneS * 8;
            *(s16x8*)(sm + off)         = hi8;
            *(s16x8*)(sm + off + 16384) = lo8;
        }
    }
    __syncthreads();

    // ---- Phase 2: gate GEMM ----
    f32x4 acc[4][4];
    #pragma unroll
    for (int g = 0; g < 4; ++g)
        #pragma unroll
        for (int t4 = 0; t4 < 4; ++t4)
            acc[g][t4] = (f32x4){0.f, 0.f, 0.f, 0.f};

    const s16x8* Bh8 = (const s16x8*)BgH;
    const s16x8* Bl8 = (const s16x8*)BgL;
    #pragma unroll
    for (int ktG = 0; ktG < 8; ++ktG) {
        const s16x8 aH = *(const s16x8*)(sm + (ktG * 4 + mt) * 512 + lane * 8);
        const s16x8 aL = *(const s16x8*)(sm + 16384 + (ktG * 4 + mt) * 512 + lane * 8);
        #pragma unroll
        for (int g = 0; g < 4; ++g) {
            #pragma unroll
            for (int t4 = 0; t4 < 4; ++t4) {
                const int idx = (ktG * 32 + g * 8 + jg * 4 + t4) * 64 + lane;
                const s16x8 bH = Bh8[idx];
                const s16x8 bL = Bl8[idx];
                acc[g][t4] = __builtin_amdgcn_mfma_f32_16x16x32_bf16(aH, bH, acc[g][t4], 0, 0, 0);
                acc[g][t4] = __builtin_amdgcn_mfma_f32_16x16x32_bf16(aH, bL, acc[g][t4], 0, 0, 0);
                acc[g][t4] = __builtin_amdgcn_mfma_f32_16x16x32_bf16(aL, bH, acc[g][t4], 0, 0, 0);
            }
        }
    }

    // ---- Phase 3: gate epilogue (lane-local) -> h' ----
    float hn[4][4];
    #pragma unroll
    for (int t4 = 0; t4 < 4; ++t4) {
        const int j = jg * 64 + t4 * 16 + (lane & 15);
        const float b_az = bi_[j]       + br_[j];
        const float b_ar = bi_[128 + j] + br_[128 + j];
        const float b_xh = bi_[256 + j];
        const float b_hh = br_[256 + j];
        #pragma unroll
        for (int r = 0; r < 4; ++r) {
            const int m = mt * 16 + (lane >> 4) * 4 + r;
            const float az = acc[0][t4][r] + b_az;
            const float ar = acc[1][t4][r] + b_ar;
            const float xh = acc[2][t4][r] + b_xh;
            const float hh = acc[3][t4][r] + b_hh;
            const float z    = sigmoidf_(az);
            const float rr   = sigmoidf_(ar);
            const float cand = tanhf(xh + rr * hh);
            const float hv   = h[(size_t)(nbase + m) * DDIM + j];
            const float v    = z * hv + (1.0f - z) * cand;
            hout[(size_t)(nbase + m) * DDIM + j] = v;
            hn[t4][r] = v;
        }
    }

    __syncthreads();   // gate GEMM LDS reads done everywhere; reuse sm

    // scatter h' into node_pre A-frag layout (k = j, same frag map)
    #pragma unroll
    for (int t4 = 0; t4 < 4; ++t4) {
        #pragma unroll
        for (int r = 0; r < 4; ++r) {
            const int m  = mt * 16 + (lane >> 4) * 4 + r;
            const int j  = jg * 64 + t4 * 16 + (lane & 15);
            const int kt2 = j >> 5, gg = (j >> 3) & 3, jj = j & 7;
            const int lane2 = (m & 15) + 16 * gg;
            const int off = (kt2 * 4 + mt) * 512 + lane2 * 8 + jj;
            const float v = hn[t4][r];
            u16 hb = f2bf(v);
            sm[off]        = (short)hb;
            sm[off + 8192] = (short)f2bf(v - bf2f(hb));
        }
    }
    __syncthreads();

    // ---- Phase 4: node_pre GEMM -> p (into msum) ----
    f32x4 acc2[4];
    #pragma unroll
    for (int t4 = 0; t4 < 4; ++t4) acc2[t4] = (f32x4){0.f, 0.f, 0.f, 0.f};

    const s16x8* Ph8 = (const s16x8*)BpH;
    const s16x8* Pl8 = (const s16x8*)BpL;
    #pragma unroll
    for (int kt2 = 0; kt2 < 4; ++kt2) {
        const s16x8 aH = *(const s16x8*)(sm + (kt2 * 4 + mt) * 512 + lane * 8);
        const s16x8 aL = *(const s16x8*)(sm + 8192 + (kt2 * 4 + mt) * 512 + lane * 8);
        #pragma unroll
        for (int t4 = 0; t4 < 4; ++t4) {
            const int idx = (kt2 * 8 + jg * 4 + t4) * 64 + lane;
            const s16x8 bH = Ph8[idx];
            const s16x8 bL = Pl8[idx];
            acc2[t4] = __builtin_amdgcn_mfma_f32_16x16x32_bf16(aH, bH, acc2[t4], 0, 0, 0);
            acc2[t4] = __builtin_amdgcn_mfma_f32_16x16x32_bf16(aH, bL, acc2[t4], 0, 0, 0);
            acc2[t4] = __builtin_amdgcn_mfma_f32_16x16x32_bf16(aL, bH, acc2[t4], 0, 0, 0);
        }
    }
    #pragma unroll
    for (int t4 = 0; t4 < 4; ++t4) {
        const int n = jg * 64 + t4 * 16 + (lane & 15);
        const float badd = (n < 64) ? binp[n] : 0.0f;
        #pragma unroll
        for (int r = 0; r < 4; ++r) {
            const int m = mt * 16 + (lane >> 4) * 4 + r;
            msum[(size_t)(nbase + m) * DDIM + n] = acc2[t4][r] + badd;
        }
    }
}

// Readout: block=64, LDS activation slices, scalar weights.
__global__ __launch_bounds__(64) void readout_kernel(
    const float* __restrict__ h,
    const float* __restrict__ Win,  const float* __restrict__ bin,
    const float* __restrict__ Whid, const float* __restrict__ bhid,
    const float* __restrict__ Wout, const float* __restrict__ bout,
    float* __restrict__ out)
{
    __shared__ float xs[64 * 65];
    const int tid = threadIdx.x;
    const int row = blockIdx.x * 64 + tid;
    const int b = row / 1000, n = row % 1000;
    const float4* xrow = (const float4*)(h + ((size_t)b * 4000 + n) * DDIM);

    {
        float acc[64];
        #pragma unroll
        for (int j = 0; j < 64; ++j) acc[j] = bin[j];
        #pragma unroll 2
        for (int k4 = 0; k4 < 32; ++k4) {
            float4 xv = xrow[k4];
            #pragma unroll
            for (int kk = 0; kk < 4; ++kk) {
                const float xk = (&xv.x)[kk];
                const float* wr = Win + (size_t)(k4 * 4 + kk) * 64;
                #pragma unroll
                for (int j = 0; j < 64; ++j) acc[j] = fmaf(xk, wr[j], acc[j]);
            }
        }
        #pragma unroll
        for (int j = 0; j < 64; ++j) xs[tid * 65 + j] = gelu_exact(acc[j]);
    }

    for (int L = 0; L < 3; ++L) {
        float acc[64];
        #pragma unroll
        for (int j = 0; j < 64; ++j) acc[j] = bhid[L * 64 + j];
        #pragma unroll 4
        for (int k = 0; k < 64; ++k) {
            const float xk = xs[tid * 65 + k];
            const float* wr = Whid + (size_t)L * 4096 + (size_t)k * 64;
            #pragma unroll
            for (int j = 0; j < 64; ++j) acc[j] = fmaf(xk, wr[j], acc[j]);
        }
        #pragma unroll
        for (int j = 0; j < 64; ++j) xs[tid * 65 + j] = gelu_exact(acc[j]);
    }

    float acc[10];
    #pragma unroll
    for (int pj = 0; pj < 10; ++pj) acc[pj] = bout[pj];
    #pragma unroll 4
    for (int k = 0; k < 64; ++k) {
        const float xk = xs[tid * 65 + k];
        const float* wr = Wout + k * 10;
        #pragma unroll
        for (int pj = 0; pj < 10; ++pj) acc[pj] = fmaf(xk, wr[pj], acc[pj]);
    }
    #pragma unroll
    for (int pj = 0; pj < 10; ++pj) out[(size_t)row * 10 + pj] = acc[pj];
}

extern "C" void kernel_launch(void* const* d_in, const int* in_sizes, int n_in,
                              void* d_out, int out_size, void* d_ws, size_t ws_size,
                              hipStream_t stream) {
    const int*   node_inputs = (const int*)d_in[0];
    const int*   ni_int = (const int*)d_in[1];
    const int*   bi_int = (const int*)d_in[2];
    const int*   ni_tmp = (const int*)d_in[3];
    const int*   bi_tmp = (const int*)d_in[4];
    const float* embed  = (const float*)d_in[5];
    const float* mWin   = (const float*)d_in[6];
    const float* mbin   = (const float*)d_in[7];
    const float* mWhid  = (const float*)d_in[8];
    const float* mbhid  = (const float*)d_in[9];
    const float* mWout  = (const float*)d_in[10];
    const float* mbout  = (const float*)d_in[11];
    const float* roWin  = (const float*)d_in[12];
    const float* robin  = (const float*)d_in[13];
    const float* roWhid = (const float*)d_in[14];
    const float* robhid = (const float*)d_in[15];
    const float* roWout = (const float*)d_in[16];
    const float* robout = (const float*)d_in[17];
    const float* giWx = (const float*)d_in[18];
    const float* giWh = (const float*)d_in[19];
    const float* gibi = (const float*)d_in[20];
    const float* gibr = (const float*)d_in[21];
    const float* gtWx = (const float*)d_in[22];
    const float* gtWh = (const float*)d_in[23];
    const float* gtbi = (const float*)d_in[24];
    const float* gtbr = (const float*)d_in[25];
    float* out = (float*)d_out;

    const int E_INT = 200000, E_TMP = 96000;
    const int NSLOT_I = 400000;   // 3125*128 exact
    const int NSLOT_T = 192000;   // 1500*128 exact
    const int NBLK_I = NSLOT_I / EBLK;
    const int NBLK_T = NSLOT_T / EBLK;

    char* ws = (char*)d_ws;
    float* B0 = (float*)(ws);
    float* B1 = (float*)(ws + HBYTES);
    float* B2 = (float*)(ws + 2 * HBYTES);
    char*  ib = ws + 3 * HBYTES;

    int* deg_i   = (int*)(ib);
    int* deg_t   = (int*)(ib + 512000);
    int* offp_i  = (int*)(ib + 1024000);
    int* offp_t  = (int*)(ib + 1536000);
    int* bexc_i  = (int*)(ib + 2048000);
    int* bexc_t  = (int*)(ib + 2052096);
    int* bsum    = (int*)(ib + 2056192);
    int* cursor  = (int*)(ib + 2060288);
    int* el_i    = (int*)(ib + 2572288);
    int* el_t    = (int*)(ib + 4172288);
    int* ssi_raw = (int*)(ib + 4940288);
    int* sst_raw = (int*)(ib + 6540296);
    int* str_i   = (int*)(ib + 8094784);
    int* str_t   = (int*)(ib + 8107384);
    int* strc_i  = (int*)(ib + 8113484);
    int* strc_t  = (int*)(ib + 8113488);
    // bf16-split B-fragment buffers
    char* fb = ib + 8114176;
    u16* BgiH = (u16*)(fb);
    u16* BgiL = (u16*)(fb +  262144);
    u16* BgtH = (u16*)(fb +  524288);
    u16* BgtL = (u16*)(fb +  786432);
    u16* BpH  = (u16*)(fb + 1048576);
    u16* BpL  = (u16*)(fb + 1081344);
    u16* EhH  = (u16*)(fb + 1114112);   // 3*4096 elems = 24576 B
    u16* EhL  = (u16*)(fb + 1138688);
    u16* EoH  = (u16*)(fb + 1163264);   // 8192 elems = 16384 B
    u16* EoL  = (u16*)(fb + 1179648);
    int* ssi = ssi_raw + 1;
    int* sst = sst_raw + 1;

    embed_kernel<<<16000, 256, 0, stream>>>(node_inputs, embed, B0);

    hipMemsetAsync(deg_i, 0, NTOT * sizeof(int), stream);
    hipMemsetAsync(deg_t, 0, NTOT * sizeof(int), stream);
    hist_kernel<<<(2 * E_INT + 255) / 256, 256, 0, stream>>>(ni_int, bi_int, E_INT, deg_i);
    hist_kernel<<<(2 * E_TMP + 255) / 256, 256, 0, stream>>>(ni_tmp, bi_tmp, E_TMP, deg_t);

    hipMemsetAsync(ssi_raw, 0xFF, (size_t)(NSLOT_I + 2) * sizeof(int), stream);
    hipMemsetAsync(sst_raw, 0xFF, (size_t)(NSLOT_T + 2) * sizeof(int), stream);

    blockscan_kernel<<<500, 256, 0, stream>>>(deg_i, offp_i, bsum);
    bscan_kernel<<<1, 512, 0, stream>>>(bsum, bexc_i, 500);
    hipMemsetAsync(cursor, 0, NTOT * sizeof(int), stream);
    fill_kernel<<<(2 * E_INT + 255) / 256, 256, 0, stream>>>(
        ni_int, bi_int, E_INT, offp_i, bexc_i, cursor, el_i, ssi);

    blockscan_kernel<<<500, 256, 0, stream>>>(deg_t, offp_t, bsum);
    bscan_kernel<<<1, 512, 0, stream>>>(bsum, bexc_t, 500);
    hipMemsetAsync(cursor, 0, NTOT * sizeof(int), stream);
    fill_kernel<<<(2 * E_TMP + 255) / 256, 256, 0, stream>>>(
        ni_tmp, bi_tmp, E_TMP, offp_t, bexc_t, cursor, el_t, sst);

    hipMemsetAsync(strc_i, 0, sizeof(int), stream);
    hipMemsetAsync(strc_t, 0, sizeof(int), stream);
    straddle_kernel<<<(NBLK_I + 255) / 256, 256, 0, stream>>>(ssi, NBLK_I, str_i, strc_i);
    straddle_kernel<<<(NBLK_T + 255) / 256, 256, 0, stream>>>(sst, NBLK_T, str_t, strc_t);

    pack_gateB_kernel<<<512, 256, 0, stream>>>(giWx, giWh, BgiH, BgiL);
    pack_gateB_kernel<<<512, 256, 0, stream>>>(gtWx, gtWh, BgtH, BgtL);
    pack_preB_kernel<<<64, 256, 0, stream>>>(mWin, BpH, BpL);
    pack_hidB_kernel<<<48, 256, 0, stream>>>(mWhid, EhH, EhL);
    pack_outB_kernel<<<32, 256, 0, stream>>>(mWout, EoH, EoL);

    node_pre_kernel<<<NTOT / 256, 256, 0, stream>>>(B0, mWin, mbin, B1);

    // rotation: X=h, Y=p, Z=free
    float* X = B0; float* Y = B1; float* Z = B2;
    for (int ph = 0; ph < 4; ++ph) {
        const bool isInt = (ph % 2 == 0);
        if (isInt) {
            zero_rows_kernel<<<NBLK_I, 64, 0, stream>>>(str_i, strc_i, Z);
            edge_mlp_mfma<<<NBLK_I, 512, 0, stream>>>(
                ni_int, bi_int, E_INT, el_i, ssi, Y,
                EhH, EhL, mbhid, EoH, EoL, mbout, Z);
            gru_mfma_kernel<<<NTOT / 64, 512, 0, stream>>>(
                X, Z, deg_i, BgiH, BgiL, gibi, gibr, BpH, BpL, mbin, Y);
        } else {
            zero_rows_kernel<<<NBLK_T, 64, 0, stream>>>(str_t, strc_t, Z);
            edge_mlp_mfma<<<NBLK_T, 512, 0, stream>>>(
                ni_tmp, bi_tmp, E_TMP, el_t, sst, Y,
                EhH, EhL, mbhid, EoH, EoL, mbout, Z);
            gru_mfma_kernel<<<NTOT / 64, 512, 0, stream>>>(
                X, Z, deg_t, BgtH, BgtL, gtbi, gtbr, BpH, BpL, mbin, Y);
        }
        float* oldX = X;  X = Y;  Y = Z;  Z = oldX;
    }

    readout_kernel<<<500, 64, 0, stream>>>(
        X, roWin, robin, roWhid, robhid, roWout, robout, out);
}

// Round 3
// 1725.336 us; speedup vs baseline: 2.3146x; 1.4480x over previous
//
#include <hip/hip_runtime.h>
#include <math.h>

// MPNN on MI355X. R22 = R21 + B-load-bound GRU fix.
// R21 counters: gru_mfma 4x417us, MfmaUtil 10.9, VALU 15.7, HBM 6.5% ->
// latency/L2-bound on B-fragment loads (every mt-wave re-streams 640KB of
// packed weights from L2: 5.1GB/dispatch). Changes:
//  (1) wave granularity 16->32 rows (block 256 thr / 4 waves, wave =
//      (jg, m-half)): each bH/bL load feeds 6 MFMAs (2 m-frags x 3 terms)
//      -> B traffic halved;
//  (2) xh/hh zero-block skip (xh: k<128 only, hh: k>=128 only) -> -25%
//      gate MFMAs and gate-B loads (exact: skipped blocks are zeros);
//  (3) staging remapped (mS=tid>>2,q=tid&3) -> LDS writes cover full 1KB
//      segments with 64 distinct lane slots = conflict-free (was 4-way,
//      8.19M conflict cycles);
//  (4) __launch_bounds__(256,2): LDS 64KB -> 2 blocks/CU, VGPR<=256.
// B traffic 5.1->1.8GB, MFMA floor 55->43us. Edge MLP / CSR / packers /
// rotation unchanged from R21 (harness-validated).

#define DDIM 128
#define NTOT 128000
#define HBYTES 65536000ULL   // 128000*128*4
#define EBLK 128

typedef unsigned short u16;
using f32x4 = __attribute__((ext_vector_type(4))) float;
using s16x8 = __attribute__((ext_vector_type(8))) short;

__device__ __forceinline__ float gelu_exact(float x) {
    return 0.5f * x * (1.0f + erff(x * 0.70710678118654752440f));
}
// A&S 7.1.26 erf, |abs err| <= 1.5e-7; gelu err <= ~1e-6 (budget 6.35e-4).
__device__ __forceinline__ float gelu_fast(float x) {
    const float ax = fabsf(x) * 0.70710678118654752440f;
    const float t  = 1.0f / (1.0f + 0.3275911f * ax);
    const float poly = t * (0.254829592f + t * (-0.284496736f +
                       t * (1.421413741f + t * (-1.453152027f +
                       t * 1.061405429f))));
    const float e = __expf(-ax * ax);
    const float erfax = 1.0f - poly * e;
    const float erfv = copysignf(erfax, x);
    return 0.5f * x * (1.0f + erfv);
}
__device__ __forceinline__ float sigmoidf_(float x) {
    return 1.0f / (1.0f + expf(-x));
}
__device__ __forceinline__ u16 f2bf(float x) {            // RNE f32->bf16
    unsigned u = __float_as_uint(x);
    u += 0x7fffu + ((u >> 16) & 1u);
    return (u16)(u >> 16);
}
__device__ __forceinline__ float bf2f(u16 h) {
    return __uint_as_float(((unsigned)h) << 16);
}

__global__ __launch_bounds__(256) void embed_kernel(
    const int* __restrict__ inp, const float* __restrict__ table,
    float* __restrict__ h)
{
    int gid = blockIdx.x * 256 + threadIdx.x;
    if (gid >= NTOT * 32) return;
    int row = gid >> 5;
    int q   = gid & 31;
    int b   = row / 4000;
    int n   = (row % 4000) % 1000;
    int e   = inp[b * 1000 + n];
    ((float4*)h)[gid] = ((const float4*)table)[e * 32 + q];
}

__global__ __launch_bounds__(256) void hist_kernel(
    const int* __restrict__ ni, const int* __restrict__ bi, int E,
    int* __restrict__ deg)
{
    int g = blockIdx.x * 256 + threadIdx.x;
    if (g < E)          atomicAdd(&deg[bi[g]], 1);
    else if (g < 2 * E) atomicAdd(&deg[ni[g - E]], 1);
}

__global__ __launch_bounds__(256) void blockscan_kernel(
    const int* __restrict__ deg, int* __restrict__ offp, int* __restrict__ bsum)
{
    __shared__ int s[256];
    int tid = threadIdx.x;
    int i = blockIdx.x * 256 + tid;
    int v = deg[i];
    s[tid] = v;
    __syncthreads();
    for (int off = 1; off < 256; off <<= 1) {
        int t = (tid >= off) ? s[tid - off] : 0;
        __syncthreads();
        s[tid] += t;
        __syncthreads();
    }
    offp[i] = s[tid] - v;
    if (tid == 255) bsum[blockIdx.x] = s[255];
}

__global__ __launch_bounds__(512) void bscan_kernel(
    const int* __restrict__ bsum, int* __restrict__ bexc, int nb)
{
    __shared__ int s[512];
    int t = threadIdx.x;
    int v = (t < nb) ? bsum[t] : 0;
    s[t] = v;
    __syncthreads();
    for (int off = 1; off < 512; off <<= 1) {
        int u = (t >= off) ? s[t - off] : 0;
        __syncthreads();
        s[t] += u;
        __syncthreads();
    }
    if (t < nb) bexc[t] = s[t] - v;
}

__global__ __launch_bounds__(256) void fill_kernel(
    const int* __restrict__ ni, const int* __restrict__ bi, int E,
    const int* __restrict__ offp, const int* __restrict__ bexc,
    int* __restrict__ cursor, int* __restrict__ elist, int* __restrict__ slotseg)
{
    int g = blockIdx.x * 256 + threadIdx.x;
    if (g >= 2 * E) return;
    int seg = (g < E) ? bi[g] : ni[g - E];
    int pos = atomicAdd(&cursor[seg], 1);
    int slot = offp[seg] + bexc[seg >> 8] + pos;
    elist[slot] = g;
    slotseg[slot] = seg;
}

// Segments straddling an EBLK boundary (the only atomicAdd targets).
__global__ __launch_bounds__(256) void straddle_kernel(
    const int* __restrict__ slotseg, int nblocks,
    int* __restrict__ list, int* __restrict__ count)
{
    int b = blockIdx.x * 256 + threadIdx.x + 1;
    if (b >= nblocks) return;
    int s = slotseg[b * EBLK];
    if (s >= 0 && slotseg[b * EBLK - 1] == s) {
        int pos = atomicAdd(count, 1);
        list[pos] = s;
    }
}

__global__ __launch_bounds__(64) void zero_rows_kernel(
    const int* __restrict__ list, const int* __restrict__ count,
    float* __restrict__ sbuf)
{
    int i = blockIdx.x;
    if (i >= *count) return;
    int seg = list[i];
    float4* row = (float4*)(sbuf + (size_t)seg * DDIM);
    if (threadIdx.x < 32) row[threadIdx.x] = make_float4(0.f, 0.f, 0.f, 0.f);
}

// ---------------------------------------------------------------------------
// B-fragment packers (run once per launch). Shared frag map:
// lane l, elem j -> k = kt*32+(l>>4)*8+j, n = nt*16+(l&15).
// ---------------------------------------------------------------------------
__global__ __launch_bounds__(256) void pack_gateB_kernel(
    const float* __restrict__ Wx, const float* __restrict__ Wh,
    u16* __restrict__ BH, u16* __restrict__ BL)
{
    int idx = blockIdx.x * 256 + threadIdx.x;   // 131072 total
    if (idx >= 131072) return;
    int j    = idx & 7;
    int lane = (idx >> 3) & 63;
    int ntG  = (idx >> 9) & 31;
    int ktG  = idx >> 14;                        // 0..7
    int k = ktG * 32 + (lane >> 4) * 8 + j;      // 0..255
    int n = ntG * 16 + (lane & 15);              // 0..511
    int g = n >> 7, jj = n & 127;
    float v;
    if (g == 0)      v = (k < 128) ? Wx[k * 384 + jj]       : Wh[(k - 128) * 384 + jj];
    else if (g == 1) v = (k < 128) ? Wx[k * 384 + 128 + jj] : Wh[(k - 128) * 384 + 128 + jj];
    else if (g == 2) v = (k < 128) ? Wx[k * 384 + 256 + jj] : 0.0f;
    else             v = (k < 128) ? 0.0f                   : Wh[(k - 128) * 384 + 256 + jj];
    u16 hb = f2bf(v);
    BH[idx] = hb;
    BL[idx] = f2bf(v - bf2f(hb));
}

// node_pre B: [K=128][N=128], n<64 -> Win rows 0..127, n>=64 -> rows 128..255.
__global__ __launch_bounds__(256) void pack_preB_kernel(
    const float* __restrict__ Win, u16* __restrict__ BH, u16* __restrict__ BL)
{
    int idx = blockIdx.x * 256 + threadIdx.x;   // 16384 total
    if (idx >= 16384) return;
    int j    = idx & 7;
    int lane = (idx >> 3) & 63;
    int nt2  = (idx >> 9) & 7;
    int kt2  = idx >> 12;                        // 0..3
    int k = kt2 * 32 + (lane >> 4) * 8 + j;      // 0..127
    int n = nt2 * 16 + (lane & 15);              // 0..127
    float v = (n < 64) ? Win[k * 64 + n] : Win[(128 + k) * 64 + (n - 64)];
    u16 hb = f2bf(v);
    BH[idx] = hb;
    BL[idx] = f2bf(v - bf2f(hb));
}

// Edge-MLP hidden B: 3 layers x [K=64][N=64]. idx=(L*8+kt*4+nt)*512+lane*8+j.
__global__ __launch_bounds__(256) void pack_hidB_kernel(
    const float* __restrict__ Whid, u16* __restrict__ BH, u16* __restrict__ BL)
{
    int idx = blockIdx.x * 256 + threadIdx.x;   // 12288 total
    if (idx >= 12288) return;
    int j    = idx & 7;
    int lane = (idx >> 3) & 63;
    int nt   = (idx >> 9) & 3;
    int kt   = (idx >> 11) & 1;
    int L    = idx >> 12;
    int k = kt * 32 + (lane >> 4) * 8 + j;       // 0..63
    int n = nt * 16 + (lane & 15);               // 0..63
    float v = Whid[L * 4096 + k * 64 + n];
    u16 hb = f2bf(v);
    BH[idx] = hb;
    BL[idx] = f2bf(v - bf2f(hb));
}

// Edge-MLP out B: [K=64][N=128]. idx=(kt*8+nt)*512+lane*8+j.
__global__ __launch_bounds__(256) void pack_outB_kernel(
    const float* __restrict__ Wout, u16* __restrict__ BH, u16* __restrict__ BL)
{
    int idx = blockIdx.x * 256 + threadIdx.x;   // 8192 total
    if (idx >= 8192) return;
    int j    = idx & 7;
    int lane = (idx >> 3) & 63;
    int nt   = (idx >> 9) & 7;
    int kt   = idx >> 12;                        // 0..1
    int k = kt * 32 + (lane >> 4) * 8 + j;       // 0..63
    int n = nt * 16 + (lane & 15);               // 0..127
    float v = Wout[k * 128 + n];
    u16 hb = f2bf(v);
    BH[idx] = hb;
    BL[idx] = f2bf(v - bf2f(hb));
}

// Initial p only: p[v][0:64)=Wtop@h[v]+bin, p[v][64:128)=Wbot@h[v].
__global__ __launch_bounds__(256) void node_pre_kernel(
    const float* __restrict__ h, const float* __restrict__ Win,
    const float* __restrict__ bin, float* __restrict__ p)
{
    const int node = blockIdx.x * 256 + threadIdx.x;
    const float4* h4 = (const float4*)(h + (size_t)node * DDIM);
    float* prow = p + (size_t)node * DDIM;

    for (int c = 0; c < 4; ++c) {
        const int top   = (c < 2) ? 1 : 0;
        const int j0    = (c & 1) * 32;
        const int kbase = top ? 0 : 128;
        float acc[32];
        #pragma unroll
        for (int j = 0; j < 32; ++j) acc[j] = top ? bin[j0 + j] : 0.0f;
        for (int k4 = 0; k4 < 32; ++k4) {
            float4 hv = h4[k4];
            #pragma unroll
            for (int kk = 0; kk < 4; ++kk) {
                const float hk = (&hv.x)[kk];
                const float* wr = Win + (size_t)(kbase + k4 * 4 + kk) * 64 + j0;
                #pragma unroll
                for (int j = 0; j < 32; ++j) acc[j] = fmaf(hk, wr[j], acc[j]);
            }
        }
        float* dst = prow + (top ? 0 : 64) + j0;
        #pragma unroll
        for (int q = 0; q < 8; ++q)
            ((float4*)dst)[q] = make_float4(acc[q*4], acc[q*4+1],
                                            acc[q*4+2], acc[q*4+3]);
    }
}

// ---------------------------------------------------------------------------
// MFMA edge MLP (R21, validated). 512 threads / 128 slots per block.
// ---------------------------------------------------------------------------
__global__ __launch_bounds__(512) void edge_mlp_mfma(
    const int* __restrict__ ni, const int* __restrict__ bi, int E,
    const int* __restrict__ elist, const int* __restrict__ slotseg,
    const float* __restrict__ p,
    const u16* __restrict__ BhH, const u16* __restrict__ BhL,
    const float* __restrict__ bhid,
    const u16* __restrict__ BoH, const u16* __restrict__ BoL,
    const float* __restrict__ bout,
    float* __restrict__ sbuf)
{
    __shared__ short smA[16384];      // hi [0,8192), lo [8192,16384)
    __shared__ float scat[16 * 132];
    __shared__ int   segLDS[EBLK];
    __shared__ int   segedge[2];

    const int tid  = threadIdx.x;
    const int lane = tid & 63;
    const int w    = tid >> 6;        // wave = m-tile
    const int s0   = blockIdx.x * EBLK;

    if (tid < 128) segLDS[tid] = slotseg[s0 + tid];
    if (tid == 0) segedge[0] = slotseg[s0 - 1];
    if (tid == 1) segedge[1] = slotseg[s0 + EBLK];

    // ---- staging: thread covers slot m=(tid&15)+16*w, k-group gg=(tid>>4)&3
    {
        const int m  = (tid & 15) | (w << 4);
        const int gg = (tid >> 4) & 3;
        const int slot = s0 + m;
        const int g = elist[slot];
        int first, second;
        if (g < E) { first = ni[g];     second = bi[g];     }
        else       { first = bi[g - E]; second = ni[g - E]; }
        #pragma unroll
        for (int kt = 0; kt < 2; ++kt) {
            const int k0 = kt * 32 + gg * 8;
            const float4* pa = (const float4*)(p + (size_t)first  * DDIM + k0);
            const float4* pb = (const float4*)(p + (size_t)second * DDIM + 64 + k0);
            const float4 a0 = pa[0], a1 = pa[1], b0 = pb[0], b1 = pb[1];
            float x[8] = { a0.x + b0.x, a0.y + b0.y, a0.z + b0.z, a0.w + b0.w,
                           a1.x + b1.x, a1.y + b1.y, a1.z + b1.z, a1.w + b1.w };
            s16x8 hi8, lo8;
            #pragma unroll
            for (int j = 0; j < 8; ++j) {
                const float v = gelu_fast(x[j]);
                u16 hb = f2bf(v);
                hi8[j] = (short)hb;
                lo8[j] = (short)f2bf(v - bf2f(hb));
            }
            const int off = (kt * 8 + w) * 512 + lane * 8;
            *(s16x8*)(smA + off)        = hi8;
            *(s16x8*)(smA + 8192 + off) = lo8;
        }
    }
    // no barrier: wave w staged exactly the segments (kt*8+w) it reads.

    // ---- 3 hidden layers ----
    const int mt = w;
    for (int L = 0; L < 3; ++L) {
        f32x4 acc[4];
        #pragma unroll
        for (int nt = 0; nt < 4; ++nt) {
            const float bv = bhid[L * 64 + nt * 16 + (lane & 15)];
            acc[nt] = (f32x4){bv, bv, bv, bv};
        }
        #pragma unroll
        for (int kt = 0; kt < 2; ++kt) {
            const s16x8 aH = *(const s16x8*)(smA + (kt * 8 + mt) * 512 + lane * 8);
            const s16x8 aL = *(const s16x8*)(smA + 8192 + (kt * 8 + mt) * 512 + lane * 8);
            #pragma unroll
            for (int nt = 0; nt < 4; ++nt) {
                const int bidx = (L * 8 + kt * 4 + nt) * 64 + lane;
                const s16x8 bH = ((const s16x8*)BhH)[bidx];
                const s16x8 bL = ((const s16x8*)BhL)[bidx];
                acc[nt] = __builtin_amdgcn_mfma_f32_16x16x32_bf16(aH, bH, acc[nt], 0, 0, 0);
                acc[nt] = __builtin_amdgcn_mfma_f32_16x16x32_bf16(aH, bL, acc[nt], 0, 0, 0);
                acc[nt] = __builtin_amdgcn_mfma_f32_16x16x32_bf16(aL, bH, acc[nt], 0, 0, 0);
            }
        }
        // epilogue: gelu + scatter back into own A-frag segments (k = col).
        #pragma unroll
        for (int nt = 0; nt < 4; ++nt) {
            #pragma unroll
            for (int r = 0; r < 4; ++r) {
                const float v = gelu_fast(acc[nt][r]);
                const int ml  = (lane >> 4) * 4 + r;        // row within tile
                const int k   = nt * 16 + (lane & 15);      // col -> next k
                const int kt2 = k >> 5, gg = (k >> 3) & 3, j = k & 7;
                const int off = (kt2 * 8 + mt) * 512 + (ml + 16 * gg) * 8 + j;
                u16 hb = f2bf(v);
                smA[off]        = (short)hb;
                smA[8192 + off] = (short)f2bf(v - bf2f(hb));
            }
        }
    }

    // ---- out layer: N=128 ----
    f32x4 acc2[8];
    #pragma unroll
    for (int nt = 0; nt < 8; ++nt) {
        const float bv = bout[nt * 16 + (lane & 15)];
        acc2[nt] = (f32x4){bv, bv, bv, bv};
    }
    #pragma unroll
    for (int kt = 0; kt < 2; ++kt) {
        const s16x8 aH = *(const s16x8*)(smA + (kt * 8 + mt) * 512 + lane * 8);
        const s16x8 aL = *(const s16x8*)(smA + 8192 + (kt * 8 + mt) * 512 + lane * 8);
        #pragma unroll
        for (int nt = 0; nt < 8; ++nt) {
            const int bidx = (kt * 8 + nt) * 64 + lane;
            const s16x8 bH = ((const s16x8*)BoH)[bidx];
            const s16x8 bL = ((const s16x8*)BoL)[bidx];
            acc2[nt] = __builtin_amdgcn_mfma_f32_16x16x32_bf16(aH, bH, acc2[nt], 0, 0, 0);
            acc2[nt] = __builtin_amdgcn_mfma_f32_16x16x32_bf16(aH, bL, acc2[nt], 0, 0, 0);
            acc2[nt] = __builtin_amdgcn_mfma_f32_16x16x32_bf16(aL, bH, acc2[nt], 0, 0, 0);
        }
    }

    // ---- fused segmented reduction (R19 semantics, 128 cols) ----
    int   runSeg = -2;
    float runacc = 0.0f;
    bool  leftC  = true;
    for (int b = 0; b < 8; ++b) {
        __syncthreads();
        if (w == b) {
            #pragma unroll
            for (int nt = 0; nt < 8; ++nt)
                #pragma unroll
                for (int r = 0; r < 4; ++r)
                    scat[((lane >> 4) * 4 + r) * 132 + nt * 16 + (lane & 15)] = acc2[nt][r];
        }
        __syncthreads();
        if (tid < 128) {
            for (int r = 0; r < 16; ++r) {
                const int rowi = b * 16 + r;
                const int sg = segLDS[rowi];
                const float v = scat[r * 132 + tid];
                if (sg != runSeg) {
                    if (runSeg >= 0) {
                        float* pp = sbuf + (size_t)runSeg * DDIM + tid;
                        if (leftC) *pp = runacc;
                        else       atomicAdd(pp, runacc);
                    }
                    runSeg = sg;
                    runacc = v;
                    leftC  = (rowi == 0) ? (segedge[0] != sg) : true;
                } else {
                    runacc += v;
                }
            }
        }
    }
    if (tid < 128 && runSeg >= 0) {
        const bool rightC = (segedge[1] != runSeg);
        float* pp = sbuf + (size_t)runSeg * DDIM + tid;
        if (leftC && rightC) *pp = runacc;
        else                 atomicAdd(pp, runacc);
    }
}

// ---------------------------------------------------------------------------
// MFMA GRU + fused node_pre, R22: 256 thr / 4 waves / 64 nodes per block.
// wave w: jg = w&1 (j-half), mh = w>>1 (m-half: m-tiles 2mh, 2mh+1).
// Each B load feeds 6 MFMAs (2 m-frags x 3 hi/lo terms); xh/hh zero-block
// skip. LDS 64KB (2 blocks/CU).
// ---------------------------------------------------------------------------
__global__ __launch_bounds__(256, 2) void gru_mfma_kernel(
    const float* __restrict__ h, float* __restrict__ msum,
    const int* __restrict__ deg,
    const u16* __restrict__ BgH, const u16* __restrict__ BgL,
    const float* __restrict__ bi_, const float* __restrict__ br_,
    const u16* __restrict__ BpH, const u16* __restrict__ BpL,
    const float* __restrict__ binp,
    float* __restrict__ hout)
{
    __shared__ short sm[32768];   // 64 KB: gate A hi [0,16384), lo [16384,32768)
    const int tid  = threadIdx.x;
    const int lane = tid & 63;
    const int w    = tid >> 6;    // 0..3
    const int jg   = w & 1;
    const int mh   = w >> 1;      // m-half
    const int nbase = blockIdx.x * 64;

    // ---- Phase 1: stage A = [m*ci | h] fragments, conflict-free map ----
    // thread: mS = tid>>2 (row), q = tid&3; chunk c*4+q -> ktG=c, g=q.
    {
        const int mS = tid >> 2, q = tid & 3;
        const int nodeS = nbase + mS;
        const int dg = deg[nodeS];
        const float ci = (dg > 0) ? (1.0f / (float)dg) : 0.0f;
        const int laneS = (mS & 15) + 16 * q;
        const int seg_m = mS >> 4;
        #pragma unroll
        for (int c = 0; c < 8; ++c) {
            const int k0 = (c * 4 + q) * 8;      // 0..248
            const float* src = (k0 < 128)
                ? (msum + (size_t)nodeS * DDIM + k0)
                : (h    + (size_t)nodeS * DDIM + (k0 - 128));
            const float4 v0 = ((const float4*)src)[0];
            const float4 v1 = ((const float4*)src)[1];
            const float sc = (k0 < 128) ? ci : 1.0f;
            float xv[8] = { v0.x * sc, v0.y * sc, v0.z * sc, v0.w * sc,
                            v1.x * sc, v1.y * sc, v1.z * sc, v1.w * sc };
            s16x8 hi8, lo8;
            #pragma unroll
            for (int i = 0; i < 8; ++i) {
                u16 hb = f2bf(xv[i]);
                hi8[i] = (short)hb;
                lo8[i] = (short)f2bf(xv[i] - bf2f(hb));
            }
            const int off = (c * 4 + seg_m) * 512 + laneS * 8;
            *(s16x8*)(sm + off)         = hi8;
            *(s16x8*)(sm + off + 16384) = lo8;
        }
    }
    __syncthreads();

    // ---- Phase 2: gate GEMM, 2 m-frags per wave, xh/hh zero-skip ----
    f32x4 acc[2][4][4];
    #pragma unroll
    for (int mf = 0; mf < 2; ++mf)
        #pragma unroll
        for (int g = 0; g < 4; ++g)
            #pragma unroll
            for (int t4 = 0; t4 < 4; ++t4)
                acc[mf][g][t4] = (f32x4){0.f, 0.f, 0.f, 0.f};

    const s16x8* Bh8 = (const s16x8*)BgH;
    const s16x8* Bl8 = (const s16x8*)BgL;
    #pragma unroll
    for (int ktG = 0; ktG < 8; ++ktG) {
        const int a0off = (ktG * 4 + 2 * mh) * 512 + lane * 8;
        const s16x8 aH0 = *(const s16x8*)(sm + a0off);
        const s16x8 aL0 = *(const s16x8*)(sm + 16384 + a0off);
        const s16x8 aH1 = *(const s16x8*)(sm + a0off + 512);
        const s16x8 aL1 = *(const s16x8*)(sm + 16384 + a0off + 512);
        #pragma unroll
        for (int g = 0; g < 4; ++g) {
            if (g == 2 && ktG >= 4) continue;   // xh: k<128 only (zeros above)
            if (g == 3 && ktG < 4)  continue;   // hh: k>=128 only
            #pragma unroll
            for (int t4 = 0; t4 < 4; ++t4) {
                const int idx = (ktG * 32 + g * 8 + jg * 4 + t4) * 64 + lane;
                const s16x8 bH = Bh8[idx];
                const s16x8 bL = Bl8[idx];
                acc[0][g][t4] = __builtin_amdgcn_mfma_f32_16x16x32_bf16(aH0, bH, acc[0][g][t4], 0, 0, 0);
                acc[0][g][t4] = __builtin_amdgcn_mfma_f32_16x16x32_bf16(aH0, bL, acc[0][g][t4], 0, 0, 0);
                acc[0][g][t4] = __builtin_amdgcn_mfma_f32_16x16x32_bf16(aL0, bH, acc[0][g][t4], 0, 0, 0);
                acc[1][g][t4] = __builtin_amdgcn_mfma_f32_16x16x32_bf16(aH1, bH, acc[1][g][t4], 0, 0, 0);
                acc[1][g][t4] = __builtin_amdgcn_mfma_f32_16x16x32_bf16(aH1, bL, acc[1][g][t4], 0, 0, 0);
                acc[1][g][t4] = __builtin_amdgcn_mfma_f32_16x16x32_bf16(aL1, bH, acc[1][g][t4], 0, 0, 0);
            }
        }
    }

    // ---- Phase 3: gate epilogue (lane-local) -> h' ----
    float hn[2][4][4];
    #pragma unroll
    for (int t4 = 0; t4 < 4; ++t4) {
        const int j = jg * 64 + t4 * 16 + (lane & 15);
        const float b_az = bi_[j]       + br_[j];
        const float b_ar = bi_[128 + j] + br_[128 + j];
        const float b_xh = bi_[256 + j];
        const float b_hh = br_[256 + j];
        #pragma unroll
        for (int mf = 0; mf < 2; ++mf) {
            const int mtile = 2 * mh + mf;
            #pragma unroll
            for (int r = 0; r < 4; ++r) {
                const int m = mtile * 16 + (lane >> 4) * 4 + r;
                const float az = acc[mf][0][t4][r] + b_az;
                const float ar = acc[mf][1][t4][r] + b_ar;
                const float xh = acc[mf][2][t4][r] + b_xh;
                const float hh = acc[mf][3][t4][r] + b_hh;
                const float z    = sigmoidf_(az);
                const float rr   = sigmoidf_(ar);
                const float cand = tanhf(xh + rr * hh);
                const float hv   = h[(size_t)(nbase + m) * DDIM + j];
                const float v    = z * hv + (1.0f - z) * cand;
                hout[(size_t)(nbase + m) * DDIM + j] = v;
                hn[mf][t4][r] = v;
            }
        }
    }

    __syncthreads();   // gate GEMM LDS reads done everywhere; reuse sm

    // scatter h' into node_pre A-frag layout (k = j, same frag map);
    // pre A: hi [0,8192), lo [8192,16384)
    #pragma unroll
    for (int mf = 0; mf < 2; ++mf) {
        const int mtile = 2 * mh + mf;
        #pragma unroll
        for (int t4 = 0; t4 < 4; ++t4) {
            #pragma unroll
            for (int r = 0; r < 4; ++r) {
                const int m  = mtile * 16 + (lane >> 4) * 4 + r;
                const int j  = jg * 64 + t4 * 16 + (lane & 15);
                const int kt2 = j >> 5, gg = (j >> 3) & 3, jj = j & 7;
                const int lane2 = (m & 15) + 16 * gg;
                const int off = (kt2 * 4 + mtile) * 512 + lane2 * 8 + jj;
                const float v = hn[mf][t4][r];
                u16 hb = f2bf(v);
                sm[off]        = (short)hb;
                sm[off + 8192] = (short)f2bf(v - bf2f(hb));
            }
        }
    }
    __syncthreads();

    // ---- Phase 4: node_pre GEMM -> p (into msum) ----
    f32x4 acc2[2][4];
    #pragma unroll
    for (int mf = 0; mf < 2; ++mf)
        #pragma unroll
        for (int t4 = 0; t4 < 4; ++t4)
            acc2[mf][t4] = (f32x4){0.f, 0.f, 0.f, 0.f};

    const s16x8* Ph8 = (const s16x8*)BpH;
    const s16x8* Pl8 = (const s16x8*)BpL;
    #pragma unroll
    for (int kt2 = 0; kt2 < 4; ++kt2) {
        const int a0off = (kt2 * 4 + 2 * mh) * 512 + lane * 8;
        const s16x8 aH0 = *(const s16x8*)(sm + a0off);
        const s16x8 aL0 = *(const s16x8*)(sm + 8192 + a0off);
        const s16x8 aH1 = *(const s16x8*)(sm + a0off + 512);
        const s16x8 aL1 = *(const s16x8*)(sm + 8192 + a0off + 512);
        #pragma unroll
        for (int t4 = 0; t4 < 4; ++t4) {
            const int idx = (kt2 * 8 + jg * 4 + t4) * 64 + lane;
            const s16x8 bH = Ph8[idx];
            const s16x8 bL = Pl8[idx];
            acc2[0][t4] = __builtin_amdgcn_mfma_f32_16x16x32_bf16(aH0, bH, acc2[0][t4], 0, 0, 0);
            acc2[0][t4] = __builtin_amdgcn_mfma_f32_16x16x32_bf16(aH0, bL, acc2[0][t4], 0, 0, 0);
            acc2[0][t4] = __builtin_amdgcn_mfma_f32_16x16x32_bf16(aL0, bH, acc2[0][t4], 0, 0, 0);
            acc2[1][t4] = __builtin_amdgcn_mfma_f32_16x16x32_bf16(aH1, bH, acc2[1][t4], 0, 0, 0);
            acc2[1][t4] = __builtin_amdgcn_mfma_f32_16x16x32_bf16(aH1, bL, acc2[1][t4], 0, 0, 0);
            acc2[1][t4] = __builtin_amdgcn_mfma_f32_16x16x32_bf16(aL1, bH, acc2[1][t4], 0, 0, 0);
        }
    }
    #pragma unroll
    for (int mf = 0; mf < 2; ++mf) {
        const int mtile = 2 * mh + mf;
        #pragma unroll
        for (int t4 = 0; t4 < 4; ++t4) {
            const int n = jg * 64 + t4 * 16 + (lane & 15);
            const float badd = (n < 64) ? binp[n] : 0.0f;
            #pragma unroll
            for (int r = 0; r < 4; ++r) {
                const int m = mtile * 16 + (lane >> 4) * 4 + r;
                msum[(size_t)(nbase + m) * DDIM + n] = acc2[mf][t4][r] + badd;
            }
        }
    }
}

// Readout: block=64, LDS activation slices, scalar weights.
__global__ __launch_bounds__(64) void readout_kernel(
    const float* __restrict__ h,
    const float* __restrict__ Win,  const float* __restrict__ bin,
    const float* __restrict__ Whid, const float* __restrict__ bhid,
    const float* __restrict__ Wout, const float* __restrict__ bout,
    float* __restrict__ out)
{
    __shared__ float xs[64 * 65];
    const int tid = threadIdx.x;
    const int row = blockIdx.x * 64 + tid;
    const int b = row / 1000, n = row % 1000;
    const float4* xrow = (const float4*)(h + ((size_t)b * 4000 + n) * DDIM);

    {
        float acc[64];
        #pragma unroll
        for (int j = 0; j < 64; ++j) acc[j] = bin[j];
        #pragma unroll 2
        for (int k4 = 0; k4 < 32; ++k4) {
            float4 xv = xrow[k4];
            #pragma unroll
            for (int kk = 0; kk < 4; ++kk) {
                const float xk = (&xv.x)[kk];
                const float* wr = Win + (size_t)(k4 * 4 + kk) * 64;
                #pragma unroll
                for (int j = 0; j < 64; ++j) acc[j] = fmaf(xk, wr[j], acc[j]);
            }
        }
        #pragma unroll
        for (int j = 0; j < 64; ++j) xs[tid * 65 + j] = gelu_exact(acc[j]);
    }

    for (int L = 0; L < 3; ++L) {
        float acc[64];
        #pragma unroll
        for (int j = 0; j < 64; ++j) acc[j] = bhid[L * 64 + j];
        #pragma unroll 4
        for (int k = 0; k < 64; ++k) {
            const float xk = xs[tid * 65 + k];
            const float* wr = Whid + (size_t)L * 4096 + (size_t)k * 64;
            #pragma unroll
            for (int j = 0; j < 64; ++j) acc[j] = fmaf(xk, wr[j], acc[j]);
        }
        #pragma unroll
        for (int j = 0; j < 64; ++j) xs[tid * 65 + j] = gelu_exact(acc[j]);
    }

    float acc[10];
    #pragma unroll
    for (int pj = 0; pj < 10; ++pj) acc[pj] = bout[pj];
    #pragma unroll 4
    for (int k = 0; k < 64; ++k) {
        const float xk = xs[tid * 65 + k];
        const float* wr = Wout + k * 10;
        #pragma unroll
        for (int pj = 0; pj < 10; ++pj) acc[pj] = fmaf(xk, wr[pj], acc[pj]);
    }
    #pragma unroll
    for (int pj = 0; pj < 10; ++pj) out[(size_t)row * 10 + pj] = acc[pj];
}

extern "C" void kernel_launch(void* const* d_in, const int* in_sizes, int n_in,
                              void* d_out, int out_size, void* d_ws, size_t ws_size,
                              hipStream_t stream) {
    const int*   node_inputs = (const int*)d_in[0];
    const int*   ni_int = (const int*)d_in[1];
    const int*   bi_int = (const int*)d_in[2];
    const int*   ni_tmp = (const int*)d_in[3];
    const int*   bi_tmp = (const int*)d_in[4];
    const float* embed  = (const float*)d_in[5];
    const float* mWin   = (const float*)d_in[6];
    const float* mbin   = (const float*)d_in[7];
    const float* mWhid  = (const float*)d_in[8];
    const float* mbhid  = (const float*)d_in[9];
    const float* mWout  = (const float*)d_in[10];
    const float* mbout  = (const float*)d_in[11];
    const float* roWin  = (const float*)d_in[12];
    const float* robin  = (const float*)d_in[13];
    const float* roWhid = (const float*)d_in[14];
    const float* robhid = (const float*)d_in[15];
    const float* roWout = (const float*)d_in[16];
    const float* robout = (const float*)d_in[17];
    const float* giWx = (const float*)d_in[18];
    const float* giWh = (const float*)d_in[19];
    const float* gibi = (const float*)d_in[20];
    const float* gibr = (const float*)d_in[21];
    const float* gtWx = (const float*)d_in[22];
    const float* gtWh = (const float*)d_in[23];
    const float* gtbi = (const float*)d_in[24];
    const float* gtbr = (const float*)d_in[25];
    float* out = (float*)d_out;

    const int E_INT = 200000, E_TMP = 96000;
    const int NSLOT_I = 400000;   // 3125*128 exact
    const int NSLOT_T = 192000;   // 1500*128 exact
    const int NBLK_I = NSLOT_I / EBLK;
    const int NBLK_T = NSLOT_T / EBLK;

    char* ws = (char*)d_ws;
    float* B0 = (float*)(ws);
    float* B1 = (float*)(ws + HBYTES);
    float* B2 = (float*)(ws + 2 * HBYTES);
    char*  ib = ws + 3 * HBYTES;

    int* deg_i   = (int*)(ib);
    int* deg_t   = (int*)(ib + 512000);
    int* offp_i  = (int*)(ib + 1024000);
    int* offp_t  = (int*)(ib + 1536000);
    int* bexc_i  = (int*)(ib + 2048000);
    int* bexc_t  = (int*)(ib + 2052096);
    int* bsum    = (int*)(ib + 2056192);
    int* cursor  = (int*)(ib + 2060288);
    int* el_i    = (int*)(ib + 2572288);
    int* el_t    = (int*)(ib + 4172288);
    int* ssi_raw = (int*)(ib + 4940288);
    int* sst_raw = (int*)(ib + 6540296);
    int* str_i   = (int*)(ib + 8094784);
    int* str_t   = (int*)(ib + 8107384);
    int* strc_i  = (int*)(ib + 8113484);
    int* strc_t  = (int*)(ib + 8113488);
    // bf16-split B-fragment buffers
    char* fb = ib + 8114176;
    u16* BgiH = (u16*)(fb);
    u16* BgiL = (u16*)(fb +  262144);
    u16* BgtH = (u16*)(fb +  524288);
    u16* BgtL = (u16*)(fb +  786432);
    u16* BpH  = (u16*)(fb + 1048576);
    u16* BpL  = (u16*)(fb + 1081344);
    u16* EhH  = (u16*)(fb + 1114112);   // 3*4096 elems = 24576 B
    u16* EhL  = (u16*)(fb + 1138688);
    u16* EoH  = (u16*)(fb + 1163264);   // 8192 elems = 16384 B
    u16* EoL  = (u16*)(fb + 1179648);
    int* ssi = ssi_raw + 1;
    int* sst = sst_raw + 1;

    embed_kernel<<<16000, 256, 0, stream>>>(node_inputs, embed, B0);

    hipMemsetAsync(deg_i, 0, NTOT * sizeof(int), stream);
    hipMemsetAsync(deg_t, 0, NTOT * sizeof(int), stream);
    hist_kernel<<<(2 * E_INT + 255) / 256, 256, 0, stream>>>(ni_int, bi_int, E_INT, deg_i);
    hist_kernel<<<(2 * E_TMP + 255) / 256, 256, 0, stream>>>(ni_tmp, bi_tmp, E_TMP, deg_t);

    hipMemsetAsync(ssi_raw, 0xFF, (size_t)(NSLOT_I + 2) * sizeof(int), stream);
    hipMemsetAsync(sst_raw, 0xFF, (size_t)(NSLOT_T + 2) * sizeof(int), stream);

    blockscan_kernel<<<500, 256, 0, stream>>>(deg_i, offp_i, bsum);
    bscan_kernel<<<1, 512, 0, stream>>>(bsum, bexc_i, 500);
    hipMemsetAsync(cursor, 0, NTOT * sizeof(int), stream);
    fill_kernel<<<(2 * E_INT + 255) / 256, 256, 0, stream>>>(
        ni_int, bi_int, E_INT, offp_i, bexc_i, cursor, el_i, ssi);

    blockscan_kernel<<<500, 256, 0, stream>>>(deg_t, offp_t, bsum);
    bscan_kernel<<<1, 512, 0, stream>>>(bsum, bexc_t, 500);
    hipMemsetAsync(cursor, 0, NTOT * sizeof(int), stream);
    fill_kernel<<<(2 * E_TMP + 255) / 256, 256, 0, stream>>>(
        ni_tmp, bi_tmp, E_TMP, offp_t, bexc_t, cursor, el_t, sst);

    hipMemsetAsync(strc_i, 0, sizeof(int), stream);
    hipMemsetAsync(strc_t, 0, sizeof(int), stream);
    straddle_kernel<<<(NBLK_I + 255) / 256, 256, 0, stream>>>(ssi, NBLK_I, str_i, strc_i);
    straddle_kernel<<<(NBLK_T + 255) / 256, 256, 0, stream>>>(sst, NBLK_T, str_t, strc_t);

    pack_gateB_kernel<<<512, 256, 0, stream>>>(giWx, giWh, BgiH, BgiL);
    pack_gateB_kernel<<<512, 256, 0, stream>>>(gtWx, gtWh, BgtH, BgtL);
    pack_preB_kernel<<<64, 256, 0, stream>>>(mWin, BpH, BpL);
    pack_hidB_kernel<<<48, 256, 0, stream>>>(mWhid, EhH, EhL);
    pack_outB_kernel<<<32, 256, 0, stream>>>(mWout, EoH, EoL);

    node_pre_kernel<<<NTOT / 256, 256, 0, stream>>>(B0, mWin, mbin, B1);

    // rotation: X=h, Y=p, Z=free
    float* X = B0; float* Y = B1; float* Z = B2;
    for (int ph = 0; ph < 4; ++ph) {
        const bool isInt = (ph % 2 == 0);
        if (isInt) {
            zero_rows_kernel<<<NBLK_I, 64, 0, stream>>>(str_i, strc_i, Z);
            edge_mlp_mfma<<<NBLK_I, 512, 0, stream>>>(
                ni_int, bi_int, E_INT, el_i, ssi, Y,
                EhH, EhL, mbhid, EoH, EoL, mbout, Z);
            gru_mfma_kernel<<<NTOT / 64, 256, 0, stream>>>(
                X, Z, deg_i, BgiH, BgiL, gibi, gibr, BpH, BpL, mbin, Y);
        } else {
            zero_rows_kernel<<<NBLK_T, 64, 0, stream>>>(str_t, strc_t, Z);
            edge_mlp_mfma<<<NBLK_T, 512, 0, stream>>>(
                ni_tmp, bi_tmp, E_TMP, el_t, sst, Y,
                EhH, EhL, mbhid, EoH, EoL, mbout, Z);
            gru_mfma_kernel<<<NTOT / 64, 256, 0, stream>>>(
                X, Z, deg_t, BgtH, BgtL, gtbi, gtbr, BpH, BpL, mbin, Y);
        }
        float* oldX = X;  X = Y;  Y = Z;  Z = oldX;
    }

    readout_kernel<<<500, 64, 0, stream>>>(
        X, roWin, robin, roWhid, robhid, roWout, robout, out);
}

// Round 4
// 1710.818 us; speedup vs baseline: 2.3343x; 1.0085x over previous
//
#include <hip/hip_runtime.h>
#include <math.h>

// MPNN on MI355X. R23 = R22 + occupancy/latency fixes.
// R22 counters: gru 4x215us MfmaUtil 17/VALU 29/HBM 13%/Occ 22% ->
// latency-bound, LDS-capped (64KB -> 2 blk/CU). Changes:
//  GRU: (1) K-split gate staging: two 128-k halves share one 32KB LDS
//       buffer (zero-skip partitions gates by k-half: ks0->z,r,xh;
//       ks1->z,r,hh => zero extra MFMA). launch_bounds(256,3) -> 3 blk/CU.
//       (2) epilogue hv reconstructed from resident LDS half (hi+lo,
//       err ~2^-18) instead of 32 global h re-reads/thread.
//       (3) sigmoid/tanh via __expf identities (exact algebra, ~1e-6).
//  Edge: 4-wave dumps into 64-row scat overlaid on dead smA; barriers
//       16->4; LDS 42->34.3KB -> 4 blk/CU (32-wave cap).
// Everything else (CSR/straddle, packers, frag maps, rotation) unchanged
// from R22 (harness-validated, absmax 1.22e-4).

#define DDIM 128
#define NTOT 128000
#define HBYTES 65536000ULL   // 128000*128*4
#define EBLK 128

typedef unsigned short u16;
using f32x4 = __attribute__((ext_vector_type(4))) float;
using s16x8 = __attribute__((ext_vector_type(8))) short;

__device__ __forceinline__ float gelu_exact(float x) {
    return 0.5f * x * (1.0f + erff(x * 0.70710678118654752440f));
}
// A&S 7.1.26 erf, |abs err| <= 1.5e-7; gelu err <= ~1e-6 (budget 6.35e-4).
__device__ __forceinline__ float gelu_fast(float x) {
    const float ax = fabsf(x) * 0.70710678118654752440f;
    const float t  = 1.0f / (1.0f + 0.3275911f * ax);
    const float poly = t * (0.254829592f + t * (-0.284496736f +
                       t * (1.421413741f + t * (-1.453152027f +
                       t * 1.061405429f))));
    const float e = __expf(-ax * ax);
    const float erfax = 1.0f - poly * e;
    const float erfv = copysignf(erfax, x);
    return 0.5f * x * (1.0f + erfv);
}
__device__ __forceinline__ float sigmoidf_(float x) {
    return 1.0f / (1.0f + expf(-x));
}
__device__ __forceinline__ float sigmoid_fast(float x) {
    return 1.0f / (1.0f + __expf(-x));    // exact identity, __expf ~2ulp
}
__device__ __forceinline__ float tanh_fast(float x) {
    const float e = __expf(2.0f * x);     // tanh = 1 - 2/(e^{2x}+1), exact
    return 1.0f - 2.0f / (e + 1.0f);      // inf/0 limits give +-1 correctly
}
__device__ __forceinline__ u16 f2bf(float x) {            // RNE f32->bf16
    unsigned u = __float_as_uint(x);
    u += 0x7fffu + ((u >> 16) & 1u);
    return (u16)(u >> 16);
}
__device__ __forceinline__ float bf2f(u16 h) {
    return __uint_as_float(((unsigned)h) << 16);
}

__global__ __launch_bounds__(256) void embed_kernel(
    const int* __restrict__ inp, const float* __restrict__ table,
    float* __restrict__ h)
{
    int gid = blockIdx.x * 256 + threadIdx.x;
    if (gid >= NTOT * 32) return;
    int row = gid >> 5;
    int q   = gid & 31;
    int b   = row / 4000;
    int n   = (row % 4000) % 1000;
    int e   = inp[b * 1000 + n];
    ((float4*)h)[gid] = ((const float4*)table)[e * 32 + q];
}

__global__ __launch_bounds__(256) void hist_kernel(
    const int* __restrict__ ni, const int* __restrict__ bi, int E,
    int* __restrict__ deg)
{
    int g = blockIdx.x * 256 + threadIdx.x;
    if (g < E)          atomicAdd(&deg[bi[g]], 1);
    else if (g < 2 * E) atomicAdd(&deg[ni[g - E]], 1);
}

__global__ __launch_bounds__(256) void blockscan_kernel(
    const int* __restrict__ deg, int* __restrict__ offp, int* __restrict__ bsum)
{
    __shared__ int s[256];
    int tid = threadIdx.x;
    int i = blockIdx.x * 256 + tid;
    int v = deg[i];
    s[tid] = v;
    __syncthreads();
    for (int off = 1; off < 256; off <<= 1) {
        int t = (tid >= off) ? s[tid - off] : 0;
        __syncthreads();
        s[tid] += t;
        __syncthreads();
    }
    offp[i] = s[tid] - v;
    if (tid == 255) bsum[blockIdx.x] = s[255];
}

__global__ __launch_bounds__(512) void bscan_kernel(
    const int* __restrict__ bsum, int* __restrict__ bexc, int nb)
{
    __shared__ int s[512];
    int t = threadIdx.x;
    int v = (t < nb) ? bsum[t] : 0;
    s[t] = v;
    __syncthreads();
    for (int off = 1; off < 512; off <<= 1) {
        int u = (t >= off) ? s[t - off] : 0;
        __syncthreads();
        s[t] += u;
        __syncthreads();
    }
    if (t < nb) bexc[t] = s[t] - v;
}

__global__ __launch_bounds__(256) void fill_kernel(
    const int* __restrict__ ni, const int* __restrict__ bi, int E,
    const int* __restrict__ offp, const int* __restrict__ bexc,
    int* __restrict__ cursor, int* __restrict__ elist, int* __restrict__ slotseg)
{
    int g = blockIdx.x * 256 + threadIdx.x;
    if (g >= 2 * E) return;
    int seg = (g < E) ? bi[g] : ni[g - E];
    int pos = atomicAdd(&cursor[seg], 1);
    int slot = offp[seg] + bexc[seg >> 8] + pos;
    elist[slot] = g;
    slotseg[slot] = seg;
}

// Segments straddling an EBLK boundary (the only atomicAdd targets).
__global__ __launch_bounds__(256) void straddle_kernel(
    const int* __restrict__ slotseg, int nblocks,
    int* __restrict__ list, int* __restrict__ count)
{
    int b = blockIdx.x * 256 + threadIdx.x + 1;
    if (b >= nblocks) return;
    int s = slotseg[b * EBLK];
    if (s >= 0 && slotseg[b * EBLK - 1] == s) {
        int pos = atomicAdd(count, 1);
        list[pos] = s;
    }
}

__global__ __launch_bounds__(64) void zero_rows_kernel(
    const int* __restrict__ list, const int* __restrict__ count,
    float* __restrict__ sbuf)
{
    int i = blockIdx.x;
    if (i >= *count) return;
    int seg = list[i];
    float4* row = (float4*)(sbuf + (size_t)seg * DDIM);
    if (threadIdx.x < 32) row[threadIdx.x] = make_float4(0.f, 0.f, 0.f, 0.f);
}

// ---------------------------------------------------------------------------
// B-fragment packers (run once per launch). Shared frag map:
// lane l, elem j -> k = kt*32+(l>>4)*8+j, n = nt*16+(l&15).
// ---------------------------------------------------------------------------
__global__ __launch_bounds__(256) void pack_gateB_kernel(
    const float* __restrict__ Wx, const float* __restrict__ Wh,
    u16* __restrict__ BH, u16* __restrict__ BL)
{
    int idx = blockIdx.x * 256 + threadIdx.x;   // 131072 total
    if (idx >= 131072) return;
    int j    = idx & 7;
    int lane = (idx >> 3) & 63;
    int ntG  = (idx >> 9) & 31;
    int ktG  = idx >> 14;                        // 0..7
    int k = ktG * 32 + (lane >> 4) * 8 + j;      // 0..255
    int n = ntG * 16 + (lane & 15);              // 0..511
    int g = n >> 7, jj = n & 127;
    float v;
    if (g == 0)      v = (k < 128) ? Wx[k * 384 + jj]       : Wh[(k - 128) * 384 + jj];
    else if (g == 1) v = (k < 128) ? Wx[k * 384 + 128 + jj] : Wh[(k - 128) * 384 + 128 + jj];
    else if (g == 2) v = (k < 128) ? Wx[k * 384 + 256 + jj] : 0.0f;
    else             v = (k < 128) ? 0.0f                   : Wh[(k - 128) * 384 + 256 + jj];
    u16 hb = f2bf(v);
    BH[idx] = hb;
    BL[idx] = f2bf(v - bf2f(hb));
}

// node_pre B: [K=128][N=128], n<64 -> Win rows 0..127, n>=64 -> rows 128..255.
__global__ __launch_bounds__(256) void pack_preB_kernel(
    const float* __restrict__ Win, u16* __restrict__ BH, u16* __restrict__ BL)
{
    int idx = blockIdx.x * 256 + threadIdx.x;   // 16384 total
    if (idx >= 16384) return;
    int j    = idx & 7;
    int lane = (idx >> 3) & 63;
    int nt2  = (idx >> 9) & 7;
    int kt2  = idx >> 12;                        // 0..3
    int k = kt2 * 32 + (lane >> 4) * 8 + j;      // 0..127
    int n = nt2 * 16 + (lane & 15);              // 0..127
    float v = (n < 64) ? Win[k * 64 + n] : Win[(128 + k) * 64 + (n - 64)];
    u16 hb = f2bf(v);
    BH[idx] = hb;
    BL[idx] = f2bf(v - bf2f(hb));
}

// Edge-MLP hidden B: 3 layers x [K=64][N=64]. idx=(L*8+kt*4+nt)*512+lane*8+j.
__global__ __launch_bounds__(256) void pack_hidB_kernel(
    const float* __restrict__ Whid, u16* __restrict__ BH, u16* __restrict__ BL)
{
    int idx = blockIdx.x * 256 + threadIdx.x;   // 12288 total
    if (idx >= 12288) return;
    int j    = idx & 7;
    int lane = (idx >> 3) & 63;
    int nt   = (idx >> 9) & 3;
    int kt   = (idx >> 11) & 1;
    int L    = idx >> 12;
    int k = kt * 32 + (lane >> 4) * 8 + j;       // 0..63
    int n = nt * 16 + (lane & 15);               // 0..63
    float v = Whid[L * 4096 + k * 64 + n];
    u16 hb = f2bf(v);
    BH[idx] = hb;
    BL[idx] = f2bf(v - bf2f(hb));
}

// Edge-MLP out B: [K=64][N=128]. idx=(kt*8+nt)*512+lane*8+j.
__global__ __launch_bounds__(256) void pack_outB_kernel(
    const float* __restrict__ Wout, u16* __restrict__ BH, u16* __restrict__ BL)
{
    int idx = blockIdx.x * 256 + threadIdx.x;   // 8192 total
    if (idx >= 8192) return;
    int j    = idx & 7;
    int lane = (idx >> 3) & 63;
    int nt   = (idx >> 9) & 7;
    int kt   = idx >> 12;                        // 0..1
    int k = kt * 32 + (lane >> 4) * 8 + j;       // 0..63
    int n = nt * 16 + (lane & 15);               // 0..127
    float v = Wout[k * 128 + n];
    u16 hb = f2bf(v);
    BH[idx] = hb;
    BL[idx] = f2bf(v - bf2f(hb));
}

// Initial p only: p[v][0:64)=Wtop@h[v]+bin, p[v][64:128)=Wbot@h[v].
__global__ __launch_bounds__(256) void node_pre_kernel(
    const float* __restrict__ h, const float* __restrict__ Win,
    const float* __restrict__ bin, float* __restrict__ p)
{
    const int node = blockIdx.x * 256 + threadIdx.x;
    const float4* h4 = (const float4*)(h + (size_t)node * DDIM);
    float* prow = p + (size_t)node * DDIM;

    for (int c = 0; c < 4; ++c) {
        const int top   = (c < 2) ? 1 : 0;
        const int j0    = (c & 1) * 32;
        const int kbase = top ? 0 : 128;
        float acc[32];
        #pragma unroll
        for (int j = 0; j < 32; ++j) acc[j] = top ? bin[j0 + j] : 0.0f;
        for (int k4 = 0; k4 < 32; ++k4) {
            float4 hv = h4[k4];
            #pragma unroll
            for (int kk = 0; kk < 4; ++kk) {
                const float hk = (&hv.x)[kk];
                const float* wr = Win + (size_t)(kbase + k4 * 4 + kk) * 64 + j0;
                #pragma unroll
                for (int j = 0; j < 32; ++j) acc[j] = fmaf(hk, wr[j], acc[j]);
            }
        }
        float* dst = prow + (top ? 0 : 64) + j0;
        #pragma unroll
        for (int q = 0; q < 8; ++q)
            ((float4*)dst)[q] = make_float4(acc[q*4], acc[q*4+1],
                                            acc[q*4+2], acc[q*4+3]);
    }
}

// ---------------------------------------------------------------------------
// MFMA edge MLP. R23: reduction scat (64 rows x 132) overlays dead smA;
// 2 dump rounds of 4 waves each; barriers 16->4; LDS ~34.3KB -> 4 blk/CU.
// Walk state (runSeg/runacc/leftC) persists in walker registers across
// rounds (same threads 0..127 walk both halves).
// ---------------------------------------------------------------------------
__global__ __launch_bounds__(512) void edge_mlp_mfma(
    const int* __restrict__ ni, const int* __restrict__ bi, int E,
    const int* __restrict__ elist, const int* __restrict__ slotseg,
    const float* __restrict__ p,
    const u16* __restrict__ BhH, const u16* __restrict__ BhL,
    const float* __restrict__ bhid,
    const u16* __restrict__ BoH, const u16* __restrict__ BoL,
    const float* __restrict__ bout,
    float* __restrict__ sbuf)
{
    __shared__ short smA[16896];      // 33792B; [0,16384) = hi/lo A-frags;
                                      // after out-layer reused as scat[64][132] f32
    __shared__ int   segLDS[EBLK];
    __shared__ int   segedge[2];
    float* scat = (float*)smA;

    const int tid  = threadIdx.x;
    const int lane = tid & 63;
    const int w    = tid >> 6;        // wave = m-tile
    const int s0   = blockIdx.x * EBLK;

    if (tid < 128) segLDS[tid] = slotseg[s0 + tid];
    if (tid == 0) segedge[0] = slotseg[s0 - 1];
    if (tid == 1) segedge[1] = slotseg[s0 + EBLK];

    // ---- staging: thread covers slot m=(tid&15)+16*w, k-group gg=(tid>>4)&3
    {
        const int m  = (tid & 15) | (w << 4);
        const int gg = (tid >> 4) & 3;
        const int slot = s0 + m;
        const int g = elist[slot];
        int first, second;
        if (g < E) { first = ni[g];     second = bi[g];     }
        else       { first = bi[g - E]; second = ni[g - E]; }
        #pragma unroll
        for (int kt = 0; kt < 2; ++kt) {
            const int k0 = kt * 32 + gg * 8;
            const float4* pa = (const float4*)(p + (size_t)first  * DDIM + k0);
            const float4* pb = (const float4*)(p + (size_t)second * DDIM + 64 + k0);
            const float4 a0 = pa[0], a1 = pa[1], b0 = pb[0], b1 = pb[1];
            float x[8] = { a0.x + b0.x, a0.y + b0.y, a0.z + b0.z, a0.w + b0.w,
                           a1.x + b1.x, a1.y + b1.y, a1.z + b1.z, a1.w + b1.w };
            s16x8 hi8, lo8;
            #pragma unroll
            for (int j = 0; j < 8; ++j) {
                const float v = gelu_fast(x[j]);
                u16 hb = f2bf(v);
                hi8[j] = (short)hb;
                lo8[j] = (short)f2bf(v - bf2f(hb));
            }
            const int off = (kt * 8 + w) * 512 + lane * 8;
            *(s16x8*)(smA + off)        = hi8;
            *(s16x8*)(smA + 8192 + off) = lo8;
        }
    }
    // no barrier: wave w staged exactly the segments (kt*8+w) it reads.

    // ---- 3 hidden layers ----
    const int mt = w;
    for (int L = 0; L < 3; ++L) {
        f32x4 acc[4];
        #pragma unroll
        for (int nt = 0; nt < 4; ++nt) {
            const float bv = bhid[L * 64 + nt * 16 + (lane & 15)];
            acc[nt] = (f32x4){bv, bv, bv, bv};
        }
        #pragma unroll
        for (int kt = 0; kt < 2; ++kt) {
            const s16x8 aH = *(const s16x8*)(smA + (kt * 8 + mt) * 512 + lane * 8);
            const s16x8 aL = *(const s16x8*)(smA + 8192 + (kt * 8 + mt) * 512 + lane * 8);
            #pragma unroll
            for (int nt = 0; nt < 4; ++nt) {
                const int bidx = (L * 8 + kt * 4 + nt) * 64 + lane;
                const s16x8 bH = ((const s16x8*)BhH)[bidx];
                const s16x8 bL = ((const s16x8*)BhL)[bidx];
                acc[nt] = __builtin_amdgcn_mfma_f32_16x16x32_bf16(aH, bH, acc[nt], 0, 0, 0);
                acc[nt] = __builtin_amdgcn_mfma_f32_16x16x32_bf16(aH, bL, acc[nt], 0, 0, 0);
                acc[nt] = __builtin_amdgcn_mfma_f32_16x16x32_bf16(aL, bH, acc[nt], 0, 0, 0);
            }
        }
        // epilogue: gelu + scatter back into own A-frag segments (k = col).
        #pragma unroll
        for (int nt = 0; nt < 4; ++nt) {
            #pragma unroll
            for (int r = 0; r < 4; ++r) {
                const float v = gelu_fast(acc[nt][r]);
                const int ml  = (lane >> 4) * 4 + r;        // row within tile
                const int k   = nt * 16 + (lane & 15);      // col -> next k
                const int kt2 = k >> 5, gg = (k >> 3) & 3, j = k & 7;
                const int off = (kt2 * 8 + mt) * 512 + (ml + 16 * gg) * 8 + j;
                u16 hb = f2bf(v);
                smA[off]        = (short)hb;
                smA[8192 + off] = (short)f2bf(v - bf2f(hb));
            }
        }
    }

    // ---- out layer: N=128 ----
    f32x4 acc2[8];
    #pragma unroll
    for (int nt = 0; nt < 8; ++nt) {
        const float bv = bout[nt * 16 + (lane & 15)];
        acc2[nt] = (f32x4){bv, bv, bv, bv};
    }
    #pragma unroll
    for (int kt = 0; kt < 2; ++kt) {
        const s16x8 aH = *(const s16x8*)(smA + (kt * 8 + mt) * 512 + lane * 8);
        const s16x8 aL = *(const s16x8*)(smA + 8192 + (kt * 8 + mt) * 512 + lane * 8);
        #pragma unroll
        for (int nt = 0; nt < 8; ++nt) {
            const int bidx = (kt * 8 + nt) * 64 + lane;
            const s16x8 bH = ((const s16x8*)BoH)[bidx];
            const s16x8 bL = ((const s16x8*)BoL)[bidx];
            acc2[nt] = __builtin_amdgcn_mfma_f32_16x16x32_bf16(aH, bH, acc2[nt], 0, 0, 0);
            acc2[nt] = __builtin_amdgcn_mfma_f32_16x16x32_bf16(aH, bL, acc2[nt], 0, 0, 0);
            acc2[nt] = __builtin_amdgcn_mfma_f32_16x16x32_bf16(aL, bH, acc2[nt], 0, 0, 0);
        }
    }

    // ---- fused segmented reduction: 2 rounds x 4-wave dumps ----
    int   runSeg = -2;
    float runacc = 0.0f;
    bool  leftC  = true;
    for (int b2 = 0; b2 < 2; ++b2) {
        __syncthreads();              // smA A-frag reads done / prev walk done
        if ((w >> 2) == b2) {
            const int rbase = (w & 3) * 16;
            #pragma unroll
            for (int nt = 0; nt < 8; ++nt)
                #pragma unroll
                for (int r = 0; r < 4; ++r)
                    scat[(rbase + (lane >> 4) * 4 + r) * 132 + nt * 16 + (lane & 15)]
                        = acc2[nt][r];
        }
        __syncthreads();
        if (tid < 128) {
            for (int r = 0; r < 64; ++r) {
                const int rowi = b2 * 64 + r;
                const int sg = segLDS[rowi];
                const float v = scat[r * 132 + tid];
                if (sg != runSeg) {
                    if (runSeg >= 0) {
                        float* pp = sbuf + (size_t)runSeg * DDIM + tid;
                        if (leftC) *pp = runacc;
                        else       atomicAdd(pp, runacc);
                    }
                    runSeg = sg;
                    runacc = v;
                    leftC  = (rowi == 0) ? (segedge[0] != sg) : true;
                } else {
                    runacc += v;
                }
            }
        }
    }
    if (tid < 128 && runSeg >= 0) {
        const bool rightC = (segedge[1] != runSeg);
        float* pp = sbuf + (size_t)runSeg * DDIM + tid;
        if (leftC && rightC) *pp = runacc;
        else                 atomicAdd(pp, runacc);
    }
}

// ---------------------------------------------------------------------------
// MFMA GRU + fused node_pre, R23: K-split staging in one 32KB LDS buffer.
// 256 thr / 4 waves / 64 nodes; wave w: jg=w&1, mh=w>>1 (2 m-frags).
// ks=0 stages msum*ci (k 0..127, feeds z,r,xh); ks=1 stages h (k 128..255,
// feeds z,r,hh). Epilogue reads hv from resident LDS half (hi+lo).
// ---------------------------------------------------------------------------
__global__ __launch_bounds__(256, 3) void gru_mfma_kernel(
    const float* __restrict__ h, float* __restrict__ msum,
    const int* __restrict__ deg,
    const u16* __restrict__ BgH, const u16* __restrict__ BgL,
    const float* __restrict__ bi_, const float* __restrict__ br_,
    const u16* __restrict__ BpH, const u16* __restrict__ BpL,
    const float* __restrict__ binp,
    float* __restrict__ hout)
{
    __shared__ short sm[16384];   // 32 KB: hi [0,8192), lo [8192,16384)
    const int tid  = threadIdx.x;
    const int lane = tid & 63;
    const int w    = tid >> 6;    // 0..3
    const int jg   = w & 1;
    const int mh   = w >> 1;      // m-half
    const int nbase = blockIdx.x * 64;

    // staging coords: thread covers row mS, lane-quarter q
    const int mS = tid >> 2, q = tid & 3;
    const int nodeS = nbase + mS;
    const int laneS = (mS & 15) + 16 * q;
    const int seg_m = mS >> 4;
    const int dg = deg[nodeS];
    const float ci = (dg > 0) ? (1.0f / (float)dg) : 0.0f;

    f32x4 acc[2][4][4];
    #pragma unroll
    for (int mf = 0; mf < 2; ++mf)
        #pragma unroll
        for (int g = 0; g < 4; ++g)
            #pragma unroll
            for (int t4 = 0; t4 < 4; ++t4)
                acc[mf][g][t4] = (f32x4){0.f, 0.f, 0.f, 0.f};

    const s16x8* Bh8 = (const s16x8*)BgH;
    const s16x8* Bl8 = (const s16x8*)BgL;

    #pragma unroll
    for (int ks = 0; ks < 2; ++ks) {
        // ---- stage k-half ks (128 k) into 32KB buffer ----
        #pragma unroll
        for (int c = 0; c < 4; ++c) {
            const int kl = (c * 4 + q) * 8;                   // 0..120
            const float* src = (ks == 0)
                ? (msum + (size_t)nodeS * DDIM + kl)
                : (h    + (size_t)nodeS * DDIM + kl);
            const float4 v0 = ((const float4*)src)[0];
            const float4 v1 = ((const float4*)src)[1];
            const float sc = (ks == 0) ? ci : 1.0f;
            float xv[8] = { v0.x * sc, v0.y * sc, v0.z * sc, v0.w * sc,
                            v1.x * sc, v1.y * sc, v1.z * sc, v1.w * sc };
            s16x8 hi8, lo8;
            #pragma unroll
            for (int i = 0; i < 8; ++i) {
                u16 hb = f2bf(xv[i]);
                hi8[i] = (short)hb;
                lo8[i] = (short)f2bf(xv[i] - bf2f(hb));
            }
            const int off = (c * 4 + seg_m) * 512 + laneS * 8;
            *(s16x8*)(sm + off)        = hi8;
            *(s16x8*)(sm + 8192 + off) = lo8;
        }
        __syncthreads();

        // ---- gate GEMM over this half (z,r always; xh ks0 / hh ks1) ----
        #pragma unroll
        for (int kt = 0; kt < 4; ++kt) {
            const int ktG = ks * 4 + kt;
            const int a0off = (kt * 4 + 2 * mh) * 512 + lane * 8;
            const s16x8 aH0 = *(const s16x8*)(sm + a0off);
            const s16x8 aL0 = *(const s16x8*)(sm + 8192 + a0off);
            const s16x8 aH1 = *(const s16x8*)(sm + a0off + 512);
            const s16x8 aL1 = *(const s16x8*)(sm + 8192 + a0off + 512);
            #pragma unroll
            for (int g = 0; g < 4; ++g) {
                if (g == 2 && ks == 1) continue;   // xh: k<128 only
                if (g == 3 && ks == 0) continue;   // hh: k>=128 only
                #pragma unroll
                for (int t4 = 0; t4 < 4; ++t4) {
                    const int idx = (ktG * 32 + g * 8 + jg * 4 + t4) * 64 + lane;
                    const s16x8 bH = Bh8[idx];
                    const s16x8 bL = Bl8[idx];
                    acc[0][g][t4] = __builtin_amdgcn_mfma_f32_16x16x32_bf16(aH0, bH, acc[0][g][t4], 0, 0, 0);
                    acc[0][g][t4] = __builtin_amdgcn_mfma_f32_16x16x32_bf16(aH0, bL, acc[0][g][t4], 0, 0, 0);
                    acc[0][g][t4] = __builtin_amdgcn_mfma_f32_16x16x32_bf16(aL0, bH, acc[0][g][t4], 0, 0, 0);
                    acc[1][g][t4] = __builtin_amdgcn_mfma_f32_16x16x32_bf16(aH1, bH, acc[1][g][t4], 0, 0, 0);
                    acc[1][g][t4] = __builtin_amdgcn_mfma_f32_16x16x32_bf16(aH1, bL, acc[1][g][t4], 0, 0, 0);
                    acc[1][g][t4] = __builtin_amdgcn_mfma_f32_16x16x32_bf16(aL1, bH, acc[1][g][t4], 0, 0, 0);
                }
            }
        }
        if (ks == 0) __syncthreads();   // all reads of half 0 done before restage
    }

    // ---- gate epilogue -> h'; hv reconstructed from resident LDS h-half ----
    float hn[2][4][4];
    #pragma unroll
    for (int t4 = 0; t4 < 4; ++t4) {
        const int j = jg * 64 + t4 * 16 + (lane & 15);
        const float b_az = bi_[j]       + br_[j];
        const float b_ar = bi_[128 + j] + br_[128 + j];
        const float b_xh = bi_[256 + j];
        const float b_hh = br_[256 + j];
        // LDS offset of element (m, k=j) in the staged h-half:
        const int jbase = (j >> 5) * 2048 + ((j >> 3) & 3) * 128 + (j & 7);
        #pragma unroll
        for (int mf = 0; mf < 2; ++mf) {
            const int mtile = 2 * mh + mf;
            #pragma unroll
            for (int r = 0; r < 4; ++r) {
                const int m15 = (lane >> 4) * 4 + r;
                const int off = jbase + mtile * 512 + m15 * 8;
                const float hv = bf2f((u16)sm[off]) + bf2f((u16)sm[8192 + off]);
                const int m = mtile * 16 + m15;
                const float az = acc[mf][0][t4][r] + b_az;
                const float ar = acc[mf][1][t4][r] + b_ar;
                const float xh = acc[mf][2][t4][r] + b_xh;
                const float hh = acc[mf][3][t4][r] + b_hh;
                const float z    = sigmoid_fast(az);
                const float rr   = sigmoid_fast(ar);
                const float cand = tanh_fast(xh + rr * hh);
                const float v    = z * hv + (1.0f - z) * cand;
                hout[(size_t)(nbase + m) * DDIM + j] = v;
                hn[mf][t4][r] = v;
            }
        }
    }

    __syncthreads();   // epilogue LDS reads done; reuse sm for pre-A frags

    // scatter h' into node_pre A-frag layout (k = j, same frag map)
    #pragma unroll
    for (int mf = 0; mf < 2; ++mf) {
        const int mtile = 2 * mh + mf;
        #pragma unroll
        for (int t4 = 0; t4 < 4; ++t4) {
            #pragma unroll
            for (int r = 0; r < 4; ++r) {
                const int m  = mtile * 16 + (lane >> 4) * 4 + r;
                const int j  = jg * 64 + t4 * 16 + (lane & 15);
                const int kt2 = j >> 5, gg = (j >> 3) & 3, jj = j & 7;
                const int lane2 = (m & 15) + 16 * gg;
                const int off = (kt2 * 4 + mtile) * 512 + lane2 * 8 + jj;
                const float v = hn[mf][t4][r];
                u16 hb = f2bf(v);
                sm[off]        = (short)hb;
                sm[off + 8192] = (short)f2bf(v - bf2f(hb));
            }
        }
    }
    __syncthreads();

    // ---- node_pre GEMM -> p (into msum) ----
    f32x4 acc2[2][4];
    #pragma unroll
    for (int mf = 0; mf < 2; ++mf)
        #pragma unroll
        for (int t4 = 0; t4 < 4; ++t4)
            acc2[mf][t4] = (f32x4){0.f, 0.f, 0.f, 0.f};

    const s16x8* Ph8 = (const s16x8*)BpH;
    const s16x8* Pl8 = (const s16x8*)BpL;
    #pragma unroll
    for (int kt2 = 0; kt2 < 4; ++kt2) {
        const int a0off = (kt2 * 4 + 2 * mh) * 512 + lane * 8;
        const s16x8 aH0 = *(const s16x8*)(sm + a0off);
        const s16x8 aL0 = *(const s16x8*)(sm + 8192 + a0off);
        const s16x8 aH1 = *(const s16x8*)(sm + a0off + 512);
        const s16x8 aL1 = *(const s16x8*)(sm + 8192 + a0off + 512);
        #pragma unroll
        for (int t4 = 0; t4 < 4; ++t4) {
            const int idx = (kt2 * 8 + jg * 4 + t4) * 64 + lane;
            const s16x8 bH = Ph8[idx];
            const s16x8 bL = Pl8[idx];
            acc2[0][t4] = __builtin_amdgcn_mfma_f32_16x16x32_bf16(aH0, bH, acc2[0][t4], 0, 0, 0);
            acc2[0][t4] = __builtin_amdgcn_mfma_f32_16x16x32_bf16(aH0, bL, acc2[0][t4], 0, 0, 0);
            acc2[0][t4] = __builtin_amdgcn_mfma_f32_16x16x32_bf16(aL0, bH, acc2[0][t4], 0, 0, 0);
            acc2[1][t4] = __builtin_amdgcn_mfma_f32_16x16x32_bf16(aH1, bH, acc2[1][t4], 0, 0, 0);
            acc2[1][t4] = __builtin_amdgcn_mfma_f32_16x16x32_bf16(aH1, bL, acc2[1][t4], 0, 0, 0);
            acc2[1][t4] = __builtin_amdgcn_mfma_f32_16x16x32_bf16(aL1, bH, acc2[1][t4], 0, 0, 0);
        }
    }
    #pragma unroll
    for (int mf = 0; mf < 2; ++mf) {
        const int mtile = 2 * mh + mf;
        #pragma unroll
        for (int t4 = 0; t4 < 4; ++t4) {
            const int n = jg * 64 + t4 * 16 + (lane & 15);
            const float badd = (n < 64) ? binp[n] : 0.0f;
            #pragma unroll
            for (int r = 0; r < 4; ++r) {
                const int m = mtile * 16 + (lane >> 4) * 4 + r;
                msum[(size_t)(nbase + m) * DDIM + n] = acc2[mf][t4][r] + badd;
            }
        }
    }
}

// Readout: block=64, LDS activation slices, scalar weights.
__global__ __launch_bounds__(64) void readout_kernel(
    const float* __restrict__ h,
    const float* __restrict__ Win,  const float* __restrict__ bin,
    const float* __restrict__ Whid, const float* __restrict__ bhid,
    const float* __restrict__ Wout, const float* __restrict__ bout,
    float* __restrict__ out)
{
    __shared__ float xs[64 * 65];
    const int tid = threadIdx.x;
    const int row = blockIdx.x * 64 + tid;
    const int b = row / 1000, n = row % 1000;
    const float4* xrow = (const float4*)(h + ((size_t)b * 4000 + n) * DDIM);

    {
        float acc[64];
        #pragma unroll
        for (int j = 0; j < 64; ++j) acc[j] = bin[j];
        #pragma unroll 2
        for (int k4 = 0; k4 < 32; ++k4) {
            float4 xv = xrow[k4];
            #pragma unroll
            for (int kk = 0; kk < 4; ++kk) {
                const float xk = (&xv.x)[kk];
                const float* wr = Win + (size_t)(k4 * 4 + kk) * 64;
                #pragma unroll
                for (int j = 0; j < 64; ++j) acc[j] = fmaf(xk, wr[j], acc[j]);
            }
        }
        #pragma unroll
        for (int j = 0; j < 64; ++j) xs[tid * 65 + j] = gelu_exact(acc[j]);
    }

    for (int L = 0; L < 3; ++L) {
        float acc[64];
        #pragma unroll
        for (int j = 0; j < 64; ++j) acc[j] = bhid[L * 64 + j];
        #pragma unroll 4
        for (int k = 0; k < 64; ++k) {
            const float xk = xs[tid * 65 + k];
            const float* wr = Whid + (size_t)L * 4096 + (size_t)k * 64;
            #pragma unroll
            for (int j = 0; j < 64; ++j) acc[j] = fmaf(xk, wr[j], acc[j]);
        }
        #pragma unroll
        for (int j = 0; j < 64; ++j) xs[tid * 65 + j] = gelu_exact(acc[j]);
    }

    float acc[10];
    #pragma unroll
    for (int pj = 0; pj < 10; ++pj) acc[pj] = bout[pj];
    #pragma unroll 4
    for (int k = 0; k < 64; ++k) {
        const float xk = xs[tid * 65 + k];
        const float* wr = Wout + k * 10;
        #pragma unroll
        for (int pj = 0; pj < 10; ++pj) acc[pj] = fmaf(xk, wr[pj], acc[pj]);
    }
    #pragma unroll
    for (int pj = 0; pj < 10; ++pj) out[(size_t)row * 10 + pj] = acc[pj];
}

extern "C" void kernel_launch(void* const* d_in, const int* in_sizes, int n_in,
                              void* d_out, int out_size, void* d_ws, size_t ws_size,
                              hipStream_t stream) {
    const int*   node_inputs = (const int*)d_in[0];
    const int*   ni_int = (const int*)d_in[1];
    const int*   bi_int = (const int*)d_in[2];
    const int*   ni_tmp = (const int*)d_in[3];
    const int*   bi_tmp = (const int*)d_in[4];
    const float* embed  = (const float*)d_in[5];
    const float* mWin   = (const float*)d_in[6];
    const float* mbin   = (const float*)d_in[7];
    const float* mWhid  = (const float*)d_in[8];
    const float* mbhid  = (const float*)d_in[9];
    const float* mWout  = (const float*)d_in[10];
    const float* mbout  = (const float*)d_in[11];
    const float* roWin  = (const float*)d_in[12];
    const float* robin  = (const float*)d_in[13];
    const float* roWhid = (const float*)d_in[14];
    const float* robhid = (const float*)d_in[15];
    const float* roWout = (const float*)d_in[16];
    const float* robout = (const float*)d_in[17];
    const float* giWx = (const float*)d_in[18];
    const float* giWh = (const float*)d_in[19];
    const float* gibi = (const float*)d_in[20];
    const float* gibr = (const float*)d_in[21];
    const float* gtWx = (const float*)d_in[22];
    const float* gtWh = (const float*)d_in[23];
    const float* gtbi = (const float*)d_in[24];
    const float* gtbr = (const float*)d_in[25];
    float* out = (float*)d_out;

    const int E_INT = 200000, E_TMP = 96000;
    const int NSLOT_I = 400000;   // 3125*128 exact
    const int NSLOT_T = 192000;   // 1500*128 exact
    const int NBLK_I = NSLOT_I / EBLK;
    const int NBLK_T = NSLOT_T / EBLK;

    char* ws = (char*)d_ws;
    float* B0 = (float*)(ws);
    float* B1 = (float*)(ws + HBYTES);
    float* B2 = (float*)(ws + 2 * HBYTES);
    char*  ib = ws + 3 * HBYTES;

    int* deg_i   = (int*)(ib);
    int* deg_t   = (int*)(ib + 512000);
    int* offp_i  = (int*)(ib + 1024000);
    int* offp_t  = (int*)(ib + 1536000);
    int* bexc_i  = (int*)(ib + 2048000);
    int* bexc_t  = (int*)(ib + 2052096);
    int* bsum    = (int*)(ib + 2056192);
    int* cursor  = (int*)(ib + 2060288);
    int* el_i    = (int*)(ib + 2572288);
    int* el_t    = (int*)(ib + 4172288);
    int* ssi_raw = (int*)(ib + 4940288);
    int* sst_raw = (int*)(ib + 6540296);
    int* str_i   = (int*)(ib + 8094784);
    int* str_t   = (int*)(ib + 8107384);
    int* strc_i  = (int*)(ib + 8113484);
    int* strc_t  = (int*)(ib + 8113488);
    // bf16-split B-fragment buffers
    char* fb = ib + 8114176;
    u16* BgiH = (u16*)(fb);
    u16* BgiL = (u16*)(fb +  262144);
    u16* BgtH = (u16*)(fb +  524288);
    u16* BgtL = (u16*)(fb +  786432);
    u16* BpH  = (u16*)(fb + 1048576);
    u16* BpL  = (u16*)(fb + 1081344);
    u16* EhH  = (u16*)(fb + 1114112);   // 3*4096 elems = 24576 B
    u16* EhL  = (u16*)(fb + 1138688);
    u16* EoH  = (u16*)(fb + 1163264);   // 8192 elems = 16384 B
    u16* EoL  = (u16*)(fb + 1179648);
    int* ssi = ssi_raw + 1;
    int* sst = sst_raw + 1;

    embed_kernel<<<16000, 256, 0, stream>>>(node_inputs, embed, B0);

    hipMemsetAsync(deg_i, 0, NTOT * sizeof(int), stream);
    hipMemsetAsync(deg_t, 0, NTOT * sizeof(int), stream);
    hist_kernel<<<(2 * E_INT + 255) / 256, 256, 0, stream>>>(ni_int, bi_int, E_INT, deg_i);
    hist_kernel<<<(2 * E_TMP + 255) / 256, 256, 0, stream>>>(ni_tmp, bi_tmp, E_TMP, deg_t);

    hipMemsetAsync(ssi_raw, 0xFF, (size_t)(NSLOT_I + 2) * sizeof(int), stream);
    hipMemsetAsync(sst_raw, 0xFF, (size_t)(NSLOT_T + 2) * sizeof(int), stream);

    blockscan_kernel<<<500, 256, 0, stream>>>(deg_i, offp_i, bsum);
    bscan_kernel<<<1, 512, 0, stream>>>(bsum, bexc_i, 500);
    hipMemsetAsync(cursor, 0, NTOT * sizeof(int), stream);
    fill_kernel<<<(2 * E_INT + 255) / 256, 256, 0, stream>>>(
        ni_int, bi_int, E_INT, offp_i, bexc_i, cursor, el_i, ssi);

    blockscan_kernel<<<500, 256, 0, stream>>>(deg_t, offp_t, bsum);
    bscan_kernel<<<1, 512, 0, stream>>>(bsum, bexc_t, 500);
    hipMemsetAsync(cursor, 0, NTOT * sizeof(int), stream);
    fill_kernel<<<(2 * E_TMP + 255) / 256, 256, 0, stream>>>(
        ni_tmp, bi_tmp, E_TMP, offp_t, bexc_t, cursor, el_t, sst);

    hipMemsetAsync(strc_i, 0, sizeof(int), stream);
    hipMemsetAsync(strc_t, 0, sizeof(int), stream);
    straddle_kernel<<<(NBLK_I + 255) / 256, 256, 0, stream>>>(ssi, NBLK_I, str_i, strc_i);
    straddle_kernel<<<(NBLK_T + 255) / 256, 256, 0, stream>>>(sst, NBLK_T, str_t, strc_t);

    pack_gateB_kernel<<<512, 256, 0, stream>>>(giWx, giWh, BgiH, BgiL);
    pack_gateB_kernel<<<512, 256, 0, stream>>>(gtWx, gtWh, BgtH, BgtL);
    pack_preB_kernel<<<64, 256, 0, stream>>>(mWin, BpH, BpL);
    pack_hidB_kernel<<<48, 256, 0, stream>>>(mWhid, EhH, EhL);
    pack_outB_kernel<<<32, 256, 0, stream>>>(mWout, EoH, EoL);

    node_pre_kernel<<<NTOT / 256, 256, 0, stream>>>(B0, mWin, mbin, B1);

    // rotation: X=h, Y=p, Z=free
    float* X = B0; float* Y = B1; float* Z = B2;
    for (int ph = 0; ph < 4; ++ph) {
        const bool isInt = (ph % 2 == 0);
        if (isInt) {
            zero_rows_kernel<<<NBLK_I, 64, 0, stream>>>(str_i, strc_i, Z);
            edge_mlp_mfma<<<NBLK_I, 512, 0, stream>>>(
                ni_int, bi_int, E_INT, el_i, ssi, Y,
                EhH, EhL, mbhid, EoH, EoL, mbout, Z);
            gru_mfma_kernel<<<NTOT / 64, 256, 0, stream>>>(
                X, Z, deg_i, BgiH, BgiL, gibi, gibr, BpH, BpL, mbin, Y);
        } else {
            zero_rows_kernel<<<NBLK_T, 64, 0, stream>>>(str_t, strc_t, Z);
            edge_mlp_mfma<<<NBLK_T, 512, 0, stream>>>(
                ni_tmp, bi_tmp, E_TMP, el_t, sst, Y,
                EhH, EhL, mbhid, EoH, EoL, mbout, Z);
            gru_mfma_kernel<<<NTOT / 64, 256, 0, stream>>>(
                X, Z, deg_t, BgtH, BgtL, gtbi, gtbr, BpH, BpL, mbin, Y);
        }
        float* oldX = X;  X = Y;  Y = Z;  Z = oldX;
    }

    readout_kernel<<<500, 64, 0, stream>>>(
        X, roWin, robin, roWhid, robhid, roWout, robout, out);
}

// Round 5
// 1455.796 us; speedup vs baseline: 2.7432x; 1.1752x over previous
//
#include <hip/hip_runtime.h>
#include <math.h>

// MPNN on MI355X. R24 = R23 + out-layer hoist (linearity) + parallel walk
// + rcpf transcendentals.
// R23 counters: edge 200us VALUBusy 56 / MfmaUtil 10.5 -> VALU-bound on
// gelu divides, scalar scatter, serial walk. Changes:
//  (1) Sum(Wout@x + bout) = Wout@Sum(x) + deg*bout: edge now reduces
//      64-wide gelu(h3) into S (sbuf64); GRU gains a K=64 Wout MFMA phase
//      (reuses pack_outB + the validated C->A scatter map) producing m.
//      Buffer roles become FIXED: h in B0 (updated in place: each gru
//      block reads its own h rows in staging before the epilogue writes
//      them), p in B1, S in B2. No rotation.
//  (2) Edge reduction: single dump of all 8 waves into scat[128][68] f32
//      overlaying dead A-frags; 256 walkers x 32 rows with seam fixups.
//      Straddle detection moves to stride-32 boundaries (pre-zero+atomic,
//      same protocol as the validated 128-stride version).
//  (3) gelu/sigmoid/tanh divides -> __builtin_amdgcn_rcpf (1 ulp).
// Frag maps, hi/lo 3-term split, CSR machinery: unchanged (validated).

#define DDIM 128
#define NTOT 128000
#define HBYTES 65536000ULL   // 128000*128*4
#define EBLK 128

typedef unsigned short u16;
using f32x4 = __attribute__((ext_vector_type(4))) float;
using s16x8 = __attribute__((ext_vector_type(8))) short;

__device__ __forceinline__ float fast_rcp(float x) {
    return __builtin_amdgcn_rcpf(x);
}
__device__ __forceinline__ float gelu_exact(float x) {
    return 0.5f * x * (1.0f + erff(x * 0.70710678118654752440f));
}
// A&S 7.1.26 erf, |abs err| <= 1.5e-7; raw v_rcp (1 ulp) for the divide.
__device__ __forceinline__ float gelu_fast(float x) {
    const float ax = fabsf(x) * 0.70710678118654752440f;
    const float t  = fast_rcp(1.0f + 0.3275911f * ax);
    const float poly = t * (0.254829592f + t * (-0.284496736f +
                       t * (1.421413741f + t * (-1.453152027f +
                       t * 1.061405429f))));
    const float e = __expf(-ax * ax);
    const float erfax = 1.0f - poly * e;
    const float erfv = copysignf(erfax, x);
    return 0.5f * x * (1.0f + erfv);
}
__device__ __forceinline__ float sigmoid_fast(float x) {
    return fast_rcp(1.0f + __expf(-x));
}
__device__ __forceinline__ float tanh_fast(float x) {
    const float e = __expf(2.0f * x);     // tanh = 1 - 2/(e^{2x}+1)
    return 1.0f - 2.0f * fast_rcp(e + 1.0f);
}
__device__ __forceinline__ u16 f2bf(float x) {            // RNE f32->bf16
    unsigned u = __float_as_uint(x);
    u += 0x7fffu + ((u >> 16) & 1u);
    return (u16)(u >> 16);
}
__device__ __forceinline__ float bf2f(u16 h) {
    return __uint_as_float(((unsigned)h) << 16);
}

__global__ __launch_bounds__(256) void embed_kernel(
    const int* __restrict__ inp, const float* __restrict__ table,
    float* __restrict__ h)
{
    int gid = blockIdx.x * 256 + threadIdx.x;
    if (gid >= NTOT * 32) return;
    int row = gid >> 5;
    int q   = gid & 31;
    int b   = row / 4000;
    int n   = (row % 4000) % 1000;
    int e   = inp[b * 1000 + n];
    ((float4*)h)[gid] = ((const float4*)table)[e * 32 + q];
}

__global__ __launch_bounds__(256) void hist_kernel(
    const int* __restrict__ ni, const int* __restrict__ bi, int E,
    int* __restrict__ deg)
{
    int g = blockIdx.x * 256 + threadIdx.x;
    if (g < E)          atomicAdd(&deg[bi[g]], 1);
    else if (g < 2 * E) atomicAdd(&deg[ni[g - E]], 1);
}

__global__ __launch_bounds__(256) void blockscan_kernel(
    const int* __restrict__ deg, int* __restrict__ offp, int* __restrict__ bsum)
{
    __shared__ int s[256];
    int tid = threadIdx.x;
    int i = blockIdx.x * 256 + tid;
    int v = deg[i];
    s[tid] = v;
    __syncthreads();
    for (int off = 1; off < 256; off <<= 1) {
        int t = (tid >= off) ? s[tid - off] : 0;
        __syncthreads();
        s[tid] += t;
        __syncthreads();
    }
    offp[i] = s[tid] - v;
    if (tid == 255) bsum[blockIdx.x] = s[255];
}

__global__ __launch_bounds__(512) void bscan_kernel(
    const int* __restrict__ bsum, int* __restrict__ bexc, int nb)
{
    __shared__ int s[512];
    int t = threadIdx.x;
    int v = (t < nb) ? bsum[t] : 0;
    s[t] = v;
    __syncthreads();
    for (int off = 1; off < 512; off <<= 1) {
        int u = (t >= off) ? s[t - off] : 0;
        __syncthreads();
        s[t] += u;
        __syncthreads();
    }
    if (t < nb) bexc[t] = s[t] - v;
}

__global__ __launch_bounds__(256) void fill_kernel(
    const int* __restrict__ ni, const int* __restrict__ bi, int E,
    const int* __restrict__ offp, const int* __restrict__ bexc,
    int* __restrict__ cursor, int* __restrict__ elist, int* __restrict__ slotseg)
{
    int g = blockIdx.x * 256 + threadIdx.x;
    if (g >= 2 * E) return;
    int seg = (g < E) ? bi[g] : ni[g - E];
    int pos = atomicAdd(&cursor[seg], 1);
    int slot = offp[seg] + bexc[seg >> 8] + pos;
    elist[slot] = g;
    slotseg[slot] = seg;
}

// Segments straddling a 32-slot boundary (walk-quarter seams AND block
// edges) — the only atomicAdd targets; their S rows are pre-zeroed.
__global__ __launch_bounds__(256) void straddle_kernel(
    const int* __restrict__ slotseg, int nblocks32,
    int* __restrict__ list, int* __restrict__ count)
{
    int b = blockIdx.x * 256 + threadIdx.x + 1;
    if (b >= nblocks32) return;
    int s = slotseg[b * 32];
    if (s >= 0 && slotseg[b * 32 - 1] == s) {
        int pos = atomicAdd(count, 1);
        list[pos] = s;
    }
}

__global__ __launch_bounds__(64) void zero_rows_kernel(
    const int* __restrict__ list, const int* __restrict__ count,
    float* __restrict__ sbuf)   // 64-wide rows
{
    int i = blockIdx.x;
    if (i >= *count) return;
    int seg = list[i];
    float4* row = (float4*)(sbuf + (size_t)seg * 64);
    if (threadIdx.x < 16) row[threadIdx.x] = make_float4(0.f, 0.f, 0.f, 0.f);
}

// ---------------------------------------------------------------------------
// B-fragment packers (run once per launch). Shared frag map:
// lane l, elem j -> k = kt*32+(l>>4)*8+j, n = nt*16+(l&15).
// ---------------------------------------------------------------------------
__global__ __launch_bounds__(256) void pack_gateB_kernel(
    const float* __restrict__ Wx, const float* __restrict__ Wh,
    u16* __restrict__ BH, u16* __restrict__ BL)
{
    int idx = blockIdx.x * 256 + threadIdx.x;   // 131072 total
    if (idx >= 131072) return;
    int j    = idx & 7;
    int lane = (idx >> 3) & 63;
    int ntG  = (idx >> 9) & 31;
    int ktG  = idx >> 14;                        // 0..7
    int k = ktG * 32 + (lane >> 4) * 8 + j;      // 0..255
    int n = ntG * 16 + (lane & 15);              // 0..511
    int g = n >> 7, jj = n & 127;
    float v;
    if (g == 0)      v = (k < 128) ? Wx[k * 384 + jj]       : Wh[(k - 128) * 384 + jj];
    else if (g == 1) v = (k < 128) ? Wx[k * 384 + 128 + jj] : Wh[(k - 128) * 384 + 128 + jj];
    else if (g == 2) v = (k < 128) ? Wx[k * 384 + 256 + jj] : 0.0f;
    else             v = (k < 128) ? 0.0f                   : Wh[(k - 128) * 384 + 256 + jj];
    u16 hb = f2bf(v);
    BH[idx] = hb;
    BL[idx] = f2bf(v - bf2f(hb));
}

// node_pre B: [K=128][N=128], n<64 -> Win rows 0..127, n>=64 -> rows 128..255.
__global__ __launch_bounds__(256) void pack_preB_kernel(
    const float* __restrict__ Win, u16* __restrict__ BH, u16* __restrict__ BL)
{
    int idx = blockIdx.x * 256 + threadIdx.x;   // 16384 total
    if (idx >= 16384) return;
    int j    = idx & 7;
    int lane = (idx >> 3) & 63;
    int nt2  = (idx >> 9) & 7;
    int kt2  = idx >> 12;                        // 0..3
    int k = kt2 * 32 + (lane >> 4) * 8 + j;      // 0..127
    int n = nt2 * 16 + (lane & 15);              // 0..127
    float v = (n < 64) ? Win[k * 64 + n] : Win[(128 + k) * 64 + (n - 64)];
    u16 hb = f2bf(v);
    BH[idx] = hb;
    BL[idx] = f2bf(v - bf2f(hb));
}

// Edge-MLP hidden B: 3 layers x [K=64][N=64]. idx=(L*8+kt*4+nt)*512+lane*8+j.
__global__ __launch_bounds__(256) void pack_hidB_kernel(
    const float* __restrict__ Whid, u16* __restrict__ BH, u16* __restrict__ BL)
{
    int idx = blockIdx.x * 256 + threadIdx.x;   // 12288 total
    if (idx >= 12288) return;
    int j    = idx & 7;
    int lane = (idx >> 3) & 63;
    int nt   = (idx >> 9) & 3;
    int kt   = (idx >> 11) & 1;
    int L    = idx >> 12;
    int k = kt * 32 + (lane >> 4) * 8 + j;       // 0..63
    int n = nt * 16 + (lane & 15);               // 0..63
    float v = Whid[L * 4096 + k * 64 + n];
    u16 hb = f2bf(v);
    BH[idx] = hb;
    BL[idx] = f2bf(v - bf2f(hb));
}

// Wout B: [K=64][N=128]. idx=(kt*8+nt)*512+lane*8+j. (consumed by GRU now)
__global__ __launch_bounds__(256) void pack_outB_kernel(
    const float* __restrict__ Wout, u16* __restrict__ BH, u16* __restrict__ BL)
{
    int idx = blockIdx.x * 256 + threadIdx.x;   // 8192 total
    if (idx >= 8192) return;
    int j    = idx & 7;
    int lane = (idx >> 3) & 63;
    int nt   = (idx >> 9) & 7;
    int kt   = idx >> 12;                        // 0..1
    int k = kt * 32 + (lane >> 4) * 8 + j;       // 0..63
    int n = nt * 16 + (lane & 15);               // 0..127
    float v = Wout[k * 128 + n];
    u16 hb = f2bf(v);
    BH[idx] = hb;
    BL[idx] = f2bf(v - bf2f(hb));
}

// Initial p only: p[v][0:64)=Wtop@h[v]+bin, p[v][64:128)=Wbot@h[v].
__global__ __launch_bounds__(256) void node_pre_kernel(
    const float* __restrict__ h, const float* __restrict__ Win,
    const float* __restrict__ bin, float* __restrict__ p)
{
    const int node = blockIdx.x * 256 + threadIdx.x;
    const float4* h4 = (const float4*)(h + (size_t)node * DDIM);
    float* prow = p + (size_t)node * DDIM;

    for (int c = 0; c < 4; ++c) {
        const int top   = (c < 2) ? 1 : 0;
        const int j0    = (c & 1) * 32;
        const int kbase = top ? 0 : 128;
        float acc[32];
        #pragma unroll
        for (int j = 0; j < 32; ++j) acc[j] = top ? bin[j0 + j] : 0.0f;
        for (int k4 = 0; k4 < 32; ++k4) {
            float4 hv = h4[k4];
            #pragma unroll
            for (int kk = 0; kk < 4; ++kk) {
                const float hk = (&hv.x)[kk];
                const float* wr = Win + (size_t)(kbase + k4 * 4 + kk) * 64 + j0;
                #pragma unroll
                for (int j = 0; j < 32; ++j) acc[j] = fmaf(hk, wr[j], acc[j]);
            }
        }
        float* dst = prow + (top ? 0 : 64) + j0;
        #pragma unroll
        for (int q = 0; q < 8; ++q)
            ((float4*)dst)[q] = make_float4(acc[q*4], acc[q*4+1],
                                            acc[q*4+2], acc[q*4+3]);
    }
}

// ---------------------------------------------------------------------------
// MFMA edge MLP, R24: 3 hidden layers only; reduces 64-wide gelu(h3) per
// segment into S (sbuf64). Single dump of all 8 waves into scat[128][68]
// overlaying dead A-frags; 256 walkers x 32 rows with seam fixups.
// ---------------------------------------------------------------------------
__global__ __launch_bounds__(512) void edge_mlp_mfma(
    const int* __restrict__ ni, const int* __restrict__ bi, int E,
    const int* __restrict__ elist, const int* __restrict__ slotseg,
    const float* __restrict__ p,
    const u16* __restrict__ BhH, const u16* __restrict__ BhL,
    const float* __restrict__ bhid,
    float* __restrict__ sbuf)
{
    __shared__ short smA[17408];      // 34816B; frags [0,16384) shorts
                                      // (hi [0,8192), lo [8192,16384));
                                      // later overlaid by scat[128][68] f32
    __shared__ int   segLDS[EBLK];
    __shared__ int   segedge[2];
    float* scat = (float*)smA;

    const int tid  = threadIdx.x;
    const int lane = tid & 63;
    const int w    = tid >> 6;        // wave = m-tile
    const int s0   = blockIdx.x * EBLK;

    if (tid < 128) segLDS[tid] = slotseg[s0 + tid];
    if (tid == 0) segedge[0] = slotseg[s0 - 1];
    if (tid == 1) segedge[1] = slotseg[s0 + EBLK];

    // ---- staging: thread covers slot m=(tid&15)+16*w, k-group gg=(tid>>4)&3
    {
        const int m  = (tid & 15) | (w << 4);
        const int gg = (tid >> 4) & 3;
        const int slot = s0 + m;
        const int g = elist[slot];
        int first, second;
        if (g < E) { first = ni[g];     second = bi[g];     }
        else       { first = bi[g - E]; second = ni[g - E]; }
        #pragma unroll
        for (int kt = 0; kt < 2; ++kt) {
            const int k0 = kt * 32 + gg * 8;
            const float4* pa = (const float4*)(p + (size_t)first  * DDIM + k0);
            const float4* pb = (const float4*)(p + (size_t)second * DDIM + 64 + k0);
            const float4 a0 = pa[0], a1 = pa[1], b0 = pb[0], b1 = pb[1];
            float x[8] = { a0.x + b0.x, a0.y + b0.y, a0.z + b0.z, a0.w + b0.w,
                           a1.x + b1.x, a1.y + b1.y, a1.z + b1.z, a1.w + b1.w };
            s16x8 hi8, lo8;
            #pragma unroll
            for (int j = 0; j < 8; ++j) {
                const float v = gelu_fast(x[j]);
                u16 hb = f2bf(v);
                hi8[j] = (short)hb;
                lo8[j] = (short)f2bf(v - bf2f(hb));
            }
            const int off = (kt * 8 + w) * 512 + lane * 8;
            *(s16x8*)(smA + off)        = hi8;
            *(s16x8*)(smA + 8192 + off) = lo8;
        }
    }
    // no barrier: wave w staged exactly the segments (kt*8+w) it reads.

    const int mt = w;
    // ---- hidden layers 0,1: frag-scatter epilogue ----
    for (int L = 0; L < 2; ++L) {
        f32x4 acc[4];
        #pragma unroll
        for (int nt = 0; nt < 4; ++nt) {
            const float bv = bhid[L * 64 + nt * 16 + (lane & 15)];
            acc[nt] = (f32x4){bv, bv, bv, bv};
        }
        #pragma unroll
        for (int kt = 0; kt < 2; ++kt) {
            const s16x8 aH = *(const s16x8*)(smA + (kt * 8 + mt) * 512 + lane * 8);
            const s16x8 aL = *(const s16x8*)(smA + 8192 + (kt * 8 + mt) * 512 + lane * 8);
            #pragma unroll
            for (int nt = 0; nt < 4; ++nt) {
                const int bidx = (L * 8 + kt * 4 + nt) * 64 + lane;
                const s16x8 bH = ((const s16x8*)BhH)[bidx];
                const s16x8 bL = ((const s16x8*)BhL)[bidx];
                acc[nt] = __builtin_amdgcn_mfma_f32_16x16x32_bf16(aH, bH, acc[nt], 0, 0, 0);
                acc[nt] = __builtin_amdgcn_mfma_f32_16x16x32_bf16(aH, bL, acc[nt], 0, 0, 0);
                acc[nt] = __builtin_amdgcn_mfma_f32_16x16x32_bf16(aL, bH, acc[nt], 0, 0, 0);
            }
        }
        #pragma unroll
        for (int nt = 0; nt < 4; ++nt) {
            #pragma unroll
            for (int r = 0; r < 4; ++r) {
                const float v = gelu_fast(acc[nt][r]);
                const int ml  = (lane >> 4) * 4 + r;
                const int k   = nt * 16 + (lane & 15);
                const int kt2 = k >> 5, gg = (k >> 3) & 3, j = k & 7;
                const int off = (kt2 * 8 + mt) * 512 + (ml + 16 * gg) * 8 + j;
                u16 hb = f2bf(v);
                smA[off]        = (short)hb;
                smA[8192 + off] = (short)f2bf(v - bf2f(hb));
            }
        }
    }

    // ---- hidden layer 2: gelu into registers (dump after barrier) ----
    float gl[4][4];
    {
        f32x4 acc[4];
        #pragma unroll
        for (int nt = 0; nt < 4; ++nt) {
            const float bv = bhid[2 * 64 + nt * 16 + (lane & 15)];
            acc[nt] = (f32x4){bv, bv, bv, bv};
        }
        #pragma unroll
        for (int kt = 0; kt < 2; ++kt) {
            const s16x8 aH = *(const s16x8*)(smA + (kt * 8 + mt) * 512 + lane * 8);
            const s16x8 aL = *(const s16x8*)(smA + 8192 + (kt * 8 + mt) * 512 + lane * 8);
            #pragma unroll
            for (int nt = 0; nt < 4; ++nt) {
                const int bidx = (2 * 8 + kt * 4 + nt) * 64 + lane;
                const s16x8 bH = ((const s16x8*)BhH)[bidx];
                const s16x8 bL = ((const s16x8*)BhL)[bidx];
                acc[nt] = __builtin_amdgcn_mfma_f32_16x16x32_bf16(aH, bH, acc[nt], 0, 0, 0);
                acc[nt] = __builtin_amdgcn_mfma_f32_16x16x32_bf16(aH, bL, acc[nt], 0, 0, 0);
                acc[nt] = __builtin_amdgcn_mfma_f32_16x16x32_bf16(aL, bH, acc[nt], 0, 0, 0);
            }
        }
        #pragma unroll
        for (int nt = 0; nt < 4; ++nt)
            #pragma unroll
            for (int r = 0; r < 4; ++r)
                gl[nt][r] = gelu_fast(acc[nt][r]);
    }

    __syncthreads();   // all frag reads done before scat overlays them
    #pragma unroll
    for (int nt = 0; nt < 4; ++nt)
        #pragma unroll
        for (int r = 0; r < 4; ++r)
            scat[(mt * 16 + (lane >> 4) * 4 + r) * 68 + nt * 16 + (lane & 15)]
                = gl[nt][r];
    __syncthreads();

    // ---- parallel segmented reduction: 256 walkers x 32 rows ----
    if (tid < 256) {
        const int col = tid & 63;
        const int r0  = (tid >> 6) * 32;
        const int r1  = r0 + 32;
        int   runSeg = -2;
        float runacc = 0.0f;
        bool  leftC  = true;
        for (int rowi = r0; rowi < r1; ++rowi) {
            const int sg = segLDS[rowi];
            const float v = scat[rowi * 68 + col];
            if (sg != runSeg) {
                if (runSeg >= 0) {
                    float* pp = sbuf + (size_t)runSeg * 64 + col;
                    if (leftC) *pp = runacc;
                    else       atomicAdd(pp, runacc);
                }
                runSeg = sg;
                runacc = v;
                if (rowi == r0) {
                    const int prev = (rowi == 0) ? segedge[0] : segLDS[rowi - 1];
                    leftC = (prev != sg);
                } else {
                    leftC = true;
                }
            } else {
                runacc += v;
            }
        }
        if (runSeg >= 0) {
            const int nxt = (r1 == 128) ? segedge[1] : segLDS[r1];
            const bool rightC = (nxt != runSeg);
            float* pp = sbuf + (size_t)runSeg * 64 + col;
            if (leftC && rightC) *pp = runacc;
            else                 atomicAdd(pp, runacc);
        }
    }
}

// ---------------------------------------------------------------------------
// MFMA GRU, R24: Wout-phase (m = Wout@(S*ci) + bout) + gates + in-place h
// update + fused node_pre. 256 thr / 4 waves / 64 nodes per block.
// wave w: jg=w&1, mh=w>>1 (m-tiles 2mh,2mh+1). LDS 32KB (+ci) -> 3 blk/CU.
// ---------------------------------------------------------------------------
__global__ __launch_bounds__(256, 3) void gru_mfma_kernel(
    float* __restrict__ hio, const float* __restrict__ Ssum,
    const int* __restrict__ deg,
    const u16* __restrict__ WoH, const u16* __restrict__ WoL,
    const float* __restrict__ bo,
    const u16* __restrict__ BgH, const u16* __restrict__ BgL,
    const float* __restrict__ bi_, const float* __restrict__ br_,
    const u16* __restrict__ BpH, const u16* __restrict__ BpL,
    const float* __restrict__ binp,
    float* __restrict__ pout)
{
    __shared__ short sm[16384];   // 32 KB: hi [0,8192), lo [8192,16384) shorts
    __shared__ float ci_s[64];
    const int tid  = threadIdx.x;
    const int lane = tid & 63;
    const int w    = tid >> 6;    // 0..3
    const int jg   = w & 1;
    const int mh   = w >> 1;      // m-half
    const int nbase = blockIdx.x * 64;

    // staging coords: thread covers row mS, lane-quarter q
    const int mS = tid >> 2, q = tid & 3;
    const int nodeS = nbase + mS;
    const int laneS = (mS & 15) + 16 * q;
    const int seg_m = mS >> 4;
    const int dg = deg[nodeS];
    const float ci = (dg > 0) ? fast_rcp((float)dg) : 0.0f;
    ci_s[mS] = ci;

    // ---- Phase A: stage S*ci fragments (K=64) ----
    #pragma unroll
    for (int c = 0; c < 2; ++c) {
        const int kl = c * 32 + q * 8;
        const float* src = Ssum + (size_t)nodeS * 64 + kl;
        const float4 v0 = ((const float4*)src)[0];
        const float4 v1 = ((const float4*)src)[1];
        float xv[8] = { v0.x * ci, v0.y * ci, v0.z * ci, v0.w * ci,
                        v1.x * ci, v1.y * ci, v1.z * ci, v1.w * ci };
        s16x8 hi8, lo8;
        #pragma unroll
        for (int i = 0; i < 8; ++i) {
            u16 hb = f2bf(xv[i]);
            hi8[i] = (short)hb;
            lo8[i] = (short)f2bf(xv[i] - bf2f(hb));
        }
        const int off = (c * 4 + seg_m) * 512 + laneS * 8;
        *(s16x8*)(sm + off)        = hi8;
        *(s16x8*)(sm + off + 8192) = lo8;
    }
    __syncthreads();

    // ---- Phase B: Wout GEMM (K=64 -> N=128): m before bias ----
    f32x4 am[2][4];
    #pragma unroll
    for (int mf = 0; mf < 2; ++mf)
        #pragma unroll
        for (int t4 = 0; t4 < 4; ++t4)
            am[mf][t4] = (f32x4){0.f, 0.f, 0.f, 0.f};
    {
        const s16x8* WH8 = (const s16x8*)WoH;
        const s16x8* WL8 = (const s16x8*)WoL;
        #pragma unroll
        for (int kt = 0; kt < 2; ++kt) {
            const int a0off = (kt * 4 + 2 * mh) * 512 + lane * 8;
            const s16x8 aH0 = *(const s16x8*)(sm + a0off);
            const s16x8 aL0 = *(const s16x8*)(sm + 8192 + a0off);
            const s16x8 aH1 = *(const s16x8*)(sm + a0off + 512);
            const s16x8 aL1 = *(const s16x8*)(sm + 8192 + a0off + 512);
            #pragma unroll
            for (int t4 = 0; t4 < 4; ++t4) {
                const int idx = (kt * 8 + jg * 4 + t4) * 64 + lane;
                const s16x8 bH = WH8[idx];
                const s16x8 bL = WL8[idx];
                am[0][t4] = __builtin_amdgcn_mfma_f32_16x16x32_bf16(aH0, bH, am[0][t4], 0, 0, 0);
                am[0][t4] = __builtin_amdgcn_mfma_f32_16x16x32_bf16(aH0, bL, am[0][t4], 0, 0, 0);
                am[0][t4] = __builtin_amdgcn_mfma_f32_16x16x32_bf16(aL0, bH, am[0][t4], 0, 0, 0);
                am[1][t4] = __builtin_amdgcn_mfma_f32_16x16x32_bf16(aH1, bH, am[1][t4], 0, 0, 0);
                am[1][t4] = __builtin_amdgcn_mfma_f32_16x16x32_bf16(aH1, bL, am[1][t4], 0, 0, 0);
                am[1][t4] = __builtin_amdgcn_mfma_f32_16x16x32_bf16(aL1, bH, am[1][t4], 0, 0, 0);
            }
        }
    }
    __syncthreads();   // S-frag reads done; sm reused for gate ks0 frags

    // ---- Phase C: m epilogue (+bout if deg>0) + scatter to gate-A frags ----
    #pragma unroll
    for (int t4 = 0; t4 < 4; ++t4) {
        const int n = jg * 64 + t4 * 16 + (lane & 15);
        const float bv = bo[n];
        const int kt2 = n >> 5, gg = (n >> 3) & 3, jj = n & 7;
        #pragma unroll
        for (int mf = 0; mf < 2; ++mf) {
            const int mtile = 2 * mh + mf;
            #pragma unroll
            for (int r = 0; r < 4; ++r) {
                const int m15 = (lane >> 4) * 4 + r;
                const float cin = ci_s[mtile * 16 + m15];
                const float mv = am[mf][t4][r] + ((cin > 0.0f) ? bv : 0.0f);
                const int off = (kt2 * 4 + mtile) * 512 + (m15 + 16 * gg) * 8 + jj;
                u16 hb = f2bf(mv);
                sm[off]        = (short)hb;
                sm[off + 8192] = (short)f2bf(mv - bf2f(hb));
            }
        }
    }
    __syncthreads();

    // ---- Phase D: gate GEMM k-half 0 (z, r, xh) ----
    f32x4 acc[2][4][4];
    #pragma unroll
    for (int mf = 0; mf < 2; ++mf)
        #pragma unroll
        for (int g = 0; g < 4; ++g)
            #pragma unroll
            for (int t4 = 0; t4 < 4; ++t4)
                acc[mf][g][t4] = (f32x4){0.f, 0.f, 0.f, 0.f};

    const s16x8* Bh8 = (const s16x8*)BgH;
    const s16x8* Bl8 = (const s16x8*)BgL;
    #pragma unroll
    for (int kt = 0; kt < 4; ++kt) {
        const int a0off = (kt * 4 + 2 * mh) * 512 + lane * 8;
        const s16x8 aH0 = *(const s16x8*)(sm + a0off);
        const s16x8 aL0 = *(const s16x8*)(sm + 8192 + a0off);
        const s16x8 aH1 = *(const s16x8*)(sm + a0off + 512);
        const s16x8 aL1 = *(const s16x8*)(sm + 8192 + a0off + 512);
        #pragma unroll
        for (int g = 0; g < 3; ++g) {          // z, r, xh
            #pragma unroll
            for (int t4 = 0; t4 < 4; ++t4) {
                const int idx = (kt * 32 + g * 8 + jg * 4 + t4) * 64 + lane;
                const s16x8 bH = Bh8[idx];
                const s16x8 bL = Bl8[idx];
                acc[0][g][t4] = __builtin_amdgcn_mfma_f32_16x16x32_bf16(aH0, bH, acc[0][g][t4], 0, 0, 0);
                acc[0][g][t4] = __builtin_amdgcn_mfma_f32_16x16x32_bf16(aH0, bL, acc[0][g][t4], 0, 0, 0);
                acc[0][g][t4] = __builtin_amdgcn_mfma_f32_16x16x32_bf16(aL0, bH, acc[0][g][t4], 0, 0, 0);
                acc[1][g][t4] = __builtin_amdgcn_mfma_f32_16x16x32_bf16(aH1, bH, acc[1][g][t4], 0, 0, 0);
                acc[1][g][t4] = __builtin_amdgcn_mfma_f32_16x16x32_bf16(aH1, bL, acc[1][g][t4], 0, 0, 0);
                acc[1][g][t4] = __builtin_amdgcn_mfma_f32_16x16x32_bf16(aL1, bH, acc[1][g][t4], 0, 0, 0);
            }
        }
    }
    __syncthreads();

    // ---- Phase E: stage h fragments (k-half 1) ----
    #pragma unroll
    for (int c = 0; c < 4; ++c) {
        const int kl = c * 32 + q * 8;
        const float* src = hio + (size_t)nodeS * DDIM + kl;
        const float4 v0 = ((const float4*)src)[0];
        const float4 v1 = ((const float4*)src)[1];
        float xv[8] = { v0.x, v0.y, v0.z, v0.w, v1.x, v1.y, v1.z, v1.w };
        s16x8 hi8, lo8;
        #pragma unroll
        for (int i = 0; i < 8; ++i) {
            u16 hb = f2bf(xv[i]);
            hi8[i] = (short)hb;
            lo8[i] = (short)f2bf(xv[i] - bf2f(hb));
        }
        const int off = (c * 4 + seg_m) * 512 + laneS * 8;
        *(s16x8*)(sm + off)        = hi8;
        *(s16x8*)(sm + off + 8192) = lo8;
    }
    __syncthreads();

    // ---- Phase F: gate GEMM k-half 1 (z, r, hh) ----
    #pragma unroll
    for (int kt = 0; kt < 4; ++kt) {
        const int ktG = 4 + kt;
        const int a0off = (kt * 4 + 2 * mh) * 512 + lane * 8;
        const s16x8 aH0 = *(const s16x8*)(sm + a0off);
        const s16x8 aL0 = *(const s16x8*)(sm + 8192 + a0off);
        const s16x8 aH1 = *(const s16x8*)(sm + a0off + 512);
        const s16x8 aL1 = *(const s16x8*)(sm + 8192 + a0off + 512);
        #pragma unroll
        for (int gi = 0; gi < 3; ++gi) {
            const int g = (gi == 2) ? 3 : gi;   // z, r, hh
            #pragma unroll
            for (int t4 = 0; t4 < 4; ++t4) {
                const int idx = (ktG * 32 + g * 8 + jg * 4 + t4) * 64 + lane;
                const s16x8 bH = Bh8[idx];
                const s16x8 bL = Bl8[idx];
                acc[0][g][t4] = __builtin_amdgcn_mfma_f32_16x16x32_bf16(aH0, bH, acc[0][g][t4], 0, 0, 0);
                acc[0][g][t4] = __builtin_amdgcn_mfma_f32_16x16x32_bf16(aH0, bL, acc[0][g][t4], 0, 0, 0);
                acc[0][g][t4] = __builtin_amdgcn_mfma_f32_16x16x32_bf16(aL0, bH, acc[0][g][t4], 0, 0, 0);
                acc[1][g][t4] = __builtin_amdgcn_mfma_f32_16x16x32_bf16(aH1, bH, acc[1][g][t4], 0, 0, 0);
                acc[1][g][t4] = __builtin_amdgcn_mfma_f32_16x16x32_bf16(aH1, bL, acc[1][g][t4], 0, 0, 0);
                acc[1][g][t4] = __builtin_amdgcn_mfma_f32_16x16x32_bf16(aL1, bH, acc[1][g][t4], 0, 0, 0);
            }
        }
    }

    // ---- Phase G: gate epilogue -> h' (hv from resident LDS h frags) ----
    float hn[2][4][4];
    #pragma unroll
    for (int t4 = 0; t4 < 4; ++t4) {
        const int j = jg * 64 + t4 * 16 + (lane & 15);
        const float b_az = bi_[j]       + br_[j];
        const float b_ar = bi_[128 + j] + br_[128 + j];
        const float b_xh = bi_[256 + j];
        const float b_hh = br_[256 + j];
        const int jbase = (j >> 5) * 2048 + ((j >> 3) & 3) * 128 + (j & 7);
        #pragma unroll
        for (int mf = 0; mf < 2; ++mf) {
            const int mtile = 2 * mh + mf;
            #pragma unroll
            for (int r = 0; r < 4; ++r) {
                const int m15 = (lane >> 4) * 4 + r;
                const int off = jbase + mtile * 512 + m15 * 8;
                const float hv = bf2f((u16)sm[off]) + bf2f((u16)sm[8192 + off]);
                const int m = mtile * 16 + m15;
                const float az = acc[mf][0][t4][r] + b_az;
                const float ar = acc[mf][1][t4][r] + b_ar;
                const float xh = acc[mf][2][t4][r] + b_xh;
                const float hh = acc[mf][3][t4][r] + b_hh;
                const float z    = sigmoid_fast(az);
                const float rr   = sigmoid_fast(ar);
                const float cand = tanh_fast(xh + rr * hh);
                const float v    = z * hv + (1.0f - z) * cand;
                hio[(size_t)(nbase + m) * DDIM + j] = v;
                hn[mf][t4][r] = v;
            }
        }
    }
    __syncthreads();   // h-frag LDS reads done; reuse sm for pre-A frags

    // ---- Phase H: scatter h' into node_pre A-frag layout ----
    #pragma unroll
    for (int mf = 0; mf < 2; ++mf) {
        const int mtile = 2 * mh + mf;
        #pragma unroll
        for (int t4 = 0; t4 < 4; ++t4) {
            #pragma unroll
            for (int r = 0; r < 4; ++r) {
                const int m15 = (lane >> 4) * 4 + r;
                const int j   = jg * 64 + t4 * 16 + (lane & 15);
                const int kt2 = j >> 5, gg = (j >> 3) & 3, jj = j & 7;
                const int off = (kt2 * 4 + mtile) * 512 + (m15 + 16 * gg) * 8 + jj;
                const float v = hn[mf][t4][r];
                u16 hb = f2bf(v);
                sm[off]        = (short)hb;
                sm[off + 8192] = (short)f2bf(v - bf2f(hb));
            }
        }
    }
    __syncthreads();

    // ---- Phase I: node_pre GEMM -> p ----
    f32x4 acc2[2][4];
    #pragma unroll
    for (int mf = 0; mf < 2; ++mf)
        #pragma unroll
        for (int t4 = 0; t4 < 4; ++t4)
            acc2[mf][t4] = (f32x4){0.f, 0.f, 0.f, 0.f};

    const s16x8* Ph8 = (const s16x8*)BpH;
    const s16x8* Pl8 = (const s16x8*)BpL;
    #pragma unroll
    for (int kt2 = 0; kt2 < 4; ++kt2) {
        const int a0off = (kt2 * 4 + 2 * mh) * 512 + lane * 8;
        const s16x8 aH0 = *(const s16x8*)(sm + a0off);
        const s16x8 aL0 = *(const s16x8*)(sm + 8192 + a0off);
        const s16x8 aH1 = *(const s16x8*)(sm + a0off + 512);
        const s16x8 aL1 = *(const s16x8*)(sm + 8192 + a0off + 512);
        #pragma unroll
        for (int t4 = 0; t4 < 4; ++t4) {
            const int idx = (kt2 * 8 + jg * 4 + t4) * 64 + lane;
            const s16x8 bH = Ph8[idx];
            const s16x8 bL = Pl8[idx];
            acc2[0][t4] = __builtin_amdgcn_mfma_f32_16x16x32_bf16(aH0, bH, acc2[0][t4], 0, 0, 0);
            acc2[0][t4] = __builtin_amdgcn_mfma_f32_16x16x32_bf16(aH0, bL, acc2[0][t4], 0, 0, 0);
            acc2[0][t4] = __builtin_amdgcn_mfma_f32_16x16x32_bf16(aL0, bH, acc2[0][t4], 0, 0, 0);
            acc2[1][t4] = __builtin_amdgcn_mfma_f32_16x16x32_bf16(aH1, bH, acc2[1][t4], 0, 0, 0);
            acc2[1][t4] = __builtin_amdgcn_mfma_f32_16x16x32_bf16(aH1, bL, acc2[1][t4], 0, 0, 0);
            acc2[1][t4] = __builtin_amdgcn_mfma_f32_16x16x32_bf16(aL1, bH, acc2[1][t4], 0, 0, 0);
        }
    }
    #pragma unroll
    for (int mf = 0; mf < 2; ++mf) {
        const int mtile = 2 * mh + mf;
        #pragma unroll
        for (int t4 = 0; t4 < 4; ++t4) {
            const int n = jg * 64 + t4 * 16 + (lane & 15);
            const float badd = (n < 64) ? binp[n] : 0.0f;
            #pragma unroll
            for (int r = 0; r < 4; ++r) {
                const int m = mtile * 16 + (lane >> 4) * 4 + r;
                pout[(size_t)(nbase + m) * DDIM + n] = acc2[mf][t4][r] + badd;
            }
        }
    }
}

// Readout: block=64, LDS activation slices, scalar weights.
__global__ __launch_bounds__(64) void readout_kernel(
    const float* __restrict__ h,
    const float* __restrict__ Win,  const float* __restrict__ bin,
    const float* __restrict__ Whid, const float* __restrict__ bhid,
    const float* __restrict__ Wout, const float* __restrict__ bout,
    float* __restrict__ out)
{
    __shared__ float xs[64 * 65];
    const int tid = threadIdx.x;
    const int row = blockIdx.x * 64 + tid;
    const int b = row / 1000, n = row % 1000;
    const float4* xrow = (const float4*)(h + ((size_t)b * 4000 + n) * DDIM);

    {
        float acc[64];
        #pragma unroll
        for (int j = 0; j < 64; ++j) acc[j] = bin[j];
        #pragma unroll 2
        for (int k4 = 0; k4 < 32; ++k4) {
            float4 xv = xrow[k4];
            #pragma unroll
            for (int kk = 0; kk < 4; ++kk) {
                const float xk = (&xv.x)[kk];
                const float* wr = Win + (size_t)(k4 * 4 + kk) * 64;
                #pragma unroll
                for (int j = 0; j < 64; ++j) acc[j] = fmaf(xk, wr[j], acc[j]);
            }
        }
        #pragma unroll
        for (int j = 0; j < 64; ++j) xs[tid * 65 + j] = gelu_exact(acc[j]);
    }

    for (int L = 0; L < 3; ++L) {
        float acc[64];
        #pragma unroll
        for (int j = 0; j < 64; ++j) acc[j] = bhid[L * 64 + j];
        #pragma unroll 4
        for (int k = 0; k < 64; ++k) {
            const float xk = xs[tid * 65 + k];
            const float* wr = Whid + (size_t)L * 4096 + (size_t)k * 64;
            #pragma unroll
            for (int j = 0; j < 64; ++j) acc[j] = fmaf(xk, wr[j], acc[j]);
        }
        #pragma unroll
        for (int j = 0; j < 64; ++j) xs[tid * 65 + j] = gelu_exact(acc[j]);
    }

    float acc[10];
    #pragma unroll
    for (int pj = 0; pj < 10; ++pj) acc[pj] = bout[pj];
    #pragma unroll 4
    for (int k = 0; k < 64; ++k) {
        const float xk = xs[tid * 65 + k];
        const float* wr = Wout + k * 10;
        #pragma unroll
        for (int pj = 0; pj < 10; ++pj) acc[pj] = fmaf(xk, wr[pj], acc[pj]);
    }
    #pragma unroll
    for (int pj = 0; pj < 10; ++pj) out[(size_t)row * 10 + pj] = acc[pj];
}

extern "C" void kernel_launch(void* const* d_in, const int* in_sizes, int n_in,
                              void* d_out, int out_size, void* d_ws, size_t ws_size,
                              hipStream_t stream) {
    const int*   node_inputs = (const int*)d_in[0];
    const int*   ni_int = (const int*)d_in[1];
    const int*   bi_int = (const int*)d_in[2];
    const int*   ni_tmp = (const int*)d_in[3];
    const int*   bi_tmp = (const int*)d_in[4];
    const float* embed  = (const float*)d_in[5];
    const float* mWin   = (const float*)d_in[6];
    const float* mbin   = (const float*)d_in[7];
    const float* mWhid  = (const float*)d_in[8];
    const float* mbhid  = (const float*)d_in[9];
    const float* mWout  = (const float*)d_in[10];
    const float* mbout  = (const float*)d_in[11];
    const float* roWin  = (const float*)d_in[12];
    const float* robin  = (const float*)d_in[13];
    const float* roWhid = (const float*)d_in[14];
    const float* robhid = (const float*)d_in[15];
    const float* roWout = (const float*)d_in[16];
    const float* robout = (const float*)d_in[17];
    const float* giWx = (const float*)d_in[18];
    const float* giWh = (const float*)d_in[19];
    const float* gibi = (const float*)d_in[20];
    const float* gibr = (const float*)d_in[21];
    const float* gtWx = (const float*)d_in[22];
    const float* gtWh = (const float*)d_in[23];
    const float* gtbi = (const float*)d_in[24];
    const float* gtbr = (const float*)d_in[25];
    float* out = (float*)d_out;

    const int E_INT = 200000, E_TMP = 96000;
    const int NSLOT_I = 400000;   // 3125*128 exact
    const int NSLOT_T = 192000;   // 1500*128 exact
    const int NBLK_I = NSLOT_I / EBLK;
    const int NBLK_T = NSLOT_T / EBLK;
    const int NS32_I = NSLOT_I / 32;   // 12500
    const int NS32_T = NSLOT_T / 32;   // 6000

    char* ws = (char*)d_ws;
    float* B0 = (float*)(ws);                 // h (in-place)
    float* B1 = (float*)(ws + HBYTES);        // p
    float* B2 = (float*)(ws + 2 * HBYTES);    // S (64-wide, 32.8MB used)
    char*  ib = ws + 3 * HBYTES;

    int* deg_i   = (int*)(ib);
    int* deg_t   = (int*)(ib + 512000);
    int* offp_i  = (int*)(ib + 1024000);
    int* offp_t  = (int*)(ib + 1536000);
    int* bexc_i  = (int*)(ib + 2048000);
    int* bexc_t  = (int*)(ib + 2052096);
    int* bsum    = (int*)(ib + 2056192);
    int* cursor  = (int*)(ib + 2060288);
    int* el_i    = (int*)(ib + 2572288);
    int* el_t    = (int*)(ib + 4172288);
    int* ssi_raw = (int*)(ib + 4940288);
    int* sst_raw = (int*)(ib + 6540296);
    // bf16-split B-fragment buffers
    char* fb = ib + 8114176;
    u16* BgiH = (u16*)(fb);
    u16* BgiL = (u16*)(fb +  262144);
    u16* BgtH = (u16*)(fb +  524288);
    u16* BgtL = (u16*)(fb +  786432);
    u16* BpH  = (u16*)(fb + 1048576);
    u16* BpL  = (u16*)(fb + 1081344);
    u16* EhH  = (u16*)(fb + 1114112);   // 3*4096 elems = 24576 B
    u16* EhL  = (u16*)(fb + 1138688);
    u16* EoH  = (u16*)(fb + 1163264);   // 8192 elems = 16384 B
    u16* EoL  = (u16*)(fb + 1179648);
    // stride-32 straddle lists (R24)
    int* str_i  = (int*)(fb + 1196032);   // up to 12500 ints
    int* str_t  = (int*)(fb + 1246032);   // up to 6000 ints
    int* strc_i = (int*)(fb + 1270032);
    int* strc_t = (int*)(fb + 1270036);
    int* ssi = ssi_raw + 1;
    int* sst = sst_raw + 1;

    embed_kernel<<<16000, 256, 0, stream>>>(node_inputs, embed, B0);

    hipMemsetAsync(deg_i, 0, NTOT * sizeof(int), stream);
    hipMemsetAsync(deg_t, 0, NTOT * sizeof(int), stream);
    hist_kernel<<<(2 * E_INT + 255) / 256, 256, 0, stream>>>(ni_int, bi_int, E_INT, deg_i);
    hist_kernel<<<(2 * E_TMP + 255) / 256, 256, 0, stream>>>(ni_tmp, bi_tmp, E_TMP, deg_t);

    hipMemsetAsync(ssi_raw, 0xFF, (size_t)(NSLOT_I + 2) * sizeof(int), stream);
    hipMemsetAsync(sst_raw, 0xFF, (size_t)(NSLOT_T + 2) * sizeof(int), stream);

    blockscan_kernel<<<500, 256, 0, stream>>>(deg_i, offp_i, bsum);
    bscan_kernel<<<1, 512, 0, stream>>>(bsum, bexc_i, 500);
    hipMemsetAsync(cursor, 0, NTOT * sizeof(int), stream);
    fill_kernel<<<(2 * E_INT + 255) / 256, 256, 0, stream>>>(
        ni_int, bi_int, E_INT, offp_i, bexc_i, cursor, el_i, ssi);

    blockscan_kernel<<<500, 256, 0, stream>>>(deg_t, offp_t, bsum);
    bscan_kernel<<<1, 512, 0, stream>>>(bsum, bexc_t, 500);
    hipMemsetAsync(cursor, 0, NTOT * sizeof(int), stream);
    fill_kernel<<<(2 * E_TMP + 255) / 256, 256, 0, stream>>>(
        ni_tmp, bi_tmp, E_TMP, offp_t, bexc_t, cursor, el_t, sst);

    hipMemsetAsync(strc_i, 0, sizeof(int), stream);
    hipMemsetAsync(strc_t, 0, sizeof(int), stream);
    straddle_kernel<<<(NS32_I + 255) / 256, 256, 0, stream>>>(ssi, NS32_I, str_i, strc_i);
    straddle_kernel<<<(NS32_T + 255) / 256, 256, 0, stream>>>(sst, NS32_T, str_t, strc_t);

    pack_gateB_kernel<<<512, 256, 0, stream>>>(giWx, giWh, BgiH, BgiL);
    pack_gateB_kernel<<<512, 256, 0, stream>>>(gtWx, gtWh, BgtH, BgtL);
    pack_preB_kernel<<<64, 256, 0, stream>>>(mWin, BpH, BpL);
    pack_hidB_kernel<<<48, 256, 0, stream>>>(mWhid, EhH, EhL);
    pack_outB_kernel<<<32, 256, 0, stream>>>(mWout, EoH, EoL);

    node_pre_kernel<<<NTOT / 256, 256, 0, stream>>>(B0, mWin, mbin, B1);

    // fixed roles: h=B0 (in place), p=B1, S=B2
    for (int ph = 0; ph < 4; ++ph) {
        const bool isInt = (ph % 2 == 0);
        if (isInt) {
            zero_rows_kernel<<<NS32_I, 64, 0, stream>>>(str_i, strc_i, B2);
            edge_mlp_mfma<<<NBLK_I, 512, 0, stream>>>(
                ni_int, bi_int, E_INT, el_i, ssi, B1,
                EhH, EhL, mbhid, B2);
            gru_mfma_kernel<<<NTOT / 64, 256, 0, stream>>>(
                B0, B2, deg_i, EoH, EoL, mbout,
                BgiH, BgiL, gibi, gibr, BpH, BpL, mbin, B1);
        } else {
            zero_rows_kernel<<<NS32_T, 64, 0, stream>>>(str_t, strc_t, B2);
            edge_mlp_mfma<<<NBLK_T, 512, 0, stream>>>(
                ni_tmp, bi_tmp, E_TMP, el_t, sst, B1,
                EhH, EhL, mbhid, B2);
            gru_mfma_kernel<<<NTOT / 64, 256, 0, stream>>>(
                B0, B2, deg_t, EoH, EoL, mbout,
                BgtH, BgtL, gtbi, gtbr, BpH, BpL, mbin, B1);
        }
    }

    readout_kernel<<<500, 64, 0, stream>>>(
        B0, roWin, robin, roWhid, robhid, roWout, robout, out);
}